// Round 8
// baseline (463.588 us; speedup 1.0000x reference)
//
#include <hip/hip_runtime.h>
#include <cstdint>
#include <cstddef>

#define NN 30000
#define NE 480000

__device__ __forceinline__ float leakyf(float x){ return x > 0.f ? x : 0.2f * x; }
__device__ __forceinline__ float eluf(float x){ return x > 0.f ? x : expm1f(x); }

struct F4 { float x, y, z, w; };

__device__ __forceinline__ F4 ld4(const float* p){
  float4 v = *(const float4*)p;
  return F4{v.x, v.y, v.z, v.w};
}

// ---------------- CSR build ----------------

__global__ void zero_int_kernel(int* __restrict__ p, int n){
  int i = blockIdx.x * blockDim.x + threadIdx.x;
  if (i < n) p[i] = 0;
}

__global__ void count_kernel(const int* __restrict__ dst, int* __restrict__ deg, int E){
  int i = blockIdx.x * blockDim.x + threadIdx.x;
  if (i < E) atomicAdd(&deg[dst[i]], 1);
}

__global__ void scan1_kernel(const int* __restrict__ deg, int* __restrict__ offs,
                             int* __restrict__ bsum){
  __shared__ int sh[256];
  int blk = blockIdx.x, t = threadIdx.x, i = blk * 256 + t;
  int v = (i < NN) ? deg[i] : 0;
  sh[t] = v; __syncthreads();
  for (int o = 1; o < 256; o <<= 1){
    int tv = (t >= o) ? sh[t - o] : 0;
    __syncthreads();
    sh[t] += tv;
    __syncthreads();
  }
  if (i < NN) offs[i + 1] = sh[t];
  if (t == 255) bsum[blk] = sh[255];
}

__global__ void scan2_kernel(int* __restrict__ bsum, int nb){
  __shared__ int sh[256];
  int t = threadIdx.x;
  int v = (t < nb) ? bsum[t] : 0;
  sh[t] = v; __syncthreads();
  for (int o = 1; o < 256; o <<= 1){
    int tv = (t >= o) ? sh[t - o] : 0;
    __syncthreads();
    sh[t] += tv;
    __syncthreads();
  }
  if (t < nb) bsum[t] = sh[t];
}

__global__ void scan3_kernel(const int* __restrict__ bsum, int* __restrict__ offs){
  int i = blockIdx.x * 256 + threadIdx.x;
  if (i == 0) offs[0] = 0;
  if (i < NN){
    int blk = i >> 8;
    int add = blk ? bsum[blk - 1] : 0;
    offs[i + 1] += add;
  }
}

__global__ void scatter_kernel(const int* __restrict__ src, const int* __restrict__ dst,
                               const int* __restrict__ et, const int* __restrict__ offs,
                               int* __restrict__ cursor, int* __restrict__ csr_src,
                               int* __restrict__ csr_et, int E){
  int i = blockIdx.x * blockDim.x + threadIdx.x;
  if (i < E){
    int d = dst[i];
    int pos = offs[d] + atomicAdd(&cursor[d], 1);
    csr_src[pos] = src[i];
    csr_et[pos]  = et[i];
  }
}

// ---------------- weight concat: Wcat2[k][b*64+c] = basis2[b][k][c]; [k][256+c] = root2[k][c] ----

__global__ void wcat2_kernel(const float* __restrict__ basis2, const float* __restrict__ root2,
                             float* __restrict__ Wcat){
  int idx = blockIdx.x * 256 + threadIdx.x;
  if (idx >= 256 * 320) return;
  int k = idx / 320, col = idx - k * 320;
  float v;
  if (col < 256){
    int b = col >> 6, c = col & 63;
    v = basis2[((size_t)b * 256 + k) * 64 + c];
  } else {
    v = root2[(size_t)k * 64 + (col - 256)];
  }
  Wcat[idx] = v;
}

// ---------------- layer-1 basis-space aggregation ----------------

__global__ void agg1_kernel(const float* __restrict__ x, const float* __restrict__ comp,
                            const int* __restrict__ offs, const int* __restrict__ csr_src,
                            const int* __restrict__ csr_et, float* __restrict__ agg){
  int wid  = (blockIdx.x * blockDim.x + threadIdx.x) >> 6;
  int lane = threadIdx.x & 63;
  if (wid >= NN) return;
  int c = lane & 31, half = lane >> 5;
  int n0 = offs[wid], n1 = offs[wid + 1];
  float a0 = 0.f, a1 = 0.f, a2 = 0.f, a3 = 0.f;
  for (int k = n0 + half; k < n1; k += 2){
    int s = csr_src[k], e = csr_et[k];
    float v = x[(size_t)s * 32 + c];
    F4 cp = ld4(comp + (size_t)e * 4);
    a0 += cp.x * v; a1 += cp.y * v; a2 += cp.z * v; a3 += cp.w * v;
  }
  a0 += __shfl_xor(a0, 32);
  a1 += __shfl_xor(a1, 32);
  a2 += __shfl_xor(a2, 32);
  a3 += __shfl_xor(a3, 32);
  int dg = n1 - n0;
  float sc = 1.f / (float)(dg > 0 ? dg : 1);
  if (lane < 32){
    float* ar = agg + (size_t)wid * 128 + c;
    ar[0]  = a0 * sc;
    ar[32] = a1 * sc;
    ar[64] = a2 * sc;
    ar[96] = a3 * sc;
  }
}

// ---------------- NCG-fused 64-row GEMM, 4x4 microtile, all column groups per block ----
// OUT[n, cg*64+c] = act( A1[n,:]@W1[:,cg*64+c] + A2[n,:]@W2[:,cg*64+c] + bias ), cg=0..NCG-1
// 256 threads = 16(tc) x 16(tr); thread owns rows tr*4..+3, cols tc*4..+3 of each cg.
// K-tile 32: At[32][68] staged once, Wl[NCG][32][68]; per k: 1 A-read + NCG W-reads + NCG*16 FMA.

template<int NCG, bool ELU, bool ATT>
__global__ __launch_bounds__(256) void gemmN_kernel(
    const float* __restrict__ A1, int lda1, int K1,
    const float* __restrict__ W1, int ldw1,
    const float* __restrict__ A2, int lda2, int K2,
    const float* __restrict__ W2, int ldw2,
    const float* __restrict__ bias,
    const float* __restrict__ atts, const float* __restrict__ attd,
    float* __restrict__ Y, int ldy,
    float* __restrict__ as_, float* __restrict__ ad_,
    int nrows)
{
  __shared__ float At[32][68];
  __shared__ float Wl[NCG][32][68];
  int t = threadIdx.x;
  int tc = t & 15, tr = t >> 4;
  int nbase = blockIdx.x * 64;
  float acc[NCG][4][4];
  #pragma unroll
  for (int cg = 0; cg < NCG; cg++)
    #pragma unroll
    for (int j = 0; j < 4; j++)
      #pragma unroll
      for (int i = 0; i < 4; i++) acc[cg][j][i] = 0.f;

  for (int seg = 0; seg < 2; seg++){
    const float* A = seg ? A2 : A1;
    const float* W = seg ? W2 : W1;
    int lda = seg ? lda2 : lda1;
    int ldw = seg ? ldw2 : ldw1;
    int K   = seg ? K2 : K1;
    if (A == nullptr || K <= 0) continue;
    for (int k0 = 0; k0 < K; k0 += 32){
      // stage W tiles: Wl[cg][kk][c] = W[k0+kk][cg*64+c]
      #pragma unroll
      for (int cg = 0; cg < NCG; cg++){
        #pragma unroll
        for (int i = 0; i < 2; i++){
          int e = i * 256 + t;
          int kk = e >> 4, c4 = (e & 15) << 2;
          float4 v = make_float4(0.f, 0.f, 0.f, 0.f);
          if (k0 + kk < K) v = *(const float4*)(W + (size_t)(k0 + kk) * ldw + cg * 64 + c4);
          *(float4*)&Wl[cg][kk][c4] = v;
        }
      }
      // stage A transposed: At[kk][r] = A[nbase+r][k0+kk]
      #pragma unroll
      for (int i = 0; i < 2; i++){
        int e = i * 256 + t;
        int r = e >> 3, c4 = (e & 7) << 2;
        int n = nbase + r;
        float4 v = make_float4(0.f, 0.f, 0.f, 0.f);
        if (n < nrows && k0 + c4 < K) v = *(const float4*)(A + (size_t)n * lda + k0 + c4);
        At[c4 + 0][r] = v.x;
        At[c4 + 1][r] = v.y;
        At[c4 + 2][r] = v.z;
        At[c4 + 3][r] = v.w;
      }
      __syncthreads();
      #pragma unroll 4
      for (int k = 0; k < 32; k++){
        float4 av = *(const float4*)&At[k][tr * 4];
        const float* pa = (const float*)&av;
        #pragma unroll
        for (int cg = 0; cg < NCG; cg++){
          float4 wv = *(const float4*)&Wl[cg][k][tc * 4];
          const float* pw = (const float*)&wv;
          #pragma unroll
          for (int j = 0; j < 4; j++)
            #pragma unroll
            for (int i = 0; i < 4; i++)
              acc[cg][j][i] = fmaf(pa[j], pw[i], acc[cg][j][i]);
        }
      }
      __syncthreads();
    }
  }

  // epilogue
  #pragma unroll
  for (int cg = 0; cg < NCG; cg++){
    float b0 = 0.f, b1 = 0.f, b2 = 0.f, b3 = 0.f;
    if (bias){
      b0 = bias[cg * 64 + tc * 4 + 0];
      b1 = bias[cg * 64 + tc * 4 + 1];
      b2 = bias[cg * 64 + tc * 4 + 2];
      b3 = bias[cg * 64 + tc * 4 + 3];
    }
    #pragma unroll
    for (int j = 0; j < 4; j++){
      int n = nbase + tr * 4 + j;
      if (n < nrows){
        float y0 = acc[cg][j][0] + b0, y1 = acc[cg][j][1] + b1;
        float y2 = acc[cg][j][2] + b2, y3 = acc[cg][j][3] + b3;
        if (ELU){ y0 = eluf(y0); y1 = eluf(y1); y2 = eluf(y2); y3 = eluf(y3); }
        *(float4*)(Y + (size_t)n * ldy + cg * 64 + tc * 4) = make_float4(y0, y1, y2, y3);
      }
    }
    if (ATT){
      float ta0 = atts[cg * 64 + tc * 4 + 0], ta1 = atts[cg * 64 + tc * 4 + 1];
      float ta2 = atts[cg * 64 + tc * 4 + 2], ta3 = atts[cg * 64 + tc * 4 + 3];
      float tb0 = attd[cg * 64 + tc * 4 + 0], tb1 = attd[cg * 64 + tc * 4 + 1];
      float tb2 = attd[cg * 64 + tc * 4 + 2], tb3 = attd[cg * 64 + tc * 4 + 3];
      #pragma unroll
      for (int j = 0; j < 4; j++){
        float ps = acc[cg][j][0]*ta0 + acc[cg][j][1]*ta1 + acc[cg][j][2]*ta2 + acc[cg][j][3]*ta3;
        float pd = acc[cg][j][0]*tb0 + acc[cg][j][1]*tb1 + acc[cg][j][2]*tb2 + acc[cg][j][3]*tb3;
        #pragma unroll
        for (int o = 8; o; o >>= 1){ ps += __shfl_xor(ps, o); pd += __shfl_xor(pd, o); }
        int n = nbase + tr * 4 + j;
        if (tc == 0 && n < nrows){ as_[n * 4 + cg] = ps; ad_[n * 4 + cg] = pd; }
      }
    }
  }
}

// ---------------- layer-3 aggregate (transform-first) ----------------

__global__ void rgcn2_agg_kernel(const float* __restrict__ xb, const float* __restrict__ comp,
                                 const float* __restrict__ bias, const int* __restrict__ offs,
                                 const int* __restrict__ csr_src, const int* __restrict__ csr_et,
                                 float* __restrict__ h3){
  int wid  = (blockIdx.x * blockDim.x + threadIdx.x) >> 6;
  int lane = threadIdx.x & 63;
  if (wid >= NN) return;
  int b = lane >> 4, q = lane & 15;
  int n0 = offs[wid], n1 = offs[wid + 1];
  float ax = 0.f, ay = 0.f, az = 0.f, aw = 0.f;
  int k = n0;
  for (; k + 1 < n1; k += 2){
    int s0 = csr_src[k],     e0 = csr_et[k];
    int s1 = csr_src[k + 1], e1 = csr_et[k + 1];
    float c0 = comp[e0 * 4 + b];
    float c1 = comp[e1 * 4 + b];
    float4 v0 = *(const float4*)(xb + (size_t)s0 * 320 + lane * 4);
    float4 v1 = *(const float4*)(xb + (size_t)s1 * 320 + lane * 4);
    ax += c0 * v0.x + c1 * v1.x;
    ay += c0 * v0.y + c1 * v1.y;
    az += c0 * v0.z + c1 * v1.z;
    aw += c0 * v0.w + c1 * v1.w;
  }
  if (k < n1){
    int s = csr_src[k], e = csr_et[k];
    float c0 = comp[e * 4 + b];
    float4 v = *(const float4*)(xb + (size_t)s * 320 + lane * 4);
    ax += c0 * v.x; ay += c0 * v.y; az += c0 * v.z; aw += c0 * v.w;
  }
  ax += __shfl_xor(ax, 16); ax += __shfl_xor(ax, 32);
  ay += __shfl_xor(ay, 16); ay += __shfl_xor(ay, 32);
  az += __shfl_xor(az, 16); az += __shfl_xor(az, 32);
  aw += __shfl_xor(aw, 16); aw += __shfl_xor(aw, 32);
  int dg = n1 - n0;
  float sc = 1.f / (float)(dg > 0 ? dg : 1);
  if (lane < 16){
    float4 r  = *(const float4*)(xb + (size_t)wid * 320 + 256 + q * 4);
    float4 bb = *(const float4*)(bias + q * 4);
    float4 o4;
    o4.x = eluf(ax * sc + r.x + bb.x);
    o4.y = eluf(ay * sc + r.y + bb.y);
    o4.z = eluf(az * sc + r.z + bb.z);
    o4.w = eluf(aw * sc + r.w + bb.w);
    *(float4*)(h3 + (size_t)wid * 64 + q * 4) = o4;
  }
}

// ---------------- GAT ----------------

__global__ void gat1_agg_kernel(const float* __restrict__ hw, const float* __restrict__ as_,
                                const float* __restrict__ ad_, const float* __restrict__ bias,
                                const int* __restrict__ offs, const int* __restrict__ csr_src,
                                float* __restrict__ out){
  int wid  = (blockIdx.x * blockDim.x + threadIdx.x) >> 6;
  int lane = threadIdx.x & 63;
  if (wid >= NN) return;
  int n0 = offs[wid], n1 = offs[wid + 1];
  int h    = lane & 3;
  int hseg = lane >> 4;
  float adn = ad_[wid * 4 + h];
  float es  = leakyf(as_[wid * 4 + h] + adn);
  float m = es;
  for (int k = n0 + (lane >> 2); k < n1; k += 16){
    int s = csr_src[k];
    m = fmaxf(m, leakyf(as_[s * 4 + h] + adn));
  }
  #pragma unroll
  for (int o = 4; o < 64; o <<= 1) m = fmaxf(m, __shfl_xor(m, o));
  float den = 0.f;
  float4 acc = make_float4(0.f, 0.f, 0.f, 0.f);
  for (int base = n0; base < n1; base += 16){
    int k = base + (lane >> 2);
    int s = 0; float p = 0.f;
    if (k < n1){
      s = csr_src[k];
      p = expf(leakyf(as_[s * 4 + h] + adn) - m);
    }
    den += p;
    int cnt = min(16, n1 - base);
    for (int jj = 0; jj < cnt; jj++){
      float pj = __shfl(p, (jj << 2) | hseg);
      int  sj  = __shfl(s, (jj << 2));
      float4 v = *(const float4*)(hw + (size_t)sj * 256 + lane * 4);
      acc.x += pj * v.x; acc.y += pj * v.y; acc.z += pj * v.z; acc.w += pj * v.w;
    }
  }
  #pragma unroll
  for (int o = 4; o < 64; o <<= 1) den += __shfl_xor(den, o);
  float ps   = expf(es - m);
  float psh  = __shfl(ps, hseg);
  float denh = __shfl(den, hseg) + psh;
  float4 v = *(const float4*)(hw + (size_t)wid * 256 + lane * 4);
  acc.x += psh * v.x; acc.y += psh * v.y; acc.z += psh * v.z; acc.w += psh * v.w;
  float4 bb = *(const float4*)(bias + lane * 4);
  float4 o4;
  o4.x = eluf(acc.x / denh + bb.x);
  o4.y = eluf(acc.y / denh + bb.y);
  o4.z = eluf(acc.z / denh + bb.z);
  o4.w = eluf(acc.w / denh + bb.w);
  *(float4*)(out + (size_t)wid * 256 + lane * 4) = o4;
}

__global__ void gat_lin2_kernel(const float* __restrict__ h, const float* __restrict__ W,
                                const float* __restrict__ atts, const float* __restrict__ attd,
                                float* __restrict__ hw, float* __restrict__ as_, float* __restrict__ ad_){
  int wid  = (blockIdx.x * blockDim.x + threadIdx.x) >> 6;
  int lane = threadIdx.x & 63;
  if (wid >= NN) return;
  float acc = 0.f;
  if (lane < 12){
    const float* hr = h + (size_t)wid * 64;
    const float* Wc = W + lane;
    #pragma unroll 8
    for (int i = 0; i < 64; i++) acc += hr[i] * Wc[(size_t)i * 12];
    hw[(size_t)wid * 12 + lane] = acc;
  }
  float ts = (lane < 12) ? acc * atts[lane] : 0.f;
  float td = (lane < 12) ? acc * attd[lane] : 0.f;
  int b = (lane < 4) ? lane * 3 : 0;
  float s0 = __shfl(ts, b) + __shfl(ts, b + 1) + __shfl(ts, b + 2);
  float d0 = __shfl(td, b) + __shfl(td, b + 1) + __shfl(td, b + 2);
  if (lane < 4){ as_[wid * 4 + lane] = s0; ad_[wid * 4 + lane] = d0; }
}

__global__ void gat2_final_kernel(const float* __restrict__ hw, const float* __restrict__ as_,
                                  const float* __restrict__ ad_, const float* __restrict__ bg2,
                                  const int* __restrict__ offs, const int* __restrict__ csr_src,
                                  float* __restrict__ out){
  int wid  = (blockIdx.x * blockDim.x + threadIdx.x) >> 6;
  int lane = threadIdx.x & 63;
  if (wid >= NN) return;
  int n0 = offs[wid], n1 = offs[wid + 1];
  F4 adn = ld4(ad_ + (size_t)wid * 4);
  F4 asn = ld4(as_ + (size_t)wid * 4);
  F4 es{leakyf(asn.x + adn.x), leakyf(asn.y + adn.y), leakyf(asn.z + adn.z), leakyf(asn.w + adn.w)};
  F4 m = es;
  for (int k = n0 + lane; k < n1; k += 64){
    int s = csr_src[k];
    F4 a = ld4(as_ + (size_t)s * 4);
    m.x = fmaxf(m.x, leakyf(a.x + adn.x));
    m.y = fmaxf(m.y, leakyf(a.y + adn.y));
    m.z = fmaxf(m.z, leakyf(a.z + adn.z));
    m.w = fmaxf(m.w, leakyf(a.w + adn.w));
  }
  #pragma unroll
  for (int o = 32; o; o >>= 1){
    m.x = fmaxf(m.x, __shfl_xor(m.x, o));
    m.y = fmaxf(m.y, __shfl_xor(m.y, o));
    m.z = fmaxf(m.z, __shfl_xor(m.z, o));
    m.w = fmaxf(m.w, __shfl_xor(m.w, o));
  }
  F4 ps{expf(es.x - m.x), expf(es.y - m.y), expf(es.z - m.z), expf(es.w - m.w)};
  float acc[12];
  #pragma unroll
  for (int j = 0; j < 12; j++) acc[j] = 0.f;
  F4 denp{0.f, 0.f, 0.f, 0.f};
  for (int k = n0 + lane; k < n1; k += 64){
    int s = csr_src[k];
    F4 a = ld4(as_ + (size_t)s * 4);
    F4 p{expf(leakyf(a.x + adn.x) - m.x), expf(leakyf(a.y + adn.y) - m.y),
         expf(leakyf(a.z + adn.z) - m.z), expf(leakyf(a.w + adn.w) - m.w)};
    denp.x += p.x; denp.y += p.y; denp.z += p.z; denp.w += p.w;
    const float* hb = hw + (size_t)s * 12;
    F4 h0 = ld4(hb), h1 = ld4(hb + 4), h2 = ld4(hb + 8);
    acc[0] += p.x * h0.x; acc[1]  += p.x * h0.y; acc[2]  += p.x * h0.z;
    acc[3] += p.y * h0.w; acc[4]  += p.y * h1.x; acc[5]  += p.y * h1.y;
    acc[6] += p.z * h1.z; acc[7]  += p.z * h1.w; acc[8]  += p.z * h2.x;
    acc[9] += p.w * h2.y; acc[10] += p.w * h2.z; acc[11] += p.w * h2.w;
  }
  #pragma unroll
  for (int o = 32; o; o >>= 1){
    denp.x += __shfl_xor(denp.x, o);
    denp.y += __shfl_xor(denp.y, o);
    denp.z += __shfl_xor(denp.z, o);
    denp.w += __shfl_xor(denp.w, o);
    #pragma unroll
    for (int j = 0; j < 12; j++) acc[j] += __shfl_xor(acc[j], o);
  }
  if (lane == 0){
    const float* hn = hw + (size_t)wid * 12;
    float dn[4]  = {denp.x + ps.x, denp.y + ps.y, denp.z + ps.z, denp.w + ps.w};
    float psv[4] = {ps.x, ps.y, ps.z, ps.w};
    float tot = 0.f;
    #pragma unroll
    for (int h_ = 0; h_ < 4; h_++){
      #pragma unroll
      for (int c = 0; c < 3; c++){
        float num = acc[h_ * 3 + c] + psv[h_] * hn[h_ * 3 + c];
        tot += num / dn[h_];
      }
    }
    tot = tot / 12.f + (bg2[0] + bg2[1] + bg2[2]) / 3.f;
    out[wid] = tanhf(tot);
  }
}

// ---------------- launch ----------------

extern "C" void kernel_launch(void* const* d_in, const int* in_sizes, int n_in,
                              void* d_out, int out_size, void* d_ws, size_t ws_size,
                              hipStream_t stream){
  const float* x      = (const float*)d_in[0];
  const int*   ei     = (const int*)d_in[1];
  const int*   et     = (const int*)d_in[2];
  const float* basis1 = (const float*)d_in[3];
  const float* comp1  = (const float*)d_in[4];
  const float* root1  = (const float*)d_in[5];
  const float* brg1   = (const float*)d_in[6];
  const float* Wg1    = (const float*)d_in[7];
  const float* atts1  = (const float*)d_in[8];
  const float* attd1  = (const float*)d_in[9];
  const float* bg1    = (const float*)d_in[10];
  const float* basis2 = (const float*)d_in[11];
  const float* comp2  = (const float*)d_in[12];
  const float* root2  = (const float*)d_in[13];
  const float* brg2   = (const float*)d_in[14];
  const float* Wg2    = (const float*)d_in[15];
  const float* atts2  = (const float*)d_in[16];
  const float* attd2  = (const float*)d_in[17];
  const float* bg2    = (const float*)d_in[18];
  float* out = (float*)d_out;

  const int* src = ei;
  const int* dst = ei + NE;

  char* ws = (char*)d_ws;
  size_t off = 0;
  auto alloc = [&](size_t bytes) -> void* {
    void* p = ws + off;
    off = (off + bytes + 255) & ~(size_t)255;
    return p;
  };
  // persistent
  int*   deg     = (int*)alloc((size_t)NN * 4);
  int*   cursor  = (int*)alloc((size_t)NN * 4);
  int*   offs    = (int*)alloc((size_t)(NN + 1) * 4);
  int*   bsum    = (int*)alloc((size_t)256 * 4);
  int*   csr_src = (int*)alloc((size_t)NE * 4);
  int*   csr_et  = (int*)alloc((size_t)NE * 4);
  float* Wcat2   = (float*)alloc((size_t)256 * 320 * 4);
  float* h1      = (float*)alloc((size_t)NN * 64 * 4);
  float* h2      = (float*)alloc((size_t)NN * 256 * 4);
  float* h3      = (float*)alloc((size_t)NN * 64 * 4);
  float* hw2     = (float*)alloc((size_t)NN * 12 * 4);
  float* as1     = (float*)alloc((size_t)NN * 4 * 4);
  float* ad1     = (float*)alloc((size_t)NN * 4 * 4);
  float* as2     = (float*)alloc((size_t)NN * 4 * 4);
  float* ad2     = (float*)alloc((size_t)NN * 4 * 4);
  // scratch union: agg1[NN*128] -> hW1[NN*256] -> xb2[NN*320]
  float* S       = (float*)alloc((size_t)NN * 320 * 4);
  float* agg1    = S;
  float* hW1     = S;
  float* xb2     = S;
  (void)ws_size; (void)n_in; (void)in_sizes; (void)out_size;

  const int BLK = 256;
  int gridN  = (NN + BLK - 1) / BLK;
  int gridE  = (NE + BLK - 1) / BLK;
  int gridW  = (NN + 3) / 4;
  int gridM  = (NN + 63) / 64;          // 469 row tiles

  // CSR build + weight concat
  zero_int_kernel<<<gridN, BLK, 0, stream>>>(deg, NN);
  zero_int_kernel<<<gridN, BLK, 0, stream>>>(cursor, NN);
  count_kernel<<<gridE, BLK, 0, stream>>>(dst, deg, NE);
  wcat2_kernel<<<(256 * 320 + 255) / 256, BLK, 0, stream>>>(basis2, root2, Wcat2);
  scan1_kernel<<<gridN, BLK, 0, stream>>>(deg, offs, bsum);
  scan2_kernel<<<1, BLK, 0, stream>>>(bsum, gridN);
  scan3_kernel<<<gridN, BLK, 0, stream>>>(bsum, offs);
  scatter_kernel<<<gridE, BLK, 0, stream>>>(src, dst, et, offs, cursor, csr_src, csr_et, NE);

  // Layer 1: RGCN (32 -> 64) + elu: agg-first, fused GEMM (basis + root + bias + elu)
  agg1_kernel<<<gridW, BLK, 0, stream>>>(x, comp1, offs, csr_src, csr_et, agg1);
  gemmN_kernel<1, true, false><<<gridM, BLK, 0, stream>>>(
      agg1, 128, 128, basis1, 64,
      x, 32, 32, root1, 64,
      brg1, nullptr, nullptr, h1, 64, nullptr, nullptr, NN);

  // Layer 2: GAT (64 -> 256 concat): linear + fused attention logits, then softmax-agg
  gemmN_kernel<4, false, true><<<gridM, BLK, 0, stream>>>(
      h1, 64, 64, Wg1, 256,
      nullptr, 0, 0, nullptr, 0,
      nullptr, atts1, attd1, hW1, 256, as1, ad1, NN);
  gat1_agg_kernel<<<gridW, BLK, 0, stream>>>(hW1, as1, ad1, bg1, offs, csr_src, h2);

  // Layer 3: RGCN (256 -> 64) + elu: transform-first
  gemmN_kernel<5, false, false><<<gridM, BLK, 0, stream>>>(
      h2, 256, 256, Wcat2, 320,
      nullptr, 0, 0, nullptr, 0,
      nullptr, nullptr, nullptr, xb2, 320, nullptr, nullptr, NN);
  rgcn2_agg_kernel<<<gridW, BLK, 0, stream>>>(xb2, comp2, brg2, offs, csr_src, csr_et, h3);

  // Layer 4: GAT (64 -> 4x3, mean heads) + mean classes + tanh
  gat_lin2_kernel<<<gridW, BLK, 0, stream>>>(h3, Wg2, atts2, attd2, hw2, as2, ad2);
  gat2_final_kernel<<<gridW, BLK, 0, stream>>>(hw2, as2, ad2, bg2, offs, csr_src, out);
}

// Round 9
// 441.556 us; speedup vs baseline: 1.0499x; 1.0499x over previous
//
#include <hip/hip_runtime.h>
#include <cstdint>
#include <cstddef>

#define NN 30000
#define NE 480000

__device__ __forceinline__ float leakyf(float x){ return x > 0.f ? x : 0.2f * x; }
__device__ __forceinline__ float eluf(float x){ return x > 0.f ? x : expm1f(x); }

struct F4 { float x, y, z, w; };

__device__ __forceinline__ F4 ld4(const float* p){
  float4 v = *(const float4*)p;
  return F4{v.x, v.y, v.z, v.w};
}

// ---------------- CSR build ----------------

__global__ void zero_int_kernel(int* __restrict__ p, int n){
  int i = blockIdx.x * blockDim.x + threadIdx.x;
  if (i < n) p[i] = 0;
}

__global__ void count_kernel(const int* __restrict__ dst, int* __restrict__ deg, int E){
  int i = blockIdx.x * blockDim.x + threadIdx.x;
  if (i < E) atomicAdd(&deg[dst[i]], 1);
}

__global__ void scan1_kernel(const int* __restrict__ deg, int* __restrict__ offs,
                             int* __restrict__ bsum){
  __shared__ int sh[256];
  int blk = blockIdx.x, t = threadIdx.x, i = blk * 256 + t;
  int v = (i < NN) ? deg[i] : 0;
  sh[t] = v; __syncthreads();
  for (int o = 1; o < 256; o <<= 1){
    int tv = (t >= o) ? sh[t - o] : 0;
    __syncthreads();
    sh[t] += tv;
    __syncthreads();
  }
  if (i < NN) offs[i + 1] = sh[t];
  if (t == 255) bsum[blk] = sh[255];
}

__global__ void scan2_kernel(int* __restrict__ bsum, int nb){
  __shared__ int sh[256];
  int t = threadIdx.x;
  int v = (t < nb) ? bsum[t] : 0;
  sh[t] = v; __syncthreads();
  for (int o = 1; o < 256; o <<= 1){
    int tv = (t >= o) ? sh[t - o] : 0;
    __syncthreads();
    sh[t] += tv;
    __syncthreads();
  }
  if (t < nb) bsum[t] = sh[t];
}

__global__ void scan3_kernel(const int* __restrict__ bsum, int* __restrict__ offs){
  int i = blockIdx.x * 256 + threadIdx.x;
  if (i == 0) offs[0] = 0;
  if (i < NN){
    int blk = i >> 8;
    int add = blk ? bsum[blk - 1] : 0;
    offs[i + 1] += add;
  }
}

__global__ void scatter_kernel(const int* __restrict__ src, const int* __restrict__ dst,
                               const int* __restrict__ et, const int* __restrict__ offs,
                               int* __restrict__ cursor, int* __restrict__ csr_src,
                               int* __restrict__ csr_et, int E){
  int i = blockIdx.x * blockDim.x + threadIdx.x;
  if (i < E){
    int d = dst[i];
    int pos = offs[d] + atomicAdd(&cursor[d], 1);
    csr_src[pos] = src[i];
    csr_et[pos]  = et[i];
  }
}

// ---------------- weight concat: Wcat2[k][b*64+c] = basis2[b][k][c]; [k][256+c] = root2[k][c] ----

__global__ void wcat2_kernel(const float* __restrict__ basis2, const float* __restrict__ root2,
                             float* __restrict__ Wcat){
  int idx = blockIdx.x * 256 + threadIdx.x;
  if (idx >= 256 * 320) return;
  int k = idx / 320, col = idx - k * 320;
  float v;
  if (col < 256){
    int b = col >> 6, c = col & 63;
    v = basis2[((size_t)b * 256 + k) * 64 + c];
  } else {
    v = root2[(size_t)k * 64 + (col - 256)];
  }
  Wcat[idx] = v;
}

// ---------------- layer-1 basis-space aggregation ----------------

__global__ void agg1_kernel(const float* __restrict__ x, const float* __restrict__ comp,
                            const int* __restrict__ offs, const int* __restrict__ csr_src,
                            const int* __restrict__ csr_et, float* __restrict__ agg){
  int wid  = (blockIdx.x * blockDim.x + threadIdx.x) >> 6;
  int lane = threadIdx.x & 63;
  if (wid >= NN) return;
  int c = lane & 31, half = lane >> 5;
  int n0 = offs[wid], n1 = offs[wid + 1];
  float a0 = 0.f, a1 = 0.f, a2 = 0.f, a3 = 0.f;
  for (int k = n0 + half; k < n1; k += 2){
    int s = csr_src[k], e = csr_et[k];
    float v = x[(size_t)s * 32 + c];
    F4 cp = ld4(comp + (size_t)e * 4);
    a0 += cp.x * v; a1 += cp.y * v; a2 += cp.z * v; a3 += cp.w * v;
  }
  a0 += __shfl_xor(a0, 32);
  a1 += __shfl_xor(a1, 32);
  a2 += __shfl_xor(a2, 32);
  a3 += __shfl_xor(a3, 32);
  int dg = n1 - n0;
  float sc = 1.f / (float)(dg > 0 ? dg : 1);
  if (lane < 32){
    float* ar = agg + (size_t)wid * 128 + c;
    ar[0]  = a0 * sc;
    ar[32] = a1 * sc;
    ar[64] = a2 * sc;
    ar[96] = a3 * sc;
  }
}

// ---------------- 128x64-tile fused GEMM, 8x4 register microtile ----------------
// OUT[n, cg*64+c] = act( A1[n,:]@W1[:,cg*64+c] + A2[n,:]@W2[:,cg*64+c] + bias )
// grid = (ncg, row_tiles); cg on x (fastest) so A-tile is L2-reused by consecutive blocks.
// 256 threads = 16(tc) x 16(tr); thread owns rows tr*8..+7, cols tc*4..+3.
// K-tile 32: per k = 3 x ds_read_b128 + 32 FMA (VALU-bound). LDS 25.6KB.

template<bool ELU, bool ATT>
__global__ __launch_bounds__(256) void gemm128_kernel(
    const float* __restrict__ A1, int lda1, int K1,
    const float* __restrict__ W1, int ldw1,
    const float* __restrict__ A2, int lda2, int K2,
    const float* __restrict__ W2, int ldw2,
    const float* __restrict__ bias,
    const float* __restrict__ atts, const float* __restrict__ attd,
    float* __restrict__ Y, int ldy,
    float* __restrict__ as_, float* __restrict__ ad_,
    int nrows)
{
  __shared__ float At[32][132];
  __shared__ float Wl[32][68];
  int t = threadIdx.x;
  int tc = t & 15, tr = t >> 4;
  int cg = blockIdx.x;
  int nbase = blockIdx.y * 128;
  float acc[8][4];
  #pragma unroll
  for (int j = 0; j < 8; j++)
    #pragma unroll
    for (int i = 0; i < 4; i++) acc[j][i] = 0.f;

  for (int seg = 0; seg < 2; seg++){
    const float* A = seg ? A2 : A1;
    const float* W = seg ? W2 : W1;
    int lda = seg ? lda2 : lda1;
    int ldw = seg ? ldw2 : ldw1;
    int K   = seg ? K2 : K1;
    if (A == nullptr || K <= 0) continue;
    for (int k0 = 0; k0 < K; k0 += 32){
      // stage W tile: Wl[kk][c] = W[k0+kk][cg*64+c]  (512 float4, 2/thread)
      #pragma unroll
      for (int i = 0; i < 2; i++){
        int e = i * 256 + t;
        int kk = e >> 4, c4 = (e & 15) << 2;
        float4 v = make_float4(0.f, 0.f, 0.f, 0.f);
        if (k0 + kk < K) v = *(const float4*)(W + (size_t)(k0 + kk) * ldw + cg * 64 + c4);
        *(float4*)&Wl[kk][c4] = v;
      }
      // stage A transposed: At[kk][r] = A[nbase+r][k0+kk]  (1024 float4, 4/thread)
      #pragma unroll
      for (int i = 0; i < 4; i++){
        int e = i * 256 + t;
        int r = e >> 3, c4 = (e & 7) << 2;
        int n = nbase + r;
        float4 v = make_float4(0.f, 0.f, 0.f, 0.f);
        if (n < nrows && k0 + c4 < K) v = *(const float4*)(A + (size_t)n * lda + k0 + c4);
        At[c4 + 0][r] = v.x;
        At[c4 + 1][r] = v.y;
        At[c4 + 2][r] = v.z;
        At[c4 + 3][r] = v.w;
      }
      __syncthreads();
      #pragma unroll 4
      for (int k = 0; k < 32; k++){
        float4 a0 = *(const float4*)&At[k][tr * 8];
        float4 a1 = *(const float4*)&At[k][tr * 8 + 4];
        float4 wv = *(const float4*)&Wl[k][tc * 4];
        const float* pa0 = (const float*)&a0;
        const float* pa1 = (const float*)&a1;
        const float* pw  = (const float*)&wv;
        #pragma unroll
        for (int j = 0; j < 4; j++)
          #pragma unroll
          for (int i = 0; i < 4; i++){
            acc[j][i]     = fmaf(pa0[j], pw[i], acc[j][i]);
            acc[j + 4][i] = fmaf(pa1[j], pw[i], acc[j + 4][i]);
          }
      }
      __syncthreads();
    }
  }

  // epilogue
  float b0 = 0.f, b1 = 0.f, b2 = 0.f, b3 = 0.f;
  if (bias){
    b0 = bias[cg * 64 + tc * 4 + 0];
    b1 = bias[cg * 64 + tc * 4 + 1];
    b2 = bias[cg * 64 + tc * 4 + 2];
    b3 = bias[cg * 64 + tc * 4 + 3];
  }
  #pragma unroll
  for (int j = 0; j < 8; j++){
    int n = nbase + tr * 8 + j;
    if (n < nrows){
      float y0 = acc[j][0] + b0, y1 = acc[j][1] + b1;
      float y2 = acc[j][2] + b2, y3 = acc[j][3] + b3;
      if (ELU){ y0 = eluf(y0); y1 = eluf(y1); y2 = eluf(y2); y3 = eluf(y3); }
      *(float4*)(Y + (size_t)n * ldy + cg * 64 + tc * 4) = make_float4(y0, y1, y2, y3);
    }
  }
  if (ATT){
    float ta0 = atts[cg * 64 + tc * 4 + 0], ta1 = atts[cg * 64 + tc * 4 + 1];
    float ta2 = atts[cg * 64 + tc * 4 + 2], ta3 = atts[cg * 64 + tc * 4 + 3];
    float tb0 = attd[cg * 64 + tc * 4 + 0], tb1 = attd[cg * 64 + tc * 4 + 1];
    float tb2 = attd[cg * 64 + tc * 4 + 2], tb3 = attd[cg * 64 + tc * 4 + 3];
    #pragma unroll
    for (int j = 0; j < 8; j++){
      float ps = acc[j][0]*ta0 + acc[j][1]*ta1 + acc[j][2]*ta2 + acc[j][3]*ta3;
      float pd = acc[j][0]*tb0 + acc[j][1]*tb1 + acc[j][2]*tb2 + acc[j][3]*tb3;
      #pragma unroll
      for (int o = 8; o; o >>= 1){ ps += __shfl_xor(ps, o); pd += __shfl_xor(pd, o); }
      int n = nbase + tr * 8 + j;
      if (tc == 0 && n < nrows){ as_[n * 4 + cg] = ps; ad_[n * 4 + cg] = pd; }
    }
  }
}

// ---------------- layer-3 aggregate (transform-first) ----------------

__global__ void rgcn2_agg_kernel(const float* __restrict__ xb, const float* __restrict__ comp,
                                 const float* __restrict__ bias, const int* __restrict__ offs,
                                 const int* __restrict__ csr_src, const int* __restrict__ csr_et,
                                 float* __restrict__ h3){
  int wid  = (blockIdx.x * blockDim.x + threadIdx.x) >> 6;
  int lane = threadIdx.x & 63;
  if (wid >= NN) return;
  int b = lane >> 4, q = lane & 15;
  int n0 = offs[wid], n1 = offs[wid + 1];
  float ax = 0.f, ay = 0.f, az = 0.f, aw = 0.f;
  int k = n0;
  for (; k + 1 < n1; k += 2){
    int s0 = csr_src[k],     e0 = csr_et[k];
    int s1 = csr_src[k + 1], e1 = csr_et[k + 1];
    float c0 = comp[e0 * 4 + b];
    float c1 = comp[e1 * 4 + b];
    float4 v0 = *(const float4*)(xb + (size_t)s0 * 320 + lane * 4);
    float4 v1 = *(const float4*)(xb + (size_t)s1 * 320 + lane * 4);
    ax += c0 * v0.x + c1 * v1.x;
    ay += c0 * v0.y + c1 * v1.y;
    az += c0 * v0.z + c1 * v1.z;
    aw += c0 * v0.w + c1 * v1.w;
  }
  if (k < n1){
    int s = csr_src[k], e = csr_et[k];
    float c0 = comp[e * 4 + b];
    float4 v = *(const float4*)(xb + (size_t)s * 320 + lane * 4);
    ax += c0 * v.x; ay += c0 * v.y; az += c0 * v.z; aw += c0 * v.w;
  }
  ax += __shfl_xor(ax, 16); ax += __shfl_xor(ax, 32);
  ay += __shfl_xor(ay, 16); ay += __shfl_xor(ay, 32);
  az += __shfl_xor(az, 16); az += __shfl_xor(az, 32);
  aw += __shfl_xor(aw, 16); aw += __shfl_xor(aw, 32);
  int dg = n1 - n0;
  float sc = 1.f / (float)(dg > 0 ? dg : 1);
  if (lane < 16){
    float4 r  = *(const float4*)(xb + (size_t)wid * 320 + 256 + q * 4);
    float4 bb = *(const float4*)(bias + q * 4);
    float4 o4;
    o4.x = eluf(ax * sc + r.x + bb.x);
    o4.y = eluf(ay * sc + r.y + bb.y);
    o4.z = eluf(az * sc + r.z + bb.z);
    o4.w = eluf(aw * sc + r.w + bb.w);
    *(float4*)(h3 + (size_t)wid * 64 + q * 4) = o4;
  }
}

// ---------------- GAT ----------------

__global__ void gat1_agg_kernel(const float* __restrict__ hw, const float* __restrict__ as_,
                                const float* __restrict__ ad_, const float* __restrict__ bias,
                                const int* __restrict__ offs, const int* __restrict__ csr_src,
                                float* __restrict__ out){
  int wid  = (blockIdx.x * blockDim.x + threadIdx.x) >> 6;
  int lane = threadIdx.x & 63;
  if (wid >= NN) return;
  int n0 = offs[wid], n1 = offs[wid + 1];
  int h    = lane & 3;
  int hseg = lane >> 4;
  float adn = ad_[wid * 4 + h];
  float es  = leakyf(as_[wid * 4 + h] + adn);
  float m = es;
  for (int k = n0 + (lane >> 2); k < n1; k += 16){
    int s = csr_src[k];
    m = fmaxf(m, leakyf(as_[s * 4 + h] + adn));
  }
  #pragma unroll
  for (int o = 4; o < 64; o <<= 1) m = fmaxf(m, __shfl_xor(m, o));
  float den = 0.f;
  float4 acc = make_float4(0.f, 0.f, 0.f, 0.f);
  for (int base = n0; base < n1; base += 16){
    int k = base + (lane >> 2);
    int s = 0; float p = 0.f;
    if (k < n1){
      s = csr_src[k];
      p = expf(leakyf(as_[s * 4 + h] + adn) - m);
    }
    den += p;
    int cnt = min(16, n1 - base);
    for (int jj = 0; jj < cnt; jj++){
      float pj = __shfl(p, (jj << 2) | hseg);
      int  sj  = __shfl(s, (jj << 2));
      float4 v = *(const float4*)(hw + (size_t)sj * 256 + lane * 4);
      acc.x += pj * v.x; acc.y += pj * v.y; acc.z += pj * v.z; acc.w += pj * v.w;
    }
  }
  #pragma unroll
  for (int o = 4; o < 64; o <<= 1) den += __shfl_xor(den, o);
  float ps   = expf(es - m);
  float psh  = __shfl(ps, hseg);
  float denh = __shfl(den, hseg) + psh;
  float4 v = *(const float4*)(hw + (size_t)wid * 256 + lane * 4);
  acc.x += psh * v.x; acc.y += psh * v.y; acc.z += psh * v.z; acc.w += psh * v.w;
  float4 bb = *(const float4*)(bias + lane * 4);
  float4 o4;
  o4.x = eluf(acc.x / denh + bb.x);
  o4.y = eluf(acc.y / denh + bb.y);
  o4.z = eluf(acc.z / denh + bb.z);
  o4.w = eluf(acc.w / denh + bb.w);
  *(float4*)(out + (size_t)wid * 256 + lane * 4) = o4;
}

__global__ void gat_lin2_kernel(const float* __restrict__ h, const float* __restrict__ W,
                                const float* __restrict__ atts, const float* __restrict__ attd,
                                float* __restrict__ hw, float* __restrict__ as_, float* __restrict__ ad_){
  int wid  = (blockIdx.x * blockDim.x + threadIdx.x) >> 6;
  int lane = threadIdx.x & 63;
  if (wid >= NN) return;
  float acc = 0.f;
  if (lane < 12){
    const float* hr = h + (size_t)wid * 64;
    const float* Wc = W + lane;
    #pragma unroll 8
    for (int i = 0; i < 64; i++) acc += hr[i] * Wc[(size_t)i * 12];
    hw[(size_t)wid * 12 + lane] = acc;
  }
  float ts = (lane < 12) ? acc * atts[lane] : 0.f;
  float td = (lane < 12) ? acc * attd[lane] : 0.f;
  int b = (lane < 4) ? lane * 3 : 0;
  float s0 = __shfl(ts, b) + __shfl(ts, b + 1) + __shfl(ts, b + 2);
  float d0 = __shfl(td, b) + __shfl(td, b + 1) + __shfl(td, b + 2);
  if (lane < 4){ as_[wid * 4 + lane] = s0; ad_[wid * 4 + lane] = d0; }
}

__global__ void gat2_final_kernel(const float* __restrict__ hw, const float* __restrict__ as_,
                                  const float* __restrict__ ad_, const float* __restrict__ bg2,
                                  const int* __restrict__ offs, const int* __restrict__ csr_src,
                                  float* __restrict__ out){
  int wid  = (blockIdx.x * blockDim.x + threadIdx.x) >> 6;
  int lane = threadIdx.x & 63;
  if (wid >= NN) return;
  int n0 = offs[wid], n1 = offs[wid + 1];
  F4 adn = ld4(ad_ + (size_t)wid * 4);
  F4 asn = ld4(as_ + (size_t)wid * 4);
  F4 es{leakyf(asn.x + adn.x), leakyf(asn.y + adn.y), leakyf(asn.z + adn.z), leakyf(asn.w + adn.w)};
  F4 m = es;
  for (int k = n0 + lane; k < n1; k += 64){
    int s = csr_src[k];
    F4 a = ld4(as_ + (size_t)s * 4);
    m.x = fmaxf(m.x, leakyf(a.x + adn.x));
    m.y = fmaxf(m.y, leakyf(a.y + adn.y));
    m.z = fmaxf(m.z, leakyf(a.z + adn.z));
    m.w = fmaxf(m.w, leakyf(a.w + adn.w));
  }
  #pragma unroll
  for (int o = 32; o; o >>= 1){
    m.x = fmaxf(m.x, __shfl_xor(m.x, o));
    m.y = fmaxf(m.y, __shfl_xor(m.y, o));
    m.z = fmaxf(m.z, __shfl_xor(m.z, o));
    m.w = fmaxf(m.w, __shfl_xor(m.w, o));
  }
  F4 ps{expf(es.x - m.x), expf(es.y - m.y), expf(es.z - m.z), expf(es.w - m.w)};
  float acc[12];
  #pragma unroll
  for (int j = 0; j < 12; j++) acc[j] = 0.f;
  F4 denp{0.f, 0.f, 0.f, 0.f};
  for (int k = n0 + lane; k < n1; k += 64){
    int s = csr_src[k];
    F4 a = ld4(as_ + (size_t)s * 4);
    F4 p{expf(leakyf(a.x + adn.x) - m.x), expf(leakyf(a.y + adn.y) - m.y),
         expf(leakyf(a.z + adn.z) - m.z), expf(leakyf(a.w + adn.w) - m.w)};
    denp.x += p.x; denp.y += p.y; denp.z += p.z; denp.w += p.w;
    const float* hb = hw + (size_t)s * 12;
    F4 h0 = ld4(hb), h1 = ld4(hb + 4), h2 = ld4(hb + 8);
    acc[0] += p.x * h0.x; acc[1]  += p.x * h0.y; acc[2]  += p.x * h0.z;
    acc[3] += p.y * h0.w; acc[4]  += p.y * h1.x; acc[5]  += p.y * h1.y;
    acc[6] += p.z * h1.z; acc[7]  += p.z * h1.w; acc[8]  += p.z * h2.x;
    acc[9] += p.w * h2.y; acc[10] += p.w * h2.z; acc[11] += p.w * h2.w;
  }
  #pragma unroll
  for (int o = 32; o; o >>= 1){
    denp.x += __shfl_xor(denp.x, o);
    denp.y += __shfl_xor(denp.y, o);
    denp.z += __shfl_xor(denp.z, o);
    denp.w += __shfl_xor(denp.w, o);
    #pragma unroll
    for (int j = 0; j < 12; j++) acc[j] += __shfl_xor(acc[j], o);
  }
  if (lane == 0){
    const float* hn = hw + (size_t)wid * 12;
    float dn[4]  = {denp.x + ps.x, denp.y + ps.y, denp.z + ps.z, denp.w + ps.w};
    float psv[4] = {ps.x, ps.y, ps.z, ps.w};
    float tot = 0.f;
    #pragma unroll
    for (int h_ = 0; h_ < 4; h_++){
      #pragma unroll
      for (int c = 0; c < 3; c++){
        float num = acc[h_ * 3 + c] + psv[h_] * hn[h_ * 3 + c];
        tot += num / dn[h_];
      }
    }
    tot = tot / 12.f + (bg2[0] + bg2[1] + bg2[2]) / 3.f;
    out[wid] = tanhf(tot);
  }
}

// ---------------- launch ----------------

extern "C" void kernel_launch(void* const* d_in, const int* in_sizes, int n_in,
                              void* d_out, int out_size, void* d_ws, size_t ws_size,
                              hipStream_t stream){
  const float* x      = (const float*)d_in[0];
  const int*   ei     = (const int*)d_in[1];
  const int*   et     = (const int*)d_in[2];
  const float* basis1 = (const float*)d_in[3];
  const float* comp1  = (const float*)d_in[4];
  const float* root1  = (const float*)d_in[5];
  const float* brg1   = (const float*)d_in[6];
  const float* Wg1    = (const float*)d_in[7];
  const float* atts1  = (const float*)d_in[8];
  const float* attd1  = (const float*)d_in[9];
  const float* bg1    = (const float*)d_in[10];
  const float* basis2 = (const float*)d_in[11];
  const float* comp2  = (const float*)d_in[12];
  const float* root2  = (const float*)d_in[13];
  const float* brg2   = (const float*)d_in[14];
  const float* Wg2    = (const float*)d_in[15];
  const float* atts2  = (const float*)d_in[16];
  const float* attd2  = (const float*)d_in[17];
  const float* bg2    = (const float*)d_in[18];
  float* out = (float*)d_out;

  const int* src = ei;
  const int* dst = ei + NE;

  char* ws = (char*)d_ws;
  size_t off = 0;
  auto alloc = [&](size_t bytes) -> void* {
    void* p = ws + off;
    off = (off + bytes + 255) & ~(size_t)255;
    return p;
  };
  // persistent
  int*   deg     = (int*)alloc((size_t)NN * 4);
  int*   cursor  = (int*)alloc((size_t)NN * 4);
  int*   offs    = (int*)alloc((size_t)(NN + 1) * 4);
  int*   bsum    = (int*)alloc((size_t)256 * 4);
  int*   csr_src = (int*)alloc((size_t)NE * 4);
  int*   csr_et  = (int*)alloc((size_t)NE * 4);
  float* Wcat2   = (float*)alloc((size_t)256 * 320 * 4);
  float* h1      = (float*)alloc((size_t)NN * 64 * 4);
  float* h2      = (float*)alloc((size_t)NN * 256 * 4);
  float* h3      = (float*)alloc((size_t)NN * 64 * 4);
  float* hw2     = (float*)alloc((size_t)NN * 12 * 4);
  float* as1     = (float*)alloc((size_t)NN * 4 * 4);
  float* ad1     = (float*)alloc((size_t)NN * 4 * 4);
  float* as2     = (float*)alloc((size_t)NN * 4 * 4);
  float* ad2     = (float*)alloc((size_t)NN * 4 * 4);
  // scratch union: agg1[NN*128] -> hW1[NN*256] -> xb2[NN*320]
  float* S       = (float*)alloc((size_t)NN * 320 * 4);
  float* agg1    = S;
  float* hW1     = S;
  float* xb2     = S;
  (void)ws_size; (void)n_in; (void)in_sizes; (void)out_size;

  const int BLK = 256;
  int gridN  = (NN + BLK - 1) / BLK;
  int gridE  = (NE + BLK - 1) / BLK;
  int gridW  = (NN + 3) / 4;
  int gridM  = (NN + 127) / 128;        // 235 row tiles of 128

  // CSR build + weight concat
  zero_int_kernel<<<gridN, BLK, 0, stream>>>(deg, NN);
  zero_int_kernel<<<gridN, BLK, 0, stream>>>(cursor, NN);
  count_kernel<<<gridE, BLK, 0, stream>>>(dst, deg, NE);
  wcat2_kernel<<<(256 * 320 + 255) / 256, BLK, 0, stream>>>(basis2, root2, Wcat2);
  scan1_kernel<<<gridN, BLK, 0, stream>>>(deg, offs, bsum);
  scan2_kernel<<<1, BLK, 0, stream>>>(bsum, gridN);
  scan3_kernel<<<gridN, BLK, 0, stream>>>(bsum, offs);
  scatter_kernel<<<gridE, BLK, 0, stream>>>(src, dst, et, offs, cursor, csr_src, csr_et, NE);

  // Layer 1: RGCN (32 -> 64) + elu: agg-first, fused GEMM (basis + root + bias + elu)
  agg1_kernel<<<gridW, BLK, 0, stream>>>(x, comp1, offs, csr_src, csr_et, agg1);
  gemm128_kernel<true, false><<<dim3(1, gridM), BLK, 0, stream>>>(
      agg1, 128, 128, basis1, 64,
      x, 32, 32, root1, 64,
      brg1, nullptr, nullptr, h1, 64, nullptr, nullptr, NN);

  // Layer 2: GAT (64 -> 256 concat): linear + fused attention logits, then softmax-agg
  gemm128_kernel<false, true><<<dim3(4, gridM), BLK, 0, stream>>>(
      h1, 64, 64, Wg1, 256,
      nullptr, 0, 0, nullptr, 0,
      nullptr, atts1, attd1, hW1, 256, as1, ad1, NN);
  gat1_agg_kernel<<<gridW, BLK, 0, stream>>>(hW1, as1, ad1, bg1, offs, csr_src, h2);

  // Layer 3: RGCN (256 -> 64) + elu: transform-first
  gemm128_kernel<false, false><<<dim3(5, gridM), BLK, 0, stream>>>(
      h2, 256, 256, Wcat2, 320,
      nullptr, 0, 0, nullptr, 0,
      nullptr, nullptr, nullptr, xb2, 320, nullptr, nullptr, NN);
  rgcn2_agg_kernel<<<gridW, BLK, 0, stream>>>(xb2, comp2, brg2, offs, csr_src, csr_et, h3);

  // Layer 4: GAT (64 -> 4x3, mean heads) + mean classes + tanh
  gat_lin2_kernel<<<gridW, BLK, 0, stream>>>(h3, Wg2, atts2, attd2, hw2, as2, ad2);
  gat2_final_kernel<<<gridW, BLK, 0, stream>>>(hw2, as2, ad2, bg2, offs, csr_src, out);
}

// Round 10
// 401.748 us; speedup vs baseline: 1.1539x; 1.0991x over previous
//
#include <hip/hip_runtime.h>
#include <cstdint>
#include <cstddef>

#define NN 30000
#define NE 480000

__device__ __forceinline__ float leakyf(float x){ return x > 0.f ? x : 0.2f * x; }
__device__ __forceinline__ float eluf(float x){ return x > 0.f ? x : expm1f(x); }

__device__ __forceinline__ float bf2f(unsigned short u){
  return __uint_as_float(((unsigned)u) << 16);
}
__device__ __forceinline__ unsigned short f2bf(float f){
  unsigned x = __float_as_uint(f);
  unsigned r = (x + 0x7FFFu + ((x >> 16) & 1u)) >> 16;
  return (unsigned short)r;
}

struct F4 { float x, y, z, w; };

__device__ __forceinline__ F4 ld4(const float* p){
  float4 v = *(const float4*)p;
  return F4{v.x, v.y, v.z, v.w};
}

// ---------------- CSR build ----------------

__global__ void zero_int_kernel(int* __restrict__ p, int n){
  int i = blockIdx.x * blockDim.x + threadIdx.x;
  if (i < n) p[i] = 0;
}

__global__ void count_kernel(const int* __restrict__ dst, int* __restrict__ deg, int E){
  int i = blockIdx.x * blockDim.x + threadIdx.x;
  if (i < E) atomicAdd(&deg[dst[i]], 1);
}

__global__ void scan1_kernel(const int* __restrict__ deg, int* __restrict__ offs,
                             int* __restrict__ bsum){
  __shared__ int sh[256];
  int blk = blockIdx.x, t = threadIdx.x, i = blk * 256 + t;
  int v = (i < NN) ? deg[i] : 0;
  sh[t] = v; __syncthreads();
  for (int o = 1; o < 256; o <<= 1){
    int tv = (t >= o) ? sh[t - o] : 0;
    __syncthreads();
    sh[t] += tv;
    __syncthreads();
  }
  if (i < NN) offs[i + 1] = sh[t];
  if (t == 255) bsum[blk] = sh[255];
}

__global__ void scan2_kernel(int* __restrict__ bsum, int nb){
  __shared__ int sh[256];
  int t = threadIdx.x;
  int v = (t < nb) ? bsum[t] : 0;
  sh[t] = v; __syncthreads();
  for (int o = 1; o < 256; o <<= 1){
    int tv = (t >= o) ? sh[t - o] : 0;
    __syncthreads();
    sh[t] += tv;
    __syncthreads();
  }
  if (t < nb) bsum[t] = sh[t];
}

__global__ void scan3_kernel(const int* __restrict__ bsum, int* __restrict__ offs){
  int i = blockIdx.x * 256 + threadIdx.x;
  if (i == 0) offs[0] = 0;
  if (i < NN){
    int blk = i >> 8;
    int add = blk ? bsum[blk - 1] : 0;
    offs[i + 1] += add;
  }
}

__global__ void scatter_kernel(const int* __restrict__ src, const int* __restrict__ dst,
                               const int* __restrict__ et, const int* __restrict__ offs,
                               int* __restrict__ cursor, int* __restrict__ csr_src,
                               int* __restrict__ csr_et, int E){
  int i = blockIdx.x * blockDim.x + threadIdx.x;
  if (i < E){
    int d = dst[i];
    int pos = offs[d] + atomicAdd(&cursor[d], 1);
    csr_src[pos] = src[i];
    csr_et[pos]  = et[i];
  }
}

// ---------------- weight concat: Wcat2[k][b*64+c] = basis2[b][k][c]; [k][256+c] = root2[k][c] ----

__global__ void wcat2_kernel(const float* __restrict__ basis2, const float* __restrict__ root2,
                             float* __restrict__ Wcat){
  int idx = blockIdx.x * 256 + threadIdx.x;
  if (idx >= 256 * 320) return;
  int k = idx / 320, col = idx - k * 320;
  float v;
  if (col < 256){
    int b = col >> 6, c = col & 63;
    v = basis2[((size_t)b * 256 + k) * 64 + c];
  } else {
    v = root2[(size_t)k * 64 + (col - 256)];
  }
  Wcat[idx] = v;
}

// ---------------- layer-1 basis-space aggregation ----------------

__global__ void agg1_kernel(const float* __restrict__ x, const float* __restrict__ comp,
                            const int* __restrict__ offs, const int* __restrict__ csr_src,
                            const int* __restrict__ csr_et, float* __restrict__ agg){
  int wid  = (blockIdx.x * blockDim.x + threadIdx.x) >> 6;
  int lane = threadIdx.x & 63;
  if (wid >= NN) return;
  int c = lane & 31, half = lane >> 5;
  int n0 = offs[wid], n1 = offs[wid + 1];
  float a0 = 0.f, a1 = 0.f, a2 = 0.f, a3 = 0.f;
  for (int k = n0 + half; k < n1; k += 2){
    int s = csr_src[k], e = csr_et[k];
    float v = x[(size_t)s * 32 + c];
    F4 cp = ld4(comp + (size_t)e * 4);
    a0 += cp.x * v; a1 += cp.y * v; a2 += cp.z * v; a3 += cp.w * v;
  }
  a0 += __shfl_xor(a0, 32);
  a1 += __shfl_xor(a1, 32);
  a2 += __shfl_xor(a2, 32);
  a3 += __shfl_xor(a3, 32);
  int dg = n1 - n0;
  float sc = 1.f / (float)(dg > 0 ? dg : 1);
  if (lane < 32){
    float* ar = agg + (size_t)wid * 128 + c;
    ar[0]  = a0 * sc;
    ar[32] = a1 * sc;
    ar[64] = a2 * sc;
    ar[96] = a3 * sc;
  }
}

// ---------------- (RPT*16)-row x 64-col fused GEMM, RPTx4 register microtile ----------------
// OUT[n, cg*64+c] = act( A1[n,:]@W1[:,cg*64+c] + A2[n,:]@W2[:,cg*64+c] + bias )
// grid = (ncg, row_tiles). 256 threads = 16(tc) x 16(tr); thread owns rows tr*RPT..+RPT-1,
// cols tc*4..+3. K-tile 32.

template<int RPT, bool ELU, bool ATT>
__global__ __launch_bounds__(256) void gemmT_kernel(
    const float* __restrict__ A1, int lda1, int K1,
    const float* __restrict__ W1, int ldw1,
    const float* __restrict__ A2, int lda2, int K2,
    const float* __restrict__ W2, int ldw2,
    const float* __restrict__ bias,
    const float* __restrict__ atts, const float* __restrict__ attd,
    float* __restrict__ Y, int ldy,
    float* __restrict__ as_, float* __restrict__ ad_,
    int nrows)
{
  __shared__ float At[32][RPT * 16 + 4];
  __shared__ float Wl[32][68];
  int t = threadIdx.x;
  int tc = t & 15, tr = t >> 4;
  int cg = blockIdx.x;
  int nbase = blockIdx.y * (RPT * 16);
  float acc[RPT][4];
  #pragma unroll
  for (int j = 0; j < RPT; j++)
    #pragma unroll
    for (int i = 0; i < 4; i++) acc[j][i] = 0.f;

  for (int seg = 0; seg < 2; seg++){
    const float* A = seg ? A2 : A1;
    const float* W = seg ? W2 : W1;
    int lda = seg ? lda2 : lda1;
    int ldw = seg ? ldw2 : ldw1;
    int K   = seg ? K2 : K1;
    if (A == nullptr || K <= 0) continue;
    for (int k0 = 0; k0 < K; k0 += 32){
      // stage W tile: Wl[kk][c] = W[k0+kk][cg*64+c]
      #pragma unroll
      for (int i = 0; i < 2; i++){
        int e = i * 256 + t;
        int kk = e >> 4, c4 = (e & 15) << 2;
        float4 v = make_float4(0.f, 0.f, 0.f, 0.f);
        if (k0 + kk < K) v = *(const float4*)(W + (size_t)(k0 + kk) * ldw + cg * 64 + c4);
        *(float4*)&Wl[kk][c4] = v;
      }
      // stage A transposed: At[kk][r] = A[nbase+r][k0+kk]
      #pragma unroll
      for (int i = 0; i < RPT / 2; i++){
        int e = i * 256 + t;
        int r = e >> 3, c4 = (e & 7) << 2;
        int n = nbase + r;
        float4 v = make_float4(0.f, 0.f, 0.f, 0.f);
        if (n < nrows && k0 + c4 < K) v = *(const float4*)(A + (size_t)n * lda + k0 + c4);
        At[c4 + 0][r] = v.x;
        At[c4 + 1][r] = v.y;
        At[c4 + 2][r] = v.z;
        At[c4 + 3][r] = v.w;
      }
      __syncthreads();
      #pragma unroll 4
      for (int k = 0; k < 32; k++){
        float4 wv = *(const float4*)&Wl[k][tc * 4];
        const float* pw = (const float*)&wv;
        #pragma unroll
        for (int jj = 0; jj < RPT / 4; jj++){
          float4 av = *(const float4*)&At[k][tr * RPT + jj * 4];
          const float* pa = (const float*)&av;
          #pragma unroll
          for (int j = 0; j < 4; j++)
            #pragma unroll
            for (int i = 0; i < 4; i++)
              acc[jj * 4 + j][i] = fmaf(pa[j], pw[i], acc[jj * 4 + j][i]);
        }
      }
      __syncthreads();
    }
  }

  // epilogue
  float b0 = 0.f, b1 = 0.f, b2 = 0.f, b3 = 0.f;
  if (bias){
    b0 = bias[cg * 64 + tc * 4 + 0];
    b1 = bias[cg * 64 + tc * 4 + 1];
    b2 = bias[cg * 64 + tc * 4 + 2];
    b3 = bias[cg * 64 + tc * 4 + 3];
  }
  #pragma unroll
  for (int j = 0; j < RPT; j++){
    int n = nbase + tr * RPT + j;
    if (n < nrows){
      float y0 = acc[j][0] + b0, y1 = acc[j][1] + b1;
      float y2 = acc[j][2] + b2, y3 = acc[j][3] + b3;
      if (ELU){ y0 = eluf(y0); y1 = eluf(y1); y2 = eluf(y2); y3 = eluf(y3); }
      *(float4*)(Y + (size_t)n * ldy + cg * 64 + tc * 4) = make_float4(y0, y1, y2, y3);
    }
  }
  if (ATT){
    float ta0 = atts[cg * 64 + tc * 4 + 0], ta1 = atts[cg * 64 + tc * 4 + 1];
    float ta2 = atts[cg * 64 + tc * 4 + 2], ta3 = atts[cg * 64 + tc * 4 + 3];
    float tb0 = attd[cg * 64 + tc * 4 + 0], tb1 = attd[cg * 64 + tc * 4 + 1];
    float tb2 = attd[cg * 64 + tc * 4 + 2], tb3 = attd[cg * 64 + tc * 4 + 3];
    #pragma unroll
    for (int j = 0; j < RPT; j++){
      float ps = acc[j][0]*ta0 + acc[j][1]*ta1 + acc[j][2]*ta2 + acc[j][3]*ta3;
      float pd = acc[j][0]*tb0 + acc[j][1]*tb1 + acc[j][2]*tb2 + acc[j][3]*tb3;
      #pragma unroll
      for (int o = 8; o; o >>= 1){ ps += __shfl_xor(ps, o); pd += __shfl_xor(pd, o); }
      int n = nbase + tr * RPT + j;
      if (tc == 0 && n < nrows){ as_[n * 4 + cg] = ps; ad_[n * 4 + cg] = pd; }
    }
  }
}

// ---------------- layer-3: per-relation message table (bf16) ----------------
// xr[n, r, o] = sum_b comp2[r,b] * xb2[n, b*64+o]  -> bf16
// thread = (n, q): reads 4 x float4 of xb2, writes 8 x ushort4.

__global__ void xr_kernel(const float* __restrict__ xb2, const float* __restrict__ comp2,
                          unsigned short* __restrict__ xr){
  int idx = blockIdx.x * 256 + threadIdx.x;
  if (idx >= NN * 16) return;
  int n = idx >> 4, q = idx & 15;
  float4 xv[4];
  #pragma unroll
  for (int b = 0; b < 4; b++)
    xv[b] = *(const float4*)(xb2 + (size_t)n * 320 + b * 64 + q * 4);
  #pragma unroll
  for (int r = 0; r < 8; r++){
    float c0 = comp2[r * 4 + 0], c1 = comp2[r * 4 + 1];
    float c2 = comp2[r * 4 + 2], c3 = comp2[r * 4 + 3];
    float m0 = c0 * xv[0].x + c1 * xv[1].x + c2 * xv[2].x + c3 * xv[3].x;
    float m1 = c0 * xv[0].y + c1 * xv[1].y + c2 * xv[2].y + c3 * xv[3].y;
    float m2 = c0 * xv[0].z + c1 * xv[1].z + c2 * xv[2].z + c3 * xv[3].z;
    float m3 = c0 * xv[0].w + c1 * xv[1].w + c2 * xv[2].w + c3 * xv[3].w;
    ushort4 u;
    u.x = f2bf(m0); u.y = f2bf(m1); u.z = f2bf(m2); u.w = f2bf(m3);
    *(ushort4*)(xr + ((size_t)n * 8 + r) * 64 + q * 4) = u;
  }
}

// ---------------- layer-3 aggregate: mean of xr[src, et, :] + root + bias, elu ----------------
// wave per node; 4 edge-groups x 16 lanes; lane reads ushort4 (8B) of the 64-wide message.

__global__ void rgcn2_agg_kernel(const unsigned short* __restrict__ xr,
                                 const float* __restrict__ xb,
                                 const float* __restrict__ bias, const int* __restrict__ offs,
                                 const int* __restrict__ csr_src, const int* __restrict__ csr_et,
                                 float* __restrict__ h3){
  int wid  = (blockIdx.x * blockDim.x + threadIdx.x) >> 6;
  int lane = threadIdx.x & 63;
  if (wid >= NN) return;
  int eg = lane >> 4, q = lane & 15;
  int n0 = offs[wid], n1 = offs[wid + 1];
  float a0 = 0.f, a1 = 0.f, a2 = 0.f, a3 = 0.f;
  for (int k = n0 + eg; k < n1; k += 4){
    int s = csr_src[k], e = csr_et[k];
    ushort4 u = *(const ushort4*)(xr + ((size_t)s * 8 + e) * 64 + q * 4);
    a0 += bf2f(u.x); a1 += bf2f(u.y); a2 += bf2f(u.z); a3 += bf2f(u.w);
  }
  a0 += __shfl_xor(a0, 16); a0 += __shfl_xor(a0, 32);
  a1 += __shfl_xor(a1, 16); a1 += __shfl_xor(a1, 32);
  a2 += __shfl_xor(a2, 16); a2 += __shfl_xor(a2, 32);
  a3 += __shfl_xor(a3, 16); a3 += __shfl_xor(a3, 32);
  int dg = n1 - n0;
  float sc = 1.f / (float)(dg > 0 ? dg : 1);
  if (lane < 16){
    float4 r  = *(const float4*)(xb + (size_t)wid * 320 + 256 + q * 4);
    float4 bb = *(const float4*)(bias + q * 4);
    float4 o4;
    o4.x = eluf(a0 * sc + r.x + bb.x);
    o4.y = eluf(a1 * sc + r.y + bb.y);
    o4.z = eluf(a2 * sc + r.z + bb.z);
    o4.w = eluf(a3 * sc + r.w + bb.w);
    *(float4*)(h3 + (size_t)wid * 64 + q * 4) = o4;
  }
}

// ---------------- GAT ----------------

__global__ void gat1_agg_kernel(const float* __restrict__ hw, const float* __restrict__ as_,
                                const float* __restrict__ ad_, const float* __restrict__ bias,
                                const int* __restrict__ offs, const int* __restrict__ csr_src,
                                float* __restrict__ out){
  int wid  = (blockIdx.x * blockDim.x + threadIdx.x) >> 6;
  int lane = threadIdx.x & 63;
  if (wid >= NN) return;
  int n0 = offs[wid], n1 = offs[wid + 1];
  int h    = lane & 3;
  int hseg = lane >> 4;
  float adn = ad_[wid * 4 + h];
  float es  = leakyf(as_[wid * 4 + h] + adn);
  float m = es;
  for (int k = n0 + (lane >> 2); k < n1; k += 16){
    int s = csr_src[k];
    m = fmaxf(m, leakyf(as_[s * 4 + h] + adn));
  }
  #pragma unroll
  for (int o = 4; o < 64; o <<= 1) m = fmaxf(m, __shfl_xor(m, o));
  float den = 0.f;
  float4 acc = make_float4(0.f, 0.f, 0.f, 0.f);
  for (int base = n0; base < n1; base += 16){
    int k = base + (lane >> 2);
    int s = 0; float p = 0.f;
    if (k < n1){
      s = csr_src[k];
      p = expf(leakyf(as_[s * 4 + h] + adn) - m);
    }
    den += p;
    int cnt = min(16, n1 - base);
    for (int jj = 0; jj < cnt; jj++){
      float pj = __shfl(p, (jj << 2) | hseg);
      int  sj  = __shfl(s, (jj << 2));
      float4 v = *(const float4*)(hw + (size_t)sj * 256 + lane * 4);
      acc.x += pj * v.x; acc.y += pj * v.y; acc.z += pj * v.z; acc.w += pj * v.w;
    }
  }
  #pragma unroll
  for (int o = 4; o < 64; o <<= 1) den += __shfl_xor(den, o);
  float ps   = expf(es - m);
  float psh  = __shfl(ps, hseg);
  float denh = __shfl(den, hseg) + psh;
  float4 v = *(const float4*)(hw + (size_t)wid * 256 + lane * 4);
  acc.x += psh * v.x; acc.y += psh * v.y; acc.z += psh * v.z; acc.w += psh * v.w;
  float4 bb = *(const float4*)(bias + lane * 4);
  float4 o4;
  o4.x = eluf(acc.x / denh + bb.x);
  o4.y = eluf(acc.y / denh + bb.y);
  o4.z = eluf(acc.z / denh + bb.z);
  o4.w = eluf(acc.w / denh + bb.w);
  *(float4*)(out + (size_t)wid * 256 + lane * 4) = o4;
}

__global__ void gat_lin2_kernel(const float* __restrict__ h, const float* __restrict__ W,
                                const float* __restrict__ atts, const float* __restrict__ attd,
                                float* __restrict__ hw, float* __restrict__ as_, float* __restrict__ ad_){
  int wid  = (blockIdx.x * blockDim.x + threadIdx.x) >> 6;
  int lane = threadIdx.x & 63;
  if (wid >= NN) return;
  float acc = 0.f;
  if (lane < 12){
    const float* hr = h + (size_t)wid * 64;
    const float* Wc = W + lane;
    #pragma unroll 8
    for (int i = 0; i < 64; i++) acc += hr[i] * Wc[(size_t)i * 12];
    hw[(size_t)wid * 12 + lane] = acc;
  }
  float ts = (lane < 12) ? acc * atts[lane] : 0.f;
  float td = (lane < 12) ? acc * attd[lane] : 0.f;
  int b = (lane < 4) ? lane * 3 : 0;
  float s0 = __shfl(ts, b) + __shfl(ts, b + 1) + __shfl(ts, b + 2);
  float d0 = __shfl(td, b) + __shfl(td, b + 1) + __shfl(td, b + 2);
  if (lane < 4){ as_[wid * 4 + lane] = s0; ad_[wid * 4 + lane] = d0; }
}

__global__ void gat2_final_kernel(const float* __restrict__ hw, const float* __restrict__ as_,
                                  const float* __restrict__ ad_, const float* __restrict__ bg2,
                                  const int* __restrict__ offs, const int* __restrict__ csr_src,
                                  float* __restrict__ out){
  int wid  = (blockIdx.x * blockDim.x + threadIdx.x) >> 6;
  int lane = threadIdx.x & 63;
  if (wid >= NN) return;
  int n0 = offs[wid], n1 = offs[wid + 1];
  F4 adn = ld4(ad_ + (size_t)wid * 4);
  F4 asn = ld4(as_ + (size_t)wid * 4);
  F4 es{leakyf(asn.x + adn.x), leakyf(asn.y + adn.y), leakyf(asn.z + adn.z), leakyf(asn.w + adn.w)};
  F4 m = es;
  for (int k = n0 + lane; k < n1; k += 64){
    int s = csr_src[k];
    F4 a = ld4(as_ + (size_t)s * 4);
    m.x = fmaxf(m.x, leakyf(a.x + adn.x));
    m.y = fmaxf(m.y, leakyf(a.y + adn.y));
    m.z = fmaxf(m.z, leakyf(a.z + adn.z));
    m.w = fmaxf(m.w, leakyf(a.w + adn.w));
  }
  #pragma unroll
  for (int o = 32; o; o >>= 1){
    m.x = fmaxf(m.x, __shfl_xor(m.x, o));
    m.y = fmaxf(m.y, __shfl_xor(m.y, o));
    m.z = fmaxf(m.z, __shfl_xor(m.z, o));
    m.w = fmaxf(m.w, __shfl_xor(m.w, o));
  }
  F4 ps{expf(es.x - m.x), expf(es.y - m.y), expf(es.z - m.z), expf(es.w - m.w)};
  float acc[12];
  #pragma unroll
  for (int j = 0; j < 12; j++) acc[j] = 0.f;
  F4 denp{0.f, 0.f, 0.f, 0.f};
  for (int k = n0 + lane; k < n1; k += 64){
    int s = csr_src[k];
    F4 a = ld4(as_ + (size_t)s * 4);
    F4 p{expf(leakyf(a.x + adn.x) - m.x), expf(leakyf(a.y + adn.y) - m.y),
         expf(leakyf(a.z + adn.z) - m.z), expf(leakyf(a.w + adn.w) - m.w)};
    denp.x += p.x; denp.y += p.y; denp.z += p.z; denp.w += p.w;
    const float* hb = hw + (size_t)s * 12;
    F4 h0 = ld4(hb), h1 = ld4(hb + 4), h2 = ld4(hb + 8);
    acc[0] += p.x * h0.x; acc[1]  += p.x * h0.y; acc[2]  += p.x * h0.z;
    acc[3] += p.y * h0.w; acc[4]  += p.y * h1.x; acc[5]  += p.y * h1.y;
    acc[6] += p.z * h1.z; acc[7]  += p.z * h1.w; acc[8]  += p.z * h2.x;
    acc[9] += p.w * h2.y; acc[10] += p.w * h2.z; acc[11] += p.w * h2.w;
  }
  #pragma unroll
  for (int o = 32; o; o >>= 1){
    denp.x += __shfl_xor(denp.x, o);
    denp.y += __shfl_xor(denp.y, o);
    denp.z += __shfl_xor(denp.z, o);
    denp.w += __shfl_xor(denp.w, o);
    #pragma unroll
    for (int j = 0; j < 12; j++) acc[j] += __shfl_xor(acc[j], o);
  }
  if (lane == 0){
    const float* hn = hw + (size_t)wid * 12;
    float dn[4]  = {denp.x + ps.x, denp.y + ps.y, denp.z + ps.z, denp.w + ps.w};
    float psv[4] = {ps.x, ps.y, ps.z, ps.w};
    float tot = 0.f;
    #pragma unroll
    for (int h_ = 0; h_ < 4; h_++){
      #pragma unroll
      for (int c = 0; c < 3; c++){
        float num = acc[h_ * 3 + c] + psv[h_] * hn[h_ * 3 + c];
        tot += num / dn[h_];
      }
    }
    tot = tot / 12.f + (bg2[0] + bg2[1] + bg2[2]) / 3.f;
    out[wid] = tanhf(tot);
  }
}

// ---------------- launch ----------------

extern "C" void kernel_launch(void* const* d_in, const int* in_sizes, int n_in,
                              void* d_out, int out_size, void* d_ws, size_t ws_size,
                              hipStream_t stream){
  const float* x      = (const float*)d_in[0];
  const int*   ei     = (const int*)d_in[1];
  const int*   et     = (const int*)d_in[2];
  const float* basis1 = (const float*)d_in[3];
  const float* comp1  = (const float*)d_in[4];
  const float* root1  = (const float*)d_in[5];
  const float* brg1   = (const float*)d_in[6];
  const float* Wg1    = (const float*)d_in[7];
  const float* atts1  = (const float*)d_in[8];
  const float* attd1  = (const float*)d_in[9];
  const float* bg1    = (const float*)d_in[10];
  const float* basis2 = (const float*)d_in[11];
  const float* comp2  = (const float*)d_in[12];
  const float* root2  = (const float*)d_in[13];
  const float* brg2   = (const float*)d_in[14];
  const float* Wg2    = (const float*)d_in[15];
  const float* atts2  = (const float*)d_in[16];
  const float* attd2  = (const float*)d_in[17];
  const float* bg2    = (const float*)d_in[18];
  float* out = (float*)d_out;

  const int* src = ei;
  const int* dst = ei + NE;

  char* ws = (char*)d_ws;
  size_t off = 0;
  auto alloc = [&](size_t bytes) -> void* {
    void* p = ws + off;
    off = (off + bytes + 255) & ~(size_t)255;
    return p;
  };
  // persistent
  int*   deg     = (int*)alloc((size_t)NN * 4);
  int*   cursor  = (int*)alloc((size_t)NN * 4);
  int*   offs    = (int*)alloc((size_t)(NN + 1) * 4);
  int*   bsum    = (int*)alloc((size_t)256 * 4);
  int*   csr_src = (int*)alloc((size_t)NE * 4);
  int*   csr_et  = (int*)alloc((size_t)NE * 4);
  float* Wcat2   = (float*)alloc((size_t)256 * 320 * 4);
  float* h1      = (float*)alloc((size_t)NN * 64 * 4);
  float* h2      = (float*)alloc((size_t)NN * 256 * 4);
  float* h3      = (float*)alloc((size_t)NN * 64 * 4);
  float* hw2     = (float*)alloc((size_t)NN * 12 * 4);
  float* as1     = (float*)alloc((size_t)NN * 4 * 4);
  float* ad1     = (float*)alloc((size_t)NN * 4 * 4);
  float* as2     = (float*)alloc((size_t)NN * 4 * 4);
  float* ad2     = (float*)alloc((size_t)NN * 4 * 4);
  // scratch union: agg1[NN*128] -> hW1[NN*256] -> xb2[NN*320]
  float* S       = (float*)alloc((size_t)NN * 320 * 4);
  float* agg1    = S;
  float* hW1     = S;
  float* xb2     = S;
  // xr (bf16, NN*512 = 30.7MB) aliases h1+h2 (38.4MB): h1 dead after GAT1 gemm,
  // h2 dead after L3 gemm; xr written after L3 gemm, read before h3-dependents.
  unsigned short* xr = (unsigned short*)h1;
  (void)ws_size; (void)n_in; (void)in_sizes; (void)out_size;

  const int BLK = 256;
  int gridN   = (NN + BLK - 1) / BLK;
  int gridE   = (NE + BLK - 1) / BLK;
  int gridW   = (NN + 3) / 4;
  int gridM64 = (NN + 63) / 64;     // 469
  int gridM128= (NN + 127) / 128;   // 235

  // CSR build + weight concat
  zero_int_kernel<<<gridN, BLK, 0, stream>>>(deg, NN);
  zero_int_kernel<<<gridN, BLK, 0, stream>>>(cursor, NN);
  count_kernel<<<gridE, BLK, 0, stream>>>(dst, deg, NE);
  wcat2_kernel<<<(256 * 320 + 255) / 256, BLK, 0, stream>>>(basis2, root2, Wcat2);
  scan1_kernel<<<gridN, BLK, 0, stream>>>(deg, offs, bsum);
  scan2_kernel<<<1, BLK, 0, stream>>>(bsum, gridN);
  scan3_kernel<<<gridN, BLK, 0, stream>>>(bsum, offs);
  scatter_kernel<<<gridE, BLK, 0, stream>>>(src, dst, et, offs, cursor, csr_src, csr_et, NE);

  // Layer 1: RGCN (32 -> 64) + elu: agg-first, fused GEMM (basis + root + bias + elu)
  agg1_kernel<<<gridW, BLK, 0, stream>>>(x, comp1, offs, csr_src, csr_et, agg1);
  gemmT_kernel<4, true, false><<<dim3(1, gridM64), BLK, 0, stream>>>(
      agg1, 128, 128, basis1, 64,
      x, 32, 32, root1, 64,
      brg1, nullptr, nullptr, h1, 64, nullptr, nullptr, NN);

  // Layer 2: GAT (64 -> 256 concat): linear + fused attention logits, then softmax-agg
  gemmT_kernel<4, false, true><<<dim3(4, gridM64), BLK, 0, stream>>>(
      h1, 64, 64, Wg1, 256,
      nullptr, 0, 0, nullptr, 0,
      nullptr, atts1, attd1, hW1, 256, as1, ad1, NN);
  gat1_agg_kernel<<<gridW, BLK, 0, stream>>>(hW1, as1, ad1, bg1, offs, csr_src, h2);

  // Layer 3: RGCN (256 -> 64) + elu: transform-first + bf16 per-relation message table
  gemmT_kernel<8, false, false><<<dim3(5, gridM128), BLK, 0, stream>>>(
      h2, 256, 256, Wcat2, 320,
      nullptr, 0, 0, nullptr, 0,
      nullptr, nullptr, nullptr, xb2, 320, nullptr, nullptr, NN);
  xr_kernel<<<(NN * 16 + 255) / 256, BLK, 0, stream>>>(xb2, comp2, xr);
  rgcn2_agg_kernel<<<gridW, BLK, 0, stream>>>(xr, xb2, brg2, offs, csr_src, csr_et, h3);

  // Layer 4: GAT (64 -> 4x3, mean heads) + mean classes + tanh
  gat_lin2_kernel<<<gridW, BLK, 0, stream>>>(h3, Wg2, atts2, attd2, hw2, as2, ad2);
  gat2_final_kernel<<<gridW, BLK, 0, stream>>>(hw2, as2, ad2, bg2, offs, csr_src, out);
}

// Round 12
// 389.096 us; speedup vs baseline: 1.1915x; 1.0325x over previous
//
#include <hip/hip_runtime.h>
#include <cstdint>
#include <cstddef>

#define NN 30000
#define NE 480000

__device__ __forceinline__ float leakyf(float x){ return x > 0.f ? x : 0.2f * x; }
__device__ __forceinline__ float eluf(float x){ return x > 0.f ? x : expm1f(x); }

__device__ __forceinline__ float bf2f(unsigned short u){
  return __uint_as_float(((unsigned)u) << 16);
}
__device__ __forceinline__ unsigned short f2bf(float f){
  unsigned x = __float_as_uint(f);
  unsigned r = (x + 0x7FFFu + ((x >> 16) & 1u)) >> 16;
  return (unsigned short)r;
}

struct F4 { float x, y, z, w; };

__device__ __forceinline__ F4 ld4(const float* p){
  float4 v = *(const float4*)p;
  return F4{v.x, v.y, v.z, v.w};
}

// ---------------- CSR build ----------------

__global__ void zero_int_kernel(int* __restrict__ p, int n){
  int i = blockIdx.x * blockDim.x + threadIdx.x;
  if (i < n) p[i] = 0;
}

__global__ void count_kernel(const int* __restrict__ dst, int* __restrict__ deg, int E){
  int i = blockIdx.x * blockDim.x + threadIdx.x;
  if (i < E) atomicAdd(&deg[dst[i]], 1);
}

__global__ void scan1_kernel(const int* __restrict__ deg, int* __restrict__ offs,
                             int* __restrict__ bsum){
  __shared__ int sh[256];
  int blk = blockIdx.x, t = threadIdx.x, i = blk * 256 + t;
  int v = (i < NN) ? deg[i] : 0;
  sh[t] = v; __syncthreads();
  for (int o = 1; o < 256; o <<= 1){
    int tv = (t >= o) ? sh[t - o] : 0;
    __syncthreads();
    sh[t] += tv;
    __syncthreads();
  }
  if (i < NN) offs[i + 1] = sh[t];
  if (t == 255) bsum[blk] = sh[255];
}

__global__ void scan2_kernel(int* __restrict__ bsum, int nb){
  __shared__ int sh[256];
  int t = threadIdx.x;
  int v = (t < nb) ? bsum[t] : 0;
  sh[t] = v; __syncthreads();
  for (int o = 1; o < 256; o <<= 1){
    int tv = (t >= o) ? sh[t - o] : 0;
    __syncthreads();
    sh[t] += tv;
    __syncthreads();
  }
  if (t < nb) bsum[t] = sh[t];
}

__global__ void scan3_kernel(const int* __restrict__ bsum, int* __restrict__ offs){
  int i = blockIdx.x * 256 + threadIdx.x;
  if (i == 0) offs[0] = 0;
  if (i < NN){
    int blk = i >> 8;
    int add = blk ? bsum[blk - 1] : 0;
    offs[i + 1] += add;
  }
}

__global__ void scatter_kernel(const int* __restrict__ src, const int* __restrict__ dst,
                               const int* __restrict__ et, const int* __restrict__ offs,
                               int* __restrict__ cursor, int* __restrict__ csr_src,
                               int* __restrict__ csr_et, int E){
  int i = blockIdx.x * blockDim.x + threadIdx.x;
  if (i < E){
    int d = dst[i];
    int pos = offs[d] + atomicAdd(&cursor[d], 1);
    csr_src[pos] = src[i];
    csr_et[pos]  = et[i];
  }
}

// ---------------- weight prep ----------------
// Wcat2 [256][384]: cols 0..255 = basis2 (4 bases x 64), 256..319 = root2, 320..383 = 0.

__global__ void wcat2_kernel(const float* __restrict__ basis2, const float* __restrict__ root2,
                             float* __restrict__ Wcat){
  int idx = blockIdx.x * 256 + threadIdx.x;
  if (idx >= 256 * 384) return;
  int k = idx / 384, col = idx - k * 384;
  float v = 0.f;
  if (col < 256){
    int b = col >> 6, c = col & 63;
    v = basis2[((size_t)b * 256 + k) * 64 + c];
  } else if (col < 320){
    v = root2[(size_t)k * 64 + (col - 256)];
  }
  Wcat[idx] = v;
}

// wa_s[k*4+h] = sum_c Wg1[k, h*64+c] * atts1[h,c]  (and wa_d with attd1)
__global__ void wa_kernel(const float* __restrict__ Wg1, const float* __restrict__ atts1,
                          const float* __restrict__ attd1, float* __restrict__ wa_s,
                          float* __restrict__ wa_d){
  int t = threadIdx.x;
  int k = t >> 2, h = t & 3;
  float s = 0.f, d = 0.f;
  const float* wr = Wg1 + (size_t)k * 256 + h * 64;
  const float* pa = atts1 + h * 64;
  const float* pb = attd1 + h * 64;
  #pragma unroll 8
  for (int c = 0; c < 64; c++){ s += wr[c] * pa[c]; d += wr[c] * pb[c]; }
  wa_s[k * 4 + h] = s;
  wa_d[k * 4 + h] = d;
}

// as1[n,h] = h1[n,:] . wa_s[:,h]
__global__ void logits_kernel(const float* __restrict__ h1, const float* __restrict__ wa_s,
                              const float* __restrict__ wa_d, float* __restrict__ as_,
                              float* __restrict__ ad_){
  __shared__ float ws[256], wd[256];
  int t = threadIdx.x;
  ws[t] = wa_s[t];
  wd[t] = wa_d[t];
  __syncthreads();
  int idx = blockIdx.x * 256 + t;
  int n = idx >> 2, h = idx & 3;
  if (n >= NN) return;
  float s = 0.f, d = 0.f;
  const float* hr = h1 + (size_t)n * 64;
  #pragma unroll 4
  for (int k4 = 0; k4 < 16; k4++){
    float4 hv = *(const float4*)(hr + k4 * 4);
    s += hv.x * ws[(k4*4+0)*4+h] + hv.y * ws[(k4*4+1)*4+h]
       + hv.z * ws[(k4*4+2)*4+h] + hv.w * ws[(k4*4+3)*4+h];
    d += hv.x * wd[(k4*4+0)*4+h] + hv.y * wd[(k4*4+1)*4+h]
       + hv.z * wd[(k4*4+2)*4+h] + hv.w * wd[(k4*4+3)*4+h];
  }
  as_[n * 4 + h] = s;
  ad_[n * 4 + h] = d;
}

// ---------------- layer-1 basis-space aggregation ----------------

__global__ void agg1_kernel(const float* __restrict__ x, const float* __restrict__ comp,
                            const int* __restrict__ offs, const int* __restrict__ csr_src,
                            const int* __restrict__ csr_et, float* __restrict__ agg){
  int wid  = (blockIdx.x * blockDim.x + threadIdx.x) >> 6;
  int lane = threadIdx.x & 63;
  if (wid >= NN) return;
  int c = lane & 31, half = lane >> 5;
  int n0 = offs[wid], n1 = offs[wid + 1];
  float a0 = 0.f, a1 = 0.f, a2 = 0.f, a3 = 0.f;
  for (int k = n0 + half; k < n1; k += 2){
    int s = csr_src[k], e = csr_et[k];
    float v = x[(size_t)s * 32 + c];
    F4 cp = ld4(comp + (size_t)e * 4);
    a0 += cp.x * v; a1 += cp.y * v; a2 += cp.z * v; a3 += cp.w * v;
  }
  a0 += __shfl_xor(a0, 32);
  a1 += __shfl_xor(a1, 32);
  a2 += __shfl_xor(a2, 32);
  a3 += __shfl_xor(a3, 32);
  int dg = n1 - n0;
  float sc = 1.f / (float)(dg > 0 ? dg : 1);
  if (lane < 32){
    float* ar = agg + (size_t)wid * 128 + c;
    ar[0]  = a0 * sc;
    ar[32] = a1 * sc;
    ar[64] = a2 * sc;
    ar[96] = a3 * sc;
  }
}

// ---------------- (RPT*16)-row x 64-col fused GEMM, per-cg offsets ----------------

template<int RPT, bool ELU>
__global__ __launch_bounds__(256) void gemmT_kernel(
    const float* __restrict__ A1, int lda1, int K1,
    const float* __restrict__ W1, int ldw1,
    const float* __restrict__ A2, int lda2, int K2,
    const float* __restrict__ W2, int ldw2,
    const float* __restrict__ bias,
    float* __restrict__ Y, int ldy,
    int nrows, int acgoff, int wcgoff)
{
  __shared__ float At[32][RPT * 16 + 4];
  __shared__ float Wl[32][68];
  int t = threadIdx.x;
  int tc = t & 15, tr = t >> 4;
  int cg = blockIdx.x;
  int nbase = blockIdx.y * (RPT * 16);
  float acc[RPT][4];
  #pragma unroll
  for (int j = 0; j < RPT; j++)
    #pragma unroll
    for (int i = 0; i < 4; i++) acc[j][i] = 0.f;

  for (int seg = 0; seg < 2; seg++){
    const float* A = seg ? A2 : A1;
    const float* W = seg ? W2 : W1;
    int lda = seg ? lda2 : lda1;
    int ldw = seg ? ldw2 : ldw1;
    int K   = seg ? K2 : K1;
    if (A == nullptr || K <= 0) continue;
    A += (size_t)cg * acgoff;
    W += (size_t)cg * wcgoff;
    for (int k0 = 0; k0 < K; k0 += 32){
      #pragma unroll
      for (int i = 0; i < 2; i++){
        int e = i * 256 + t;
        int kk = e >> 4, c4 = (e & 15) << 2;
        float4 v = make_float4(0.f, 0.f, 0.f, 0.f);
        if (k0 + kk < K) v = *(const float4*)(W + (size_t)(k0 + kk) * ldw + c4);
        *(float4*)&Wl[kk][c4] = v;
      }
      #pragma unroll
      for (int i = 0; i < RPT / 2; i++){
        int e = i * 256 + t;
        int r = e >> 3, c4 = (e & 7) << 2;
        int n = nbase + r;
        float4 v = make_float4(0.f, 0.f, 0.f, 0.f);
        if (n < nrows && k0 + c4 < K) v = *(const float4*)(A + (size_t)n * lda + k0 + c4);
        At[c4 + 0][r] = v.x;
        At[c4 + 1][r] = v.y;
        At[c4 + 2][r] = v.z;
        At[c4 + 3][r] = v.w;
      }
      __syncthreads();
      #pragma unroll 4
      for (int k = 0; k < 32; k++){
        float4 wv = *(const float4*)&Wl[k][tc * 4];
        const float* pw = (const float*)&wv;
        #pragma unroll
        for (int jj = 0; jj < RPT / 4; jj++){
          float4 av = *(const float4*)&At[k][tr * RPT + jj * 4];
          const float* pa = (const float*)&av;
          #pragma unroll
          for (int j = 0; j < 4; j++)
            #pragma unroll
            for (int i = 0; i < 4; i++)
              acc[jj * 4 + j][i] = fmaf(pa[j], pw[i], acc[jj * 4 + j][i]);
        }
      }
      __syncthreads();
    }
  }

  float b0 = 0.f, b1 = 0.f, b2 = 0.f, b3 = 0.f;
  if (bias){
    b0 = bias[cg * 64 + tc * 4 + 0];
    b1 = bias[cg * 64 + tc * 4 + 1];
    b2 = bias[cg * 64 + tc * 4 + 2];
    b3 = bias[cg * 64 + tc * 4 + 3];
  }
  #pragma unroll
  for (int j = 0; j < RPT; j++){
    int n = nbase + tr * RPT + j;
    if (n < nrows){
      float y0 = acc[j][0] + b0, y1 = acc[j][1] + b1;
      float y2 = acc[j][2] + b2, y3 = acc[j][3] + b3;
      if (ELU){ y0 = eluf(y0); y1 = eluf(y1); y2 = eluf(y2); y3 = eluf(y3); }
      *(float4*)(Y + (size_t)n * ldy + cg * 64 + tc * 4) = make_float4(y0, y1, y2, y3);
    }
  }
}

// ---------------- L3 GEMM: 128 rows x 2 column-groups (8x8 microtile) ----------------

__global__ __launch_bounds__(256, 1) void gemmL3_kernel(
    const float* __restrict__ A, int lda, int K,
    const float* __restrict__ W, int ldw,
    float* __restrict__ Y, int ldy, int nrows)
{
  __shared__ float At[32][132];
  __shared__ float Wl[32][132];
  int t = threadIdx.x;
  int tc = t & 15, tr = t >> 4;
  int cgb = blockIdx.x * 2;
  int nbase = blockIdx.y * 128;
  float acc[8][8];
  #pragma unroll
  for (int j = 0; j < 8; j++)
    #pragma unroll
    for (int i = 0; i < 8; i++) acc[j][i] = 0.f;

  for (int k0 = 0; k0 < K; k0 += 32){
    #pragma unroll
    for (int i = 0; i < 4; i++){
      int e = i * 256 + t;
      int kk = e >> 5, cc4 = (e & 31) << 2;
      float4 v = make_float4(0.f, 0.f, 0.f, 0.f);
      if (k0 + kk < K) v = *(const float4*)(W + (size_t)(k0 + kk) * ldw + cgb * 64 + cc4);
      *(float4*)&Wl[kk][cc4] = v;
    }
    #pragma unroll
    for (int i = 0; i < 4; i++){
      int e = i * 256 + t;
      int r = e >> 3, c4 = (e & 7) << 2;
      int n = nbase + r;
      float4 v = make_float4(0.f, 0.f, 0.f, 0.f);
      if (n < nrows && k0 + c4 < K) v = *(const float4*)(A + (size_t)n * lda + k0 + c4);
      At[c4 + 0][r] = v.x;
      At[c4 + 1][r] = v.y;
      At[c4 + 2][r] = v.z;
      At[c4 + 3][r] = v.w;
    }
    __syncthreads();
    #pragma unroll 2
    for (int k = 0; k < 32; k++){
      float4 a0 = *(const float4*)&At[k][tr * 8];
      float4 a1 = *(const float4*)&At[k][tr * 8 + 4];
      float4 w0 = *(const float4*)&Wl[k][tc * 4];
      float4 w1 = *(const float4*)&Wl[k][64 + tc * 4];
      float a[8] = {a0.x, a0.y, a0.z, a0.w, a1.x, a1.y, a1.z, a1.w};
      float w[8] = {w0.x, w0.y, w0.z, w0.w, w1.x, w1.y, w1.z, w1.w};
      #pragma unroll
      for (int j = 0; j < 8; j++)
        #pragma unroll
        for (int i = 0; i < 8; i++)
          acc[j][i] = fmaf(a[j], w[i], acc[j][i]);
    }
    __syncthreads();
  }

  #pragma unroll
  for (int cg = 0; cg < 2; cg++){
    #pragma unroll
    for (int j = 0; j < 8; j++){
      int n = nbase + tr * 8 + j;
      if (n < nrows)
        *(float4*)(Y + (size_t)n * ldy + (cgb + cg) * 64 + tc * 4) =
            make_float4(acc[j][cg*4+0], acc[j][cg*4+1], acc[j][cg*4+2], acc[j][cg*4+3]);
    }
  }
}

// ---------------- GAT1: aggregate h1 with per-(edge,head) softmax weights ----------------

__global__ void gat1_agg_kernel(const float* __restrict__ h1, const float* __restrict__ as_,
                                const float* __restrict__ ad_, const int* __restrict__ offs,
                                const int* __restrict__ csr_src, float* __restrict__ aggG){
  int wid  = (blockIdx.x * blockDim.x + threadIdx.x) >> 6;
  int lane = threadIdx.x & 63;
  if (wid >= NN) return;
  int n0 = offs[wid], n1 = offs[wid + 1];
  int h = lane & 3;
  float adn = ad_[wid * 4 + h];
  float es  = leakyf(as_[wid * 4 + h] + adn);
  float m = es;
  for (int k = n0 + (lane >> 2); k < n1; k += 16){
    int s = csr_src[k];
    m = fmaxf(m, leakyf(as_[s * 4 + h] + adn));
  }
  #pragma unroll
  for (int o = 4; o < 64; o <<= 1) m = fmaxf(m, __shfl_xor(m, o));
  float den = 0.f;
  float a0 = 0.f, a1 = 0.f, a2 = 0.f, a3 = 0.f;
  for (int base = n0; base < n1; base += 16){
    int k = base + (lane >> 2);
    int s = 0; float p = 0.f;
    if (k < n1){
      s = csr_src[k];
      p = expf(leakyf(as_[s * 4 + h] + adn) - m);
    }
    den += p;
    int cnt = min(16, n1 - base);
    for (int jj = 0; jj < cnt; jj++){
      int sj = __shfl(s, jj << 2);
      float p0 = __shfl(p, (jj << 2));
      float p1 = __shfl(p, (jj << 2) | 1);
      float p2 = __shfl(p, (jj << 2) | 2);
      float p3 = __shfl(p, (jj << 2) | 3);
      float v = h1[(size_t)sj * 64 + lane];
      a0 += p0 * v; a1 += p1 * v; a2 += p2 * v; a3 += p3 * v;
    }
  }
  #pragma unroll
  for (int o = 4; o < 64; o <<= 1) den += __shfl_xor(den, o);
  float ps = expf(es - m);
  float ps0 = __shfl(ps, 0), ps1 = __shfl(ps, 1), ps2 = __shfl(ps, 2), ps3 = __shfl(ps, 3);
  float dn0 = __shfl(den, 0) + ps0, dn1 = __shfl(den, 1) + ps1;
  float dn2 = __shfl(den, 2) + ps2, dn3 = __shfl(den, 3) + ps3;
  float v = h1[(size_t)wid * 64 + lane];
  a0 = (a0 + ps0 * v) / dn0;
  a1 = (a1 + ps1 * v) / dn1;
  a2 = (a2 + ps2 * v) / dn2;
  a3 = (a3 + ps3 * v) / dn3;
  float* ag = aggG + (size_t)wid * 256;
  ag[lane]       = a0;
  ag[64 + lane]  = a1;
  ag[128 + lane] = a2;
  ag[192 + lane] = a3;
}

// ---------------- layer-3: per-relation message table (bf16) ----------------

__global__ void xr_kernel(const float* __restrict__ xb2, const float* __restrict__ comp2,
                          unsigned short* __restrict__ xr){
  int idx = blockIdx.x * 256 + threadIdx.x;
  if (idx >= NN * 16) return;
  int n = idx >> 4, q = idx & 15;
  float4 xv[4];
  #pragma unroll
  for (int b = 0; b < 4; b++)
    xv[b] = *(const float4*)(xb2 + (size_t)n * 384 + b * 64 + q * 4);
  #pragma unroll
  for (int r = 0; r < 8; r++){
    float c0 = comp2[r * 4 + 0], c1 = comp2[r * 4 + 1];
    float c2 = comp2[r * 4 + 2], c3 = comp2[r * 4 + 3];
    float m0 = c0 * xv[0].x + c1 * xv[1].x + c2 * xv[2].x + c3 * xv[3].x;
    float m1 = c0 * xv[0].y + c1 * xv[1].y + c2 * xv[2].y + c3 * xv[3].y;
    float m2 = c0 * xv[0].z + c1 * xv[1].z + c2 * xv[2].z + c3 * xv[3].z;
    float m3 = c0 * xv[0].w + c1 * xv[1].w + c2 * xv[2].w + c3 * xv[3].w;
    ushort4 u;
    u.x = f2bf(m0); u.y = f2bf(m1); u.z = f2bf(m2); u.w = f2bf(m3);
    *(ushort4*)(xr + ((size_t)n * 8 + r) * 64 + q * 4) = u;
  }
}

__global__ void rgcn2_agg_kernel(const unsigned short* __restrict__ xr,
                                 const float* __restrict__ xb,
                                 const float* __restrict__ bias, const int* __restrict__ offs,
                                 const int* __restrict__ csr_src, const int* __restrict__ csr_et,
                                 float* __restrict__ h3){
  int wid  = (blockIdx.x * blockDim.x + threadIdx.x) >> 6;
  int lane = threadIdx.x & 63;
  if (wid >= NN) return;
  int eg = lane >> 4, q = lane & 15;
  int n0 = offs[wid], n1 = offs[wid + 1];
  float a0 = 0.f, a1 = 0.f, a2 = 0.f, a3 = 0.f;
  for (int k = n0 + eg; k < n1; k += 4){
    int s = csr_src[k], e = csr_et[k];
    ushort4 u = *(const ushort4*)(xr + ((size_t)s * 8 + e) * 64 + q * 4);
    a0 += bf2f(u.x); a1 += bf2f(u.y); a2 += bf2f(u.z); a3 += bf2f(u.w);
  }
  a0 += __shfl_xor(a0, 16); a0 += __shfl_xor(a0, 32);
  a1 += __shfl_xor(a1, 16); a1 += __shfl_xor(a1, 32);
  a2 += __shfl_xor(a2, 16); a2 += __shfl_xor(a2, 32);
  a3 += __shfl_xor(a3, 16); a3 += __shfl_xor(a3, 32);
  int dg = n1 - n0;
  float sc = 1.f / (float)(dg > 0 ? dg : 1);
  if (lane < 16){
    float4 r  = *(const float4*)(xb + (size_t)wid * 384 + 256 + q * 4);
    float4 bb = *(const float4*)(bias + q * 4);
    float4 o4;
    o4.x = eluf(a0 * sc + r.x + bb.x);
    o4.y = eluf(a1 * sc + r.y + bb.y);
    o4.z = eluf(a2 * sc + r.z + bb.z);
    o4.w = eluf(a3 * sc + r.w + bb.w);
    *(float4*)(h3 + (size_t)wid * 64 + q * 4) = o4;
  }
}

// ---------------- GAT2 ----------------

__global__ void gat_lin2_kernel(const float* __restrict__ h, const float* __restrict__ W,
                                const float* __restrict__ atts, const float* __restrict__ attd,
                                float* __restrict__ hw, float* __restrict__ as_, float* __restrict__ ad_){
  int wid  = (blockIdx.x * blockDim.x + threadIdx.x) >> 6;
  int lane = threadIdx.x & 63;
  if (wid >= NN) return;
  float acc = 0.f;
  if (lane < 12){
    const float* hr = h + (size_t)wid * 64;
    const float* Wc = W + lane;
    #pragma unroll 8
    for (int i = 0; i < 64; i++) acc += hr[i] * Wc[(size_t)i * 12];
    hw[(size_t)wid * 12 + lane] = acc;
  }
  float ts = (lane < 12) ? acc * atts[lane] : 0.f;
  float td = (lane < 12) ? acc * attd[lane] : 0.f;
  int b = (lane < 4) ? lane * 3 : 0;
  float s0 = __shfl(ts, b) + __shfl(ts, b + 1) + __shfl(ts, b + 2);
  float d0 = __shfl(td, b) + __shfl(td, b + 1) + __shfl(td, b + 2);
  if (lane < 4){ as_[wid * 4 + lane] = s0; ad_[wid * 4 + lane] = d0; }
}

__global__ void gat2_final_kernel(const float* __restrict__ hw, const float* __restrict__ as_,
                                  const float* __restrict__ ad_, const float* __restrict__ bg2,
                                  const int* __restrict__ offs, const int* __restrict__ csr_src,
                                  float* __restrict__ out){
  int wid  = (blockIdx.x * blockDim.x + threadIdx.x) >> 6;
  int lane = threadIdx.x & 63;
  if (wid >= NN) return;
  int n0 = offs[wid], n1 = offs[wid + 1];
  F4 adn = ld4(ad_ + (size_t)wid * 4);
  F4 asn = ld4(as_ + (size_t)wid * 4);
  F4 es{leakyf(asn.x + adn.x), leakyf(asn.y + adn.y), leakyf(asn.z + adn.z), leakyf(asn.w + adn.w)};
  F4 m = es;
  for (int k = n0 + lane; k < n1; k += 64){
    int s = csr_src[k];
    F4 a = ld4(as_ + (size_t)s * 4);
    m.x = fmaxf(m.x, leakyf(a.x + adn.x));
    m.y = fmaxf(m.y, leakyf(a.y + adn.y));
    m.z = fmaxf(m.z, leakyf(a.z + adn.z));
    m.w = fmaxf(m.w, leakyf(a.w + adn.w));
  }
  #pragma unroll
  for (int o = 32; o; o >>= 1){
    m.x = fmaxf(m.x, __shfl_xor(m.x, o));
    m.y = fmaxf(m.y, __shfl_xor(m.y, o));
    m.z = fmaxf(m.z, __shfl_xor(m.z, o));
    m.w = fmaxf(m.w, __shfl_xor(m.w, o));
  }
  F4 ps{expf(es.x - m.x), expf(es.y - m.y), expf(es.z - m.z), expf(es.w - m.w)};
  float acc[12];
  #pragma unroll
  for (int j = 0; j < 12; j++) acc[j] = 0.f;
  F4 denp{0.f, 0.f, 0.f, 0.f};
  for (int k = n0 + lane; k < n1; k += 64){
    int s = csr_src[k];
    F4 a = ld4(as_ + (size_t)s * 4);
    F4 p{expf(leakyf(a.x + adn.x) - m.x), expf(leakyf(a.y + adn.y) - m.y),
         expf(leakyf(a.z + adn.z) - m.z), expf(leakyf(a.w + adn.w) - m.w)};
    denp.x += p.x; denp.y += p.y; denp.z += p.z; denp.w += p.w;
    const float* hb = hw + (size_t)s * 12;
    F4 h0 = ld4(hb), h1 = ld4(hb + 4), h2 = ld4(hb + 8);
    acc[0] += p.x * h0.x; acc[1]  += p.x * h0.y; acc[2]  += p.x * h0.z;
    acc[3] += p.y * h0.w; acc[4]  += p.y * h1.x; acc[5]  += p.y * h1.y;
    acc[6] += p.z * h1.z; acc[7]  += p.z * h1.w; acc[8]  += p.z * h2.x;
    acc[9] += p.w * h2.y; acc[10] += p.w * h2.z; acc[11] += p.w * h2.w;
  }
  #pragma unroll
  for (int o = 32; o; o >>= 1){
    denp.x += __shfl_xor(denp.x, o);
    denp.y += __shfl_xor(denp.y, o);
    denp.z += __shfl_xor(denp.z, o);
    denp.w += __shfl_xor(denp.w, o);
    #pragma unroll
    for (int j = 0; j < 12; j++) acc[j] += __shfl_xor(acc[j], o);
  }
  if (lane == 0){
    const float* hn = hw + (size_t)wid * 12;
    float dn[4]  = {denp.x + ps.x, denp.y + ps.y, denp.z + ps.z, denp.w + ps.w};
    float psv[4] = {ps.x, ps.y, ps.z, ps.w};
    float tot = 0.f;
    #pragma unroll
    for (int h_ = 0; h_ < 4; h_++){
      #pragma unroll
      for (int c = 0; c < 3; c++){
        float num = acc[h_ * 3 + c] + psv[h_] * hn[h_ * 3 + c];
        tot += num / dn[h_];
      }
    }
    tot = tot / 12.f + (bg2[0] + bg2[1] + bg2[2]) / 3.f;
    out[wid] = tanhf(tot);
  }
}

// ---------------- launch ----------------

extern "C" void kernel_launch(void* const* d_in, const int* in_sizes, int n_in,
                              void* d_out, int out_size, void* d_ws, size_t ws_size,
                              hipStream_t stream){
  const float* x      = (const float*)d_in[0];
  const int*   ei     = (const int*)d_in[1];
  const int*   et     = (const int*)d_in[2];
  const float* basis1 = (const float*)d_in[3];
  const float* comp1  = (const float*)d_in[4];
  const float* root1  = (const float*)d_in[5];
  const float* brg1   = (const float*)d_in[6];
  const float* Wg1    = (const float*)d_in[7];
  const float* atts1  = (const float*)d_in[8];
  const float* attd1  = (const float*)d_in[9];
  const float* bg1    = (const float*)d_in[10];
  const float* basis2 = (const float*)d_in[11];
  const float* comp2  = (const float*)d_in[12];
  const float* root2  = (const float*)d_in[13];
  const float* brg2   = (const float*)d_in[14];
  const float* Wg2    = (const float*)d_in[15];
  const float* atts2  = (const float*)d_in[16];
  const float* attd2  = (const float*)d_in[17];
  const float* bg2    = (const float*)d_in[18];
  float* out = (float*)d_out;

  const int* src = ei;
  const int* dst = ei + NE;

  char* ws = (char*)d_ws;
  size_t off = 0;
  auto alloc = [&](size_t bytes) -> void* {
    void* p = ws + off;
    off = (off + bytes + 255) & ~(size_t)255;
    return p;
  };
  // persistent
  int*   deg     = (int*)alloc((size_t)NN * 4);
  int*   cursor  = (int*)alloc((size_t)NN * 4);
  int*   offs    = (int*)alloc((size_t)(NN + 1) * 4);
  int*   bsum    = (int*)alloc((size_t)256 * 4);
  int*   csr_src = (int*)alloc((size_t)NE * 4);
  int*   csr_et  = (int*)alloc((size_t)NE * 4);
  float* Wcat2   = (float*)alloc((size_t)256 * 384 * 4);
  float* wa_s    = (float*)alloc((size_t)256 * 4);
  float* wa_d    = (float*)alloc((size_t)256 * 4);
  float* h1      = (float*)alloc((size_t)NN * 64 * 4);
  float* h2      = (float*)alloc((size_t)NN * 256 * 4);
  float* h3      = (float*)alloc((size_t)NN * 64 * 4);
  float* hw2     = (float*)alloc((size_t)NN * 12 * 4);
  float* as1     = (float*)alloc((size_t)NN * 4 * 4);
  float* ad1     = (float*)alloc((size_t)NN * 4 * 4);
  float* as2     = (float*)alloc((size_t)NN * 4 * 4);
  float* ad2     = (float*)alloc((size_t)NN * 4 * 4);
  // scratch union: agg1[NN*128] -> aggG[NN*256] -> xb2[NN*384]
  float* S       = (float*)alloc((size_t)NN * 384 * 4);
  float* agg1    = S;
  float* aggG    = S;
  float* xb2     = S;
  // xr (bf16, NN*512*2 = 30.7MB) aliases h1+h2: h1 dead after gat1_agg,
  // h2 dead after L3 gemm; xr written after L3 gemm.
  unsigned short* xr = (unsigned short*)h1;
  (void)ws_size; (void)n_in; (void)in_sizes; (void)out_size;

  const int BLK = 256;
  int gridN   = (NN + BLK - 1) / BLK;
  int gridE   = (NE + BLK - 1) / BLK;
  int gridW   = (NN + 3) / 4;
  int gridM64 = (NN + 63) / 64;     // 469
  int gridM128= (NN + 127) / 128;   // 235

  // CSR build + weight prep
  zero_int_kernel<<<gridN, BLK, 0, stream>>>(deg, NN);
  zero_int_kernel<<<gridN, BLK, 0, stream>>>(cursor, NN);
  count_kernel<<<gridE, BLK, 0, stream>>>(dst, deg, NE);
  wcat2_kernel<<<(256 * 384 + 255) / 256, BLK, 0, stream>>>(basis2, root2, Wcat2);
  wa_kernel<<<1, BLK, 0, stream>>>(Wg1, atts1, attd1, wa_s, wa_d);
  scan1_kernel<<<gridN, BLK, 0, stream>>>(deg, offs, bsum);
  scan2_kernel<<<1, BLK, 0, stream>>>(bsum, gridN);
  scan3_kernel<<<gridN, BLK, 0, stream>>>(bsum, offs);
  scatter_kernel<<<gridE, BLK, 0, stream>>>(src, dst, et, offs, cursor, csr_src, csr_et, NE);

  // Layer 1: RGCN (32 -> 64) + elu
  agg1_kernel<<<gridW, BLK, 0, stream>>>(x, comp1, offs, csr_src, csr_et, agg1);
  gemmT_kernel<4, true><<<dim3(1, gridM64), BLK, 0, stream>>>(
      agg1, 128, 128, basis1, 64,
      x, 32, 32, root1, 64,
      brg1, h1, 64, NN, 0, 0);

  // Layer 2: GAT (64 -> 256 concat) + elu: logits -> aggregate h1 -> block-diag GEMM
  logits_kernel<<<(NN * 4 + 255) / 256, BLK, 0, stream>>>(h1, wa_s, wa_d, as1, ad1);
  gat1_agg_kernel<<<gridW, BLK, 0, stream>>>(h1, as1, ad1, offs, csr_src, aggG);
  gemmT_kernel<4, true><<<dim3(4, gridM64), BLK, 0, stream>>>(
      aggG, 256, 64, Wg1, 256,
      nullptr, 0, 0, nullptr, 0,
      bg1, h2, 256, NN, 64, 64);   // FIX: wcgoff = 64 (column offset into Wg1), was 64*256+64 (OOB)

  // Layer 3: RGCN (256 -> 64) + elu: transform-first (2 cgs/block) + bf16 message table
  gemmL3_kernel<<<dim3(3, gridM128), BLK, 0, stream>>>(
      h2, 256, 256, Wcat2, 384, xb2, 384, NN);
  xr_kernel<<<(NN * 16 + 255) / 256, BLK, 0, stream>>>(xb2, comp2, xr);
  rgcn2_agg_kernel<<<gridW, BLK, 0, stream>>>(xr, xb2, brg2, offs, csr_src, csr_et, h3);

  // Layer 4: GAT (64 -> 4x3, mean heads) + mean classes + tanh
  gat_lin2_kernel<<<gridW, BLK, 0, stream>>>(h3, Wg2, atts2, attd2, hw2, as2, ad2);
  gat2_final_kernel<<<gridW, BLK, 0, stream>>>(hw2, as2, ad2, bg2, offs, csr_src, out);
}

// Round 13
// 350.317 us; speedup vs baseline: 1.3233x; 1.1107x over previous
//
#include <hip/hip_runtime.h>
#include <cstdint>
#include <cstddef>

#define NN 30000
#define NE 480000

typedef __attribute__((ext_vector_type(8))) short short8v;
typedef __attribute__((ext_vector_type(4))) float f32x4;

__device__ __forceinline__ float leakyf(float x){ return x > 0.f ? x : 0.2f * x; }
__device__ __forceinline__ float eluf(float x){ return x > 0.f ? x : expm1f(x); }

__device__ __forceinline__ float bf2f(unsigned short u){
  return __uint_as_float(((unsigned)u) << 16);
}
__device__ __forceinline__ unsigned short f2bf(float f){
  unsigned x = __float_as_uint(f);
  unsigned r = (x + 0x7FFFu + ((x >> 16) & 1u)) >> 16;
  return (unsigned short)r;
}

struct F4 { float x, y, z, w; };

__device__ __forceinline__ F4 ld4(const float* p){
  float4 v = *(const float4*)p;
  return F4{v.x, v.y, v.z, v.w};
}

// ---------------- CSR build ----------------

__global__ void zero_int_kernel(int* __restrict__ p, int n){
  int i = blockIdx.x * blockDim.x + threadIdx.x;
  if (i < n) p[i] = 0;
}

__global__ void count_kernel(const int* __restrict__ dst, int* __restrict__ deg, int E){
  int i = blockIdx.x * blockDim.x + threadIdx.x;
  if (i < E) atomicAdd(&deg[dst[i]], 1);
}

__global__ void scan1_kernel(const int* __restrict__ deg, int* __restrict__ offs,
                             int* __restrict__ bsum){
  __shared__ int sh[256];
  int blk = blockIdx.x, t = threadIdx.x, i = blk * 256 + t;
  int v = (i < NN) ? deg[i] : 0;
  sh[t] = v; __syncthreads();
  for (int o = 1; o < 256; o <<= 1){
    int tv = (t >= o) ? sh[t - o] : 0;
    __syncthreads();
    sh[t] += tv;
    __syncthreads();
  }
  if (i < NN) offs[i + 1] = sh[t];
  if (t == 255) bsum[blk] = sh[255];
}

__global__ void scan2_kernel(int* __restrict__ bsum, int nb){
  __shared__ int sh[256];
  int t = threadIdx.x;
  int v = (t < nb) ? bsum[t] : 0;
  sh[t] = v; __syncthreads();
  for (int o = 1; o < 256; o <<= 1){
    int tv = (t >= o) ? sh[t - o] : 0;
    __syncthreads();
    sh[t] += tv;
    __syncthreads();
  }
  if (t < nb) bsum[t] = sh[t];
}

__global__ void scan3_kernel(const int* __restrict__ bsum, int* __restrict__ offs){
  int i = blockIdx.x * 256 + threadIdx.x;
  if (i == 0) offs[0] = 0;
  if (i < NN){
    int blk = i >> 8;
    int add = blk ? bsum[blk - 1] : 0;
    offs[i + 1] += add;
  }
}

__global__ void scatter_kernel(const int* __restrict__ src, const int* __restrict__ dst,
                               const int* __restrict__ et, const int* __restrict__ offs,
                               int* __restrict__ cursor, int* __restrict__ csr_src,
                               int* __restrict__ csr_et, int E){
  int i = blockIdx.x * blockDim.x + threadIdx.x;
  if (i < E){
    int d = dst[i];
    int pos = offs[d] + atomicAdd(&cursor[d], 1);
    csr_src[pos] = src[i];
    csr_et[pos]  = et[i];
  }
}

// ---------------- weight prep ----------------
// Wcat2 [256][384]: cols 0..255 = basis2 (4 bases x 64), 256..319 = root2, 320..383 = 0.

__global__ void wcat2_kernel(const float* __restrict__ basis2, const float* __restrict__ root2,
                             float* __restrict__ Wcat){
  int idx = blockIdx.x * 256 + threadIdx.x;
  if (idx >= 256 * 384) return;
  int k = idx / 384, col = idx - k * 384;
  float v = 0.f;
  if (col < 256){
    int b = col >> 6, c = col & 63;
    v = basis2[((size_t)b * 256 + k) * 64 + c];
  } else if (col < 320){
    v = root2[(size_t)k * 64 + (col - 256)];
  }
  Wcat[idx] = v;
}

// pack Wcat2 into MFMA B-fragment order, bf16 hi/lo split.
// frag id = (cg*4+nf)*8 + kstep; lane l, j: element Wcat[kstep*32 + (l>>4)*8 + j][nf16*16 + (l&15)]
__global__ void packB_kernel(const float* __restrict__ Wcat, unsigned short* __restrict__ Bhi,
                             unsigned short* __restrict__ Blo){
  int idx = blockIdx.x * 256 + threadIdx.x;   // 20 nf * 8 kstep * 64 lanes = 10240
  if (idx >= 10240) return;
  int lane = idx & 63;
  int rest = idx >> 6;
  int kstep = rest & 7;
  int nf = rest >> 3;                          // 0..19
  int col = nf * 16 + (lane & 15);
  int kbase = kstep * 32 + ((lane >> 4) << 3);
  size_t obase = (size_t)idx * 8;
  #pragma unroll
  for (int j = 0; j < 8; j++){
    float v = Wcat[(size_t)(kbase + j) * 384 + col];
    unsigned short h = f2bf(v);
    float res = v - bf2f(h);
    Bhi[obase + j] = h;
    Blo[obase + j] = f2bf(res);
  }
}

// wa_s[k*4+h] = sum_c Wg1[k, h*64+c] * atts1[h,c]  (and wa_d with attd1)
__global__ void wa_kernel(const float* __restrict__ Wg1, const float* __restrict__ atts1,
                          const float* __restrict__ attd1, float* __restrict__ wa_s,
                          float* __restrict__ wa_d){
  int t = threadIdx.x;
  int k = t >> 2, h = t & 3;
  float s = 0.f, d = 0.f;
  const float* wr = Wg1 + (size_t)k * 256 + h * 64;
  const float* pa = atts1 + h * 64;
  const float* pb = attd1 + h * 64;
  #pragma unroll 8
  for (int c = 0; c < 64; c++){ s += wr[c] * pa[c]; d += wr[c] * pb[c]; }
  wa_s[k * 4 + h] = s;
  wa_d[k * 4 + h] = d;
}

// as1[n,h] = h1[n,:] . wa_s[:,h]
__global__ void logits_kernel(const float* __restrict__ h1, const float* __restrict__ wa_s,
                              const float* __restrict__ wa_d, float* __restrict__ as_,
                              float* __restrict__ ad_){
  __shared__ float ws[256], wd[256];
  int t = threadIdx.x;
  ws[t] = wa_s[t];
  wd[t] = wa_d[t];
  __syncthreads();
  int idx = blockIdx.x * 256 + t;
  int n = idx >> 2, h = idx & 3;
  if (n >= NN) return;
  float s = 0.f, d = 0.f;
  const float* hr = h1 + (size_t)n * 64;
  #pragma unroll 4
  for (int k4 = 0; k4 < 16; k4++){
    float4 hv = *(const float4*)(hr + k4 * 4);
    s += hv.x * ws[(k4*4+0)*4+h] + hv.y * ws[(k4*4+1)*4+h]
       + hv.z * ws[(k4*4+2)*4+h] + hv.w * ws[(k4*4+3)*4+h];
    d += hv.x * wd[(k4*4+0)*4+h] + hv.y * wd[(k4*4+1)*4+h]
       + hv.z * wd[(k4*4+2)*4+h] + hv.w * wd[(k4*4+3)*4+h];
  }
  as_[n * 4 + h] = s;
  ad_[n * 4 + h] = d;
}

// ---------------- layer-1 basis-space aggregation ----------------

__global__ void agg1_kernel(const float* __restrict__ x, const float* __restrict__ comp,
                            const int* __restrict__ offs, const int* __restrict__ csr_src,
                            const int* __restrict__ csr_et, float* __restrict__ agg){
  int wid  = (blockIdx.x * blockDim.x + threadIdx.x) >> 6;
  int lane = threadIdx.x & 63;
  if (wid >= NN) return;
  int c = lane & 31, half = lane >> 5;
  int n0 = offs[wid], n1 = offs[wid + 1];
  float a0 = 0.f, a1 = 0.f, a2 = 0.f, a3 = 0.f;
  for (int k = n0 + half; k < n1; k += 2){
    int s = csr_src[k], e = csr_et[k];
    float v = x[(size_t)s * 32 + c];
    F4 cp = ld4(comp + (size_t)e * 4);
    a0 += cp.x * v; a1 += cp.y * v; a2 += cp.z * v; a3 += cp.w * v;
  }
  a0 += __shfl_xor(a0, 32);
  a1 += __shfl_xor(a1, 32);
  a2 += __shfl_xor(a2, 32);
  a3 += __shfl_xor(a3, 32);
  int dg = n1 - n0;
  float sc = 1.f / (float)(dg > 0 ? dg : 1);
  if (lane < 32){
    float* ar = agg + (size_t)wid * 128 + c;
    ar[0]  = a0 * sc;
    ar[32] = a1 * sc;
    ar[64] = a2 * sc;
    ar[96] = a3 * sc;
  }
}

// ---------------- (RPT*16)-row x 64-col fused GEMM, per-cg offsets ----------------

template<int RPT, bool ELU>
__global__ __launch_bounds__(256) void gemmT_kernel(
    const float* __restrict__ A1, int lda1, int K1,
    const float* __restrict__ W1, int ldw1,
    const float* __restrict__ A2, int lda2, int K2,
    const float* __restrict__ W2, int ldw2,
    const float* __restrict__ bias,
    float* __restrict__ Y, int ldy,
    int nrows, int acgoff, int wcgoff)
{
  __shared__ float At[32][RPT * 16 + 4];
  __shared__ float Wl[32][68];
  int t = threadIdx.x;
  int tc = t & 15, tr = t >> 4;
  int cg = blockIdx.x;
  int nbase = blockIdx.y * (RPT * 16);
  float acc[RPT][4];
  #pragma unroll
  for (int j = 0; j < RPT; j++)
    #pragma unroll
    for (int i = 0; i < 4; i++) acc[j][i] = 0.f;

  for (int seg = 0; seg < 2; seg++){
    const float* A = seg ? A2 : A1;
    const float* W = seg ? W2 : W1;
    int lda = seg ? lda2 : lda1;
    int ldw = seg ? ldw2 : ldw1;
    int K   = seg ? K2 : K1;
    if (A == nullptr || K <= 0) continue;
    A += (size_t)cg * acgoff;
    W += (size_t)cg * wcgoff;
    for (int k0 = 0; k0 < K; k0 += 32){
      #pragma unroll
      for (int i = 0; i < 2; i++){
        int e = i * 256 + t;
        int kk = e >> 4, c4 = (e & 15) << 2;
        float4 v = make_float4(0.f, 0.f, 0.f, 0.f);
        if (k0 + kk < K) v = *(const float4*)(W + (size_t)(k0 + kk) * ldw + c4);
        *(float4*)&Wl[kk][c4] = v;
      }
      #pragma unroll
      for (int i = 0; i < RPT / 2; i++){
        int e = i * 256 + t;
        int r = e >> 3, c4 = (e & 7) << 2;
        int n = nbase + r;
        float4 v = make_float4(0.f, 0.f, 0.f, 0.f);
        if (n < nrows && k0 + c4 < K) v = *(const float4*)(A + (size_t)n * lda + k0 + c4);
        At[c4 + 0][r] = v.x;
        At[c4 + 1][r] = v.y;
        At[c4 + 2][r] = v.z;
        At[c4 + 3][r] = v.w;
      }
      __syncthreads();
      #pragma unroll 4
      for (int k = 0; k < 32; k++){
        float4 wv = *(const float4*)&Wl[k][tc * 4];
        const float* pw = (const float*)&wv;
        #pragma unroll
        for (int jj = 0; jj < RPT / 4; jj++){
          float4 av = *(const float4*)&At[k][tr * RPT + jj * 4];
          const float* pa = (const float*)&av;
          #pragma unroll
          for (int j = 0; j < 4; j++)
            #pragma unroll
            for (int i = 0; i < 4; i++)
              acc[jj * 4 + j][i] = fmaf(pa[j], pw[i], acc[jj * 4 + j][i]);
        }
      }
      __syncthreads();
    }
  }

  float b0 = 0.f, b1 = 0.f, b2 = 0.f, b3 = 0.f;
  if (bias){
    b0 = bias[cg * 64 + tc * 4 + 0];
    b1 = bias[cg * 64 + tc * 4 + 1];
    b2 = bias[cg * 64 + tc * 4 + 2];
    b3 = bias[cg * 64 + tc * 4 + 3];
  }
  #pragma unroll
  for (int j = 0; j < RPT; j++){
    int n = nbase + tr * RPT + j;
    if (n < nrows){
      float y0 = acc[j][0] + b0, y1 = acc[j][1] + b1;
      float y2 = acc[j][2] + b2, y3 = acc[j][3] + b3;
      if (ELU){ y0 = eluf(y0); y1 = eluf(y1); y2 = eluf(y2); y3 = eluf(y3); }
      *(float4*)(Y + (size_t)n * ldy + cg * 64 + tc * 4) = make_float4(y0, y1, y2, y3);
    }
  }
}

// ---------------- L3 GEMM via bf16-split MFMA ----------------
// xb2[30000x320] = h2[30000x256] @ Wcat2[256x320], 3-term bf16 split (~fp32 accuracy).
// Block = 4 waves; wave = 64 rows x 64 cols (4x4 frags of 16x16x32). grid = (5 cg, 118).
// A frag: lane holds A[mrow + (lane&15)][k0 + 8*(lane>>4) + j], j=0..7 (contiguous k).
// B frags pre-packed by packB_kernel. C/D: col=lane&15, row=4*(lane>>4)+reg.

__global__ __launch_bounds__(256) void gemmL3_mfma_kernel(
    const float* __restrict__ A, const unsigned short* __restrict__ Bhi,
    const unsigned short* __restrict__ Blo, float* __restrict__ Y)
{
  int t = threadIdx.x;
  int lane = t & 63, wv = t >> 6;
  int cg = blockIdx.x;
  int mbase = blockIdx.y * 256 + wv * 64;
  int fr = lane & 15;
  int ksub = (lane >> 4) << 3;
  f32x4 acc[4][4];
  #pragma unroll
  for (int mi = 0; mi < 4; mi++)
    #pragma unroll
    for (int ni = 0; ni < 4; ni++)
      acc[mi][ni] = (f32x4){0.f, 0.f, 0.f, 0.f};

  for (int ks = 0; ks < 8; ks++){
    short8v ahi[4], alo[4];
    #pragma unroll
    for (int mi = 0; mi < 4; mi++){
      int r = mbase + mi * 16 + fr;
      float av[8];
      if (r < NN){
        float4 p0 = *(const float4*)(A + (size_t)r * 256 + ks * 32 + ksub);
        float4 p1 = *(const float4*)(A + (size_t)r * 256 + ks * 32 + ksub + 4);
        av[0] = p0.x; av[1] = p0.y; av[2] = p0.z; av[3] = p0.w;
        av[4] = p1.x; av[5] = p1.y; av[6] = p1.z; av[7] = p1.w;
      } else {
        #pragma unroll
        for (int j = 0; j < 8; j++) av[j] = 0.f;
      }
      #pragma unroll
      for (int j = 0; j < 8; j++){
        unsigned short h = f2bf(av[j]);
        float res = av[j] - bf2f(h);
        ahi[mi][j] = (short)h;
        alo[mi][j] = (short)f2bf(res);
      }
    }
    #pragma unroll
    for (int ni = 0; ni < 4; ni++){
      size_t boff = ((((size_t)(cg * 4 + ni)) * 8 + ks) * 64 + lane) * 8;
      short8v bh = *(const short8v*)(Bhi + boff);
      short8v bl = *(const short8v*)(Blo + boff);
      #pragma unroll
      for (int mi = 0; mi < 4; mi++){
        acc[mi][ni] = __builtin_amdgcn_mfma_f32_16x16x32_bf16(ahi[mi], bh, acc[mi][ni], 0, 0, 0);
        acc[mi][ni] = __builtin_amdgcn_mfma_f32_16x16x32_bf16(ahi[mi], bl, acc[mi][ni], 0, 0, 0);
        acc[mi][ni] = __builtin_amdgcn_mfma_f32_16x16x32_bf16(alo[mi], bh, acc[mi][ni], 0, 0, 0);
      }
    }
  }
  int crow = (lane >> 4) << 2;
  #pragma unroll
  for (int mi = 0; mi < 4; mi++){
    #pragma unroll
    for (int reg = 0; reg < 4; reg++){
      int r = mbase + mi * 16 + crow + reg;
      if (r < NN){
        #pragma unroll
        for (int ni = 0; ni < 4; ni++)
          Y[(size_t)r * 384 + cg * 64 + ni * 16 + fr] = acc[mi][ni][reg];
      }
    }
  }
}

// ---------------- GAT1: aggregate h1 with per-(edge,head) softmax weights ----------------

__global__ void gat1_agg_kernel(const float* __restrict__ h1, const float* __restrict__ as_,
                                const float* __restrict__ ad_, const int* __restrict__ offs,
                                const int* __restrict__ csr_src, float* __restrict__ aggG){
  int wid  = (blockIdx.x * blockDim.x + threadIdx.x) >> 6;
  int lane = threadIdx.x & 63;
  if (wid >= NN) return;
  int n0 = offs[wid], n1 = offs[wid + 1];
  int h = lane & 3;
  float adn = ad_[wid * 4 + h];
  float es  = leakyf(as_[wid * 4 + h] + adn);
  float m = es;
  for (int k = n0 + (lane >> 2); k < n1; k += 16){
    int s = csr_src[k];
    m = fmaxf(m, leakyf(as_[s * 4 + h] + adn));
  }
  #pragma unroll
  for (int o = 4; o < 64; o <<= 1) m = fmaxf(m, __shfl_xor(m, o));
  float den = 0.f;
  float a0 = 0.f, a1 = 0.f, a2 = 0.f, a3 = 0.f;
  for (int base = n0; base < n1; base += 16){
    int k = base + (lane >> 2);
    int s = 0; float p = 0.f;
    if (k < n1){
      s = csr_src[k];
      p = expf(leakyf(as_[s * 4 + h] + adn) - m);
    }
    den += p;
    int cnt = min(16, n1 - base);
    for (int jj = 0; jj < cnt; jj++){
      int sj = __shfl(s, jj << 2);
      float p0 = __shfl(p, (jj << 2));
      float p1 = __shfl(p, (jj << 2) | 1);
      float p2 = __shfl(p, (jj << 2) | 2);
      float p3 = __shfl(p, (jj << 2) | 3);
      float v = h1[(size_t)sj * 64 + lane];
      a0 += p0 * v; a1 += p1 * v; a2 += p2 * v; a3 += p3 * v;
    }
  }
  #pragma unroll
  for (int o = 4; o < 64; o <<= 1) den += __shfl_xor(den, o);
  float ps = expf(es - m);
  float ps0 = __shfl(ps, 0), ps1 = __shfl(ps, 1), ps2 = __shfl(ps, 2), ps3 = __shfl(ps, 3);
  float dn0 = __shfl(den, 0) + ps0, dn1 = __shfl(den, 1) + ps1;
  float dn2 = __shfl(den, 2) + ps2, dn3 = __shfl(den, 3) + ps3;
  float v = h1[(size_t)wid * 64 + lane];
  a0 = (a0 + ps0 * v) / dn0;
  a1 = (a1 + ps1 * v) / dn1;
  a2 = (a2 + ps2 * v) / dn2;
  a3 = (a3 + ps3 * v) / dn3;
  float* ag = aggG + (size_t)wid * 256;
  ag[lane]       = a0;
  ag[64 + lane]  = a1;
  ag[128 + lane] = a2;
  ag[192 + lane] = a3;
}

// ---------------- layer-3: per-relation message table (bf16) ----------------

__global__ void xr_kernel(const float* __restrict__ xb2, const float* __restrict__ comp2,
                          unsigned short* __restrict__ xr){
  int idx = blockIdx.x * 256 + threadIdx.x;
  if (idx >= NN * 16) return;
  int n = idx >> 4, q = idx & 15;
  float4 xv[4];
  #pragma unroll
  for (int b = 0; b < 4; b++)
    xv[b] = *(const float4*)(xb2 + (size_t)n * 384 + b * 64 + q * 4);
  #pragma unroll
  for (int r = 0; r < 8; r++){
    float c0 = comp2[r * 4 + 0], c1 = comp2[r * 4 + 1];
    float c2 = comp2[r * 4 + 2], c3 = comp2[r * 4 + 3];
    float m0 = c0 * xv[0].x + c1 * xv[1].x + c2 * xv[2].x + c3 * xv[3].x;
    float m1 = c0 * xv[0].y + c1 * xv[1].y + c2 * xv[2].y + c3 * xv[3].y;
    float m2 = c0 * xv[0].z + c1 * xv[1].z + c2 * xv[2].z + c3 * xv[3].z;
    float m3 = c0 * xv[0].w + c1 * xv[1].w + c2 * xv[2].w + c3 * xv[3].w;
    ushort4 u;
    u.x = f2bf(m0); u.y = f2bf(m1); u.z = f2bf(m2); u.w = f2bf(m3);
    *(ushort4*)(xr + ((size_t)n * 8 + r) * 64 + q * 4) = u;
  }
}

__global__ void rgcn2_agg_kernel(const unsigned short* __restrict__ xr,
                                 const float* __restrict__ xb,
                                 const float* __restrict__ bias, const int* __restrict__ offs,
                                 const int* __restrict__ csr_src, const int* __restrict__ csr_et,
                                 float* __restrict__ h3){
  int wid  = (blockIdx.x * blockDim.x + threadIdx.x) >> 6;
  int lane = threadIdx.x & 63;
  if (wid >= NN) return;
  int eg = lane >> 4, q = lane & 15;
  int n0 = offs[wid], n1 = offs[wid + 1];
  float a0 = 0.f, a1 = 0.f, a2 = 0.f, a3 = 0.f;
  for (int k = n0 + eg; k < n1; k += 4){
    int s = csr_src[k], e = csr_et[k];
    ushort4 u = *(const ushort4*)(xr + ((size_t)s * 8 + e) * 64 + q * 4);
    a0 += bf2f(u.x); a1 += bf2f(u.y); a2 += bf2f(u.z); a3 += bf2f(u.w);
  }
  a0 += __shfl_xor(a0, 16); a0 += __shfl_xor(a0, 32);
  a1 += __shfl_xor(a1, 16); a1 += __shfl_xor(a1, 32);
  a2 += __shfl_xor(a2, 16); a2 += __shfl_xor(a2, 32);
  a3 += __shfl_xor(a3, 16); a3 += __shfl_xor(a3, 32);
  int dg = n1 - n0;
  float sc = 1.f / (float)(dg > 0 ? dg : 1);
  if (lane < 16){
    float4 r  = *(const float4*)(xb + (size_t)wid * 384 + 256 + q * 4);
    float4 bb = *(const float4*)(bias + q * 4);
    float4 o4;
    o4.x = eluf(a0 * sc + r.x + bb.x);
    o4.y = eluf(a1 * sc + r.y + bb.y);
    o4.z = eluf(a2 * sc + r.z + bb.z);
    o4.w = eluf(a3 * sc + r.w + bb.w);
    *(float4*)(h3 + (size_t)wid * 64 + q * 4) = o4;
  }
}

// ---------------- GAT2 ----------------

__global__ void gat_lin2_kernel(const float* __restrict__ h, const float* __restrict__ W,
                                const float* __restrict__ atts, const float* __restrict__ attd,
                                float* __restrict__ hw, float* __restrict__ as_, float* __restrict__ ad_){
  int wid  = (blockIdx.x * blockDim.x + threadIdx.x) >> 6;
  int lane = threadIdx.x & 63;
  if (wid >= NN) return;
  float acc = 0.f;
  if (lane < 12){
    const float* hr = h + (size_t)wid * 64;
    const float* Wc = W + lane;
    #pragma unroll 8
    for (int i = 0; i < 64; i++) acc += hr[i] * Wc[(size_t)i * 12];
    hw[(size_t)wid * 12 + lane] = acc;
  }
  float ts = (lane < 12) ? acc * atts[lane] : 0.f;
  float td = (lane < 12) ? acc * attd[lane] : 0.f;
  int b = (lane < 4) ? lane * 3 : 0;
  float s0 = __shfl(ts, b) + __shfl(ts, b + 1) + __shfl(ts, b + 2);
  float d0 = __shfl(td, b) + __shfl(td, b + 1) + __shfl(td, b + 2);
  if (lane < 4){ as_[wid * 4 + lane] = s0; ad_[wid * 4 + lane] = d0; }
}

__global__ void gat2_final_kernel(const float* __restrict__ hw, const float* __restrict__ as_,
                                  const float* __restrict__ ad_, const float* __restrict__ bg2,
                                  const int* __restrict__ offs, const int* __restrict__ csr_src,
                                  float* __restrict__ out){
  int wid  = (blockIdx.x * blockDim.x + threadIdx.x) >> 6;
  int lane = threadIdx.x & 63;
  if (wid >= NN) return;
  int n0 = offs[wid], n1 = offs[wid + 1];
  F4 adn = ld4(ad_ + (size_t)wid * 4);
  F4 asn = ld4(as_ + (size_t)wid * 4);
  F4 es{leakyf(asn.x + adn.x), leakyf(asn.y + adn.y), leakyf(asn.z + adn.z), leakyf(asn.w + adn.w)};
  F4 m = es;
  for (int k = n0 + lane; k < n1; k += 64){
    int s = csr_src[k];
    F4 a = ld4(as_ + (size_t)s * 4);
    m.x = fmaxf(m.x, leakyf(a.x + adn.x));
    m.y = fmaxf(m.y, leakyf(a.y + adn.y));
    m.z = fmaxf(m.z, leakyf(a.z + adn.z));
    m.w = fmaxf(m.w, leakyf(a.w + adn.w));
  }
  #pragma unroll
  for (int o = 32; o; o >>= 1){
    m.x = fmaxf(m.x, __shfl_xor(m.x, o));
    m.y = fmaxf(m.y, __shfl_xor(m.y, o));
    m.z = fmaxf(m.z, __shfl_xor(m.z, o));
    m.w = fmaxf(m.w, __shfl_xor(m.w, o));
  }
  F4 ps{expf(es.x - m.x), expf(es.y - m.y), expf(es.z - m.z), expf(es.w - m.w)};
  float acc[12];
  #pragma unroll
  for (int j = 0; j < 12; j++) acc[j] = 0.f;
  F4 denp{0.f, 0.f, 0.f, 0.f};
  for (int k = n0 + lane; k < n1; k += 64){
    int s = csr_src[k];
    F4 a = ld4(as_ + (size_t)s * 4);
    F4 p{expf(leakyf(a.x + adn.x) - m.x), expf(leakyf(a.y + adn.y) - m.y),
         expf(leakyf(a.z + adn.z) - m.z), expf(leakyf(a.w + adn.w) - m.w)};
    denp.x += p.x; denp.y += p.y; denp.z += p.z; denp.w += p.w;
    const float* hb = hw + (size_t)s * 12;
    F4 h0 = ld4(hb), h1 = ld4(hb + 4), h2 = ld4(hb + 8);
    acc[0] += p.x * h0.x; acc[1]  += p.x * h0.y; acc[2]  += p.x * h0.z;
    acc[3] += p.y * h0.w; acc[4]  += p.y * h1.x; acc[5]  += p.y * h1.y;
    acc[6] += p.z * h1.z; acc[7]  += p.z * h1.w; acc[8]  += p.z * h2.x;
    acc[9] += p.w * h2.y; acc[10] += p.w * h2.z; acc[11] += p.w * h2.w;
  }
  #pragma unroll
  for (int o = 32; o; o >>= 1){
    denp.x += __shfl_xor(denp.x, o);
    denp.y += __shfl_xor(denp.y, o);
    denp.z += __shfl_xor(denp.z, o);
    denp.w += __shfl_xor(denp.w, o);
    #pragma unroll
    for (int j = 0; j < 12; j++) acc[j] += __shfl_xor(acc[j], o);
  }
  if (lane == 0){
    const float* hn = hw + (size_t)wid * 12;
    float dn[4]  = {denp.x + ps.x, denp.y + ps.y, denp.z + ps.z, denp.w + ps.w};
    float psv[4] = {ps.x, ps.y, ps.z, ps.w};
    float tot = 0.f;
    #pragma unroll
    for (int h_ = 0; h_ < 4; h_++){
      #pragma unroll
      for (int c = 0; c < 3; c++){
        float num = acc[h_ * 3 + c] + psv[h_] * hn[h_ * 3 + c];
        tot += num / dn[h_];
      }
    }
    tot = tot / 12.f + (bg2[0] + bg2[1] + bg2[2]) / 3.f;
    out[wid] = tanhf(tot);
  }
}

// ---------------- launch ----------------

extern "C" void kernel_launch(void* const* d_in, const int* in_sizes, int n_in,
                              void* d_out, int out_size, void* d_ws, size_t ws_size,
                              hipStream_t stream){
  const float* x      = (const float*)d_in[0];
  const int*   ei     = (const int*)d_in[1];
  const int*   et     = (const int*)d_in[2];
  const float* basis1 = (const float*)d_in[3];
  const float* comp1  = (const float*)d_in[4];
  const float* root1  = (const float*)d_in[5];
  const float* brg1   = (const float*)d_in[6];
  const float* Wg1    = (const float*)d_in[7];
  const float* atts1  = (const float*)d_in[8];
  const float* attd1  = (const float*)d_in[9];
  const float* bg1    = (const float*)d_in[10];
  const float* basis2 = (const float*)d_in[11];
  const float* comp2  = (const float*)d_in[12];
  const float* root2  = (const float*)d_in[13];
  const float* brg2   = (const float*)d_in[14];
  const float* Wg2    = (const float*)d_in[15];
  const float* atts2  = (const float*)d_in[16];
  const float* attd2  = (const float*)d_in[17];
  const float* bg2    = (const float*)d_in[18];
  float* out = (float*)d_out;

  const int* src = ei;
  const int* dst = ei + NE;

  char* ws = (char*)d_ws;
  size_t off = 0;
  auto alloc = [&](size_t bytes) -> void* {
    void* p = ws + off;
    off = (off + bytes + 255) & ~(size_t)255;
    return p;
  };
  // persistent
  int*   deg     = (int*)alloc((size_t)NN * 4);
  int*   cursor  = (int*)alloc((size_t)NN * 4);
  int*   offs    = (int*)alloc((size_t)(NN + 1) * 4);
  int*   bsum    = (int*)alloc((size_t)256 * 4);
  int*   csr_src = (int*)alloc((size_t)NE * 4);
  int*   csr_et  = (int*)alloc((size_t)NE * 4);
  float* Wcat2   = (float*)alloc((size_t)256 * 384 * 4);
  unsigned short* Bhi = (unsigned short*)alloc((size_t)81920 * 2);
  unsigned short* Blo = (unsigned short*)alloc((size_t)81920 * 2);
  float* wa_s    = (float*)alloc((size_t)256 * 4);
  float* wa_d    = (float*)alloc((size_t)256 * 4);
  float* h1      = (float*)alloc((size_t)NN * 64 * 4);
  float* h2      = (float*)alloc((size_t)NN * 256 * 4);
  float* h3      = (float*)alloc((size_t)NN * 64 * 4);
  float* hw2     = (float*)alloc((size_t)NN * 12 * 4);
  float* as1     = (float*)alloc((size_t)NN * 4 * 4);
  float* ad1     = (float*)alloc((size_t)NN * 4 * 4);
  float* as2     = (float*)alloc((size_t)NN * 4 * 4);
  float* ad2     = (float*)alloc((size_t)NN * 4 * 4);
  // scratch union: agg1[NN*128] -> aggG[NN*256] -> xb2[NN*384]
  float* S       = (float*)alloc((size_t)NN * 384 * 4);
  float* agg1    = S;
  float* aggG    = S;
  float* xb2     = S;
  // xr (bf16) aliases h1+h2: h1 dead after gat1_agg, h2 dead after L3 gemm.
  unsigned short* xr = (unsigned short*)h1;
  (void)ws_size; (void)n_in; (void)in_sizes; (void)out_size;

  const int BLK = 256;
  int gridN   = (NN + BLK - 1) / BLK;
  int gridE   = (NE + BLK - 1) / BLK;
  int gridW   = (NN + 3) / 4;
  int gridM64 = (NN + 63) / 64;     // 469
  int gridM256= (NN + 255) / 256;   // 118

  // CSR build + weight prep
  zero_int_kernel<<<gridN, BLK, 0, stream>>>(deg, NN);
  zero_int_kernel<<<gridN, BLK, 0, stream>>>(cursor, NN);
  count_kernel<<<gridE, BLK, 0, stream>>>(dst, deg, NE);
  wcat2_kernel<<<(256 * 384 + 255) / 256, BLK, 0, stream>>>(basis2, root2, Wcat2);
  packB_kernel<<<(10240 + 255) / 256, BLK, 0, stream>>>(Wcat2, Bhi, Blo);
  wa_kernel<<<1, BLK, 0, stream>>>(Wg1, atts1, attd1, wa_s, wa_d);
  scan1_kernel<<<gridN, BLK, 0, stream>>>(deg, offs, bsum);
  scan2_kernel<<<1, BLK, 0, stream>>>(bsum, gridN);
  scan3_kernel<<<gridN, BLK, 0, stream>>>(bsum, offs);
  scatter_kernel<<<gridE, BLK, 0, stream>>>(src, dst, et, offs, cursor, csr_src, csr_et, NE);

  // Layer 1: RGCN (32 -> 64) + elu
  agg1_kernel<<<gridW, BLK, 0, stream>>>(x, comp1, offs, csr_src, csr_et, agg1);
  gemmT_kernel<4, true><<<dim3(1, gridM64), BLK, 0, stream>>>(
      agg1, 128, 128, basis1, 64,
      x, 32, 32, root1, 64,
      brg1, h1, 64, NN, 0, 0);

  // Layer 2: GAT (64 -> 256 concat) + elu: logits -> aggregate h1 -> block-diag GEMM
  logits_kernel<<<(NN * 4 + 255) / 256, BLK, 0, stream>>>(h1, wa_s, wa_d, as1, ad1);
  gat1_agg_kernel<<<gridW, BLK, 0, stream>>>(h1, as1, ad1, offs, csr_src, aggG);
  gemmT_kernel<4, true><<<dim3(4, gridM64), BLK, 0, stream>>>(
      aggG, 256, 64, Wg1, 256,
      nullptr, 0, 0, nullptr, 0,
      bg1, h2, 256, NN, 64, 64);

  // Layer 3: RGCN (256 -> 64) + elu: bf16-split MFMA transform + bf16 message table
  gemmL3_mfma_kernel<<<dim3(5, gridM256), BLK, 0, stream>>>(h2, Bhi, Blo, xb2);
  xr_kernel<<<(NN * 16 + 255) / 256, BLK, 0, stream>>>(xb2, comp2, xr);
  rgcn2_agg_kernel<<<gridW, BLK, 0, stream>>>(xr, xb2, brg2, offs, csr_src, csr_et, h3);

  // Layer 4: GAT (64 -> 4x3, mean heads) + mean classes + tanh
  gat_lin2_kernel<<<gridW, BLK, 0, stream>>>(h3, Wg2, atts2, attd2, hw2, as2, ad2);
  gat2_final_kernel<<<gridW, BLK, 0, stream>>>(hw2, as2, ad2, bg2, offs, csr_src, out);
}

// Round 14
// 342.671 us; speedup vs baseline: 1.3529x; 1.0223x over previous
//
#include <hip/hip_runtime.h>
#include <cstdint>
#include <cstddef>

#define NN 30000
#define NE 480000

typedef __attribute__((ext_vector_type(8))) short short8v;
typedef __attribute__((ext_vector_type(4))) float f32x4;

__device__ __forceinline__ float leakyf(float x){ return x > 0.f ? x : 0.2f * x; }
__device__ __forceinline__ float eluf(float x){ return x > 0.f ? x : expm1f(x); }

__device__ __forceinline__ float bf2f(unsigned short u){
  return __uint_as_float(((unsigned)u) << 16);
}
__device__ __forceinline__ unsigned short f2bf(float f){
  unsigned x = __float_as_uint(f);
  unsigned r = (x + 0x7FFFu + ((x >> 16) & 1u)) >> 16;
  return (unsigned short)r;
}

struct F4 { float x, y, z, w; };

__device__ __forceinline__ F4 ld4(const float* p){
  float4 v = *(const float4*)p;
  return F4{v.x, v.y, v.z, v.w};
}

__device__ __forceinline__ float4 redeg16(float4 v){
  v.x += __shfl_xor(v.x, 16); v.y += __shfl_xor(v.y, 16);
  v.z += __shfl_xor(v.z, 16); v.w += __shfl_xor(v.w, 16);
  v.x += __shfl_xor(v.x, 32); v.y += __shfl_xor(v.y, 32);
  v.z += __shfl_xor(v.z, 32); v.w += __shfl_xor(v.w, 32);
  return v;
}

// ---------------- CSR build ----------------

__global__ void zero2_kernel(int* __restrict__ a, int* __restrict__ b, int n){
  int i = blockIdx.x * blockDim.x + threadIdx.x;
  if (i < n){ a[i] = 0; b[i] = 0; }
}

__global__ void count_kernel(const int* __restrict__ dst, int* __restrict__ deg, int E){
  int i = blockIdx.x * blockDim.x + threadIdx.x;
  if (i < E) atomicAdd(&deg[dst[i]], 1);
}

__global__ void scan1_kernel(const int* __restrict__ deg, int* __restrict__ offs,
                             int* __restrict__ bsum){
  __shared__ int sh[256];
  int blk = blockIdx.x, t = threadIdx.x, i = blk * 256 + t;
  int v = (i < NN) ? deg[i] : 0;
  sh[t] = v; __syncthreads();
  for (int o = 1; o < 256; o <<= 1){
    int tv = (t >= o) ? sh[t - o] : 0;
    __syncthreads();
    sh[t] += tv;
    __syncthreads();
  }
  if (i < NN) offs[i + 1] = sh[t];
  if (t == 255) bsum[blk] = sh[255];
}

__global__ void scan2_kernel(int* __restrict__ bsum, int nb){
  __shared__ int sh[256];
  int t = threadIdx.x;
  int v = (t < nb) ? bsum[t] : 0;
  sh[t] = v; __syncthreads();
  for (int o = 1; o < 256; o <<= 1){
    int tv = (t >= o) ? sh[t - o] : 0;
    __syncthreads();
    sh[t] += tv;
    __syncthreads();
  }
  if (t < nb) bsum[t] = sh[t];
}

__global__ void scan3_kernel(const int* __restrict__ bsum, int* __restrict__ offs){
  int i = blockIdx.x * 256 + threadIdx.x;
  if (i == 0) offs[0] = 0;
  if (i < NN){
    int blk = i >> 8;
    int add = blk ? bsum[blk - 1] : 0;
    offs[i + 1] += add;
  }
}

__global__ void scatter_kernel(const int* __restrict__ src, const int* __restrict__ dst,
                               const int* __restrict__ et, const int* __restrict__ offs,
                               int* __restrict__ cursor, int* __restrict__ csr_src,
                               int* __restrict__ csr_et, int E){
  int i = blockIdx.x * blockDim.x + threadIdx.x;
  if (i < E){
    int d = dst[i];
    int pos = offs[d] + atomicAdd(&cursor[d], 1);
    csr_src[pos] = src[i];
    csr_et[pos]  = et[i];
  }
}

// ---------------- weight prep ----------------
// Wcat2 [256][384]: cols 0..255 = basis2 (4 bases x 64), 256..319 = root2, 320..383 = 0.

__global__ void wcat2_kernel(const float* __restrict__ basis2, const float* __restrict__ root2,
                             float* __restrict__ Wcat){
  int idx = blockIdx.x * 256 + threadIdx.x;
  if (idx >= 256 * 384) return;
  int k = idx / 384, col = idx - k * 384;
  float v = 0.f;
  if (col < 256){
    int b = col >> 6, c = col & 63;
    v = basis2[((size_t)b * 256 + k) * 64 + c];
  } else if (col < 320){
    v = root2[(size_t)k * 64 + (col - 256)];
  }
  Wcat[idx] = v;
}

// generic MFMA B-fragment pack, bf16 hi/lo split.
// idx = ((cg*4+nf)*ksteps + ks)*64 + lane; element W[ks*32+(lane>>4)*8+j][cg*64+nf*16+(lane&15)]
__global__ void packB_kernel(const float* __restrict__ W, int ldw, int ksteps, int total,
                             unsigned short* __restrict__ Bhi, unsigned short* __restrict__ Blo){
  int idx = blockIdx.x * 256 + threadIdx.x;
  if (idx >= total) return;
  int lane = idx & 63;
  int rest = idx >> 6;
  int ks = rest % ksteps;
  int nfcg = rest / ksteps;
  int nf = nfcg & 3, cg = nfcg >> 2;
  int col = cg * 64 + nf * 16 + (lane & 15);
  int kbase = ks * 32 + ((lane >> 4) << 3);
  size_t obase = (size_t)idx * 8;
  #pragma unroll
  for (int j = 0; j < 8; j++){
    float v = W[(size_t)(kbase + j) * ldw + col];
    unsigned short h = f2bf(v);
    float res = v - bf2f(h);
    Bhi[obase + j] = h;
    Blo[obase + j] = f2bf(res);
  }
}

// wa_s[k*4+h] = sum_c Wg1[k, h*64+c] * atts1[h,c]  (and wa_d with attd1)
__global__ void wa_kernel(const float* __restrict__ Wg1, const float* __restrict__ atts1,
                          const float* __restrict__ attd1, float* __restrict__ wa_s,
                          float* __restrict__ wa_d){
  int t = threadIdx.x;
  int k = t >> 2, h = t & 3;
  float s = 0.f, d = 0.f;
  const float* wr = Wg1 + (size_t)k * 256 + h * 64;
  const float* pa = atts1 + h * 64;
  const float* pb = attd1 + h * 64;
  #pragma unroll 8
  for (int c = 0; c < 64; c++){ s += wr[c] * pa[c]; d += wr[c] * pb[c]; }
  wa_s[k * 4 + h] = s;
  wa_d[k * 4 + h] = d;
}

// as1[n,h] = h1[n,:] . wa_s[:,h]
__global__ void logits_kernel(const float* __restrict__ h1, const float* __restrict__ wa_s,
                              const float* __restrict__ wa_d, float* __restrict__ as_,
                              float* __restrict__ ad_){
  __shared__ float ws[256], wd[256];
  int t = threadIdx.x;
  ws[t] = wa_s[t];
  wd[t] = wa_d[t];
  __syncthreads();
  int idx = blockIdx.x * 256 + t;
  int n = idx >> 2, h = idx & 3;
  if (n >= NN) return;
  float s = 0.f, d = 0.f;
  const float* hr = h1 + (size_t)n * 64;
  #pragma unroll 4
  for (int k4 = 0; k4 < 16; k4++){
    float4 hv = *(const float4*)(hr + k4 * 4);
    s += hv.x * ws[(k4*4+0)*4+h] + hv.y * ws[(k4*4+1)*4+h]
       + hv.z * ws[(k4*4+2)*4+h] + hv.w * ws[(k4*4+3)*4+h];
    d += hv.x * wd[(k4*4+0)*4+h] + hv.y * wd[(k4*4+1)*4+h]
       + hv.z * wd[(k4*4+2)*4+h] + hv.w * wd[(k4*4+3)*4+h];
  }
  as_[n * 4 + h] = s;
  ad_[n * 4 + h] = d;
}

// ---------------- layer-1 basis-space aggregation (4 edge-groups x float2) ----------------

__global__ void agg1_kernel(const float* __restrict__ x, const float* __restrict__ comp,
                            const int* __restrict__ offs, const int* __restrict__ csr_src,
                            const int* __restrict__ csr_et, float* __restrict__ agg){
  int wid  = (blockIdx.x * blockDim.x + threadIdx.x) >> 6;
  int lane = threadIdx.x & 63;
  if (wid >= NN) return;
  int q = lane & 15, eg = lane >> 4;
  int c2 = q * 2;
  int n0 = offs[wid], n1 = offs[wid + 1];
  float a00 = 0.f, a01 = 0.f, a10 = 0.f, a11 = 0.f;
  float a20 = 0.f, a21 = 0.f, a30 = 0.f, a31 = 0.f;
  for (int k = n0 + eg; k < n1; k += 4){
    int s = csr_src[k], e = csr_et[k];
    float2 v = *(const float2*)(x + (size_t)s * 32 + c2);
    F4 cp = ld4(comp + (size_t)e * 4);
    a00 += cp.x * v.x; a01 += cp.x * v.y;
    a10 += cp.y * v.x; a11 += cp.y * v.y;
    a20 += cp.z * v.x; a21 += cp.z * v.y;
    a30 += cp.w * v.x; a31 += cp.w * v.y;
  }
  #pragma unroll
  for (int o = 16; o < 64; o <<= 1){
    a00 += __shfl_xor(a00, o); a01 += __shfl_xor(a01, o);
    a10 += __shfl_xor(a10, o); a11 += __shfl_xor(a11, o);
    a20 += __shfl_xor(a20, o); a21 += __shfl_xor(a21, o);
    a30 += __shfl_xor(a30, o); a31 += __shfl_xor(a31, o);
  }
  int dg = n1 - n0;
  float sc = 1.f / (float)(dg > 0 ? dg : 1);
  if (lane < 16){
    float* ar = agg + (size_t)wid * 128 + c2;
    *(float2*)(ar)      = make_float2(a00 * sc, a01 * sc);
    *(float2*)(ar + 32) = make_float2(a10 * sc, a11 * sc);
    *(float2*)(ar + 64) = make_float2(a20 * sc, a21 * sc);
    *(float2*)(ar + 96) = make_float2(a30 * sc, a31 * sc);
  }
}

// ---------------- (RPT*16)-row x 64-col fused GEMM (layer 1 only) ----------------

template<int RPT, bool ELU>
__global__ __launch_bounds__(256) void gemmT_kernel(
    const float* __restrict__ A1, int lda1, int K1,
    const float* __restrict__ W1, int ldw1,
    const float* __restrict__ A2, int lda2, int K2,
    const float* __restrict__ W2, int ldw2,
    const float* __restrict__ bias,
    float* __restrict__ Y, int ldy,
    int nrows, int acgoff, int wcgoff)
{
  __shared__ float At[32][RPT * 16 + 4];
  __shared__ float Wl[32][68];
  int t = threadIdx.x;
  int tc = t & 15, tr = t >> 4;
  int cg = blockIdx.x;
  int nbase = blockIdx.y * (RPT * 16);
  float acc[RPT][4];
  #pragma unroll
  for (int j = 0; j < RPT; j++)
    #pragma unroll
    for (int i = 0; i < 4; i++) acc[j][i] = 0.f;

  for (int seg = 0; seg < 2; seg++){
    const float* A = seg ? A2 : A1;
    const float* W = seg ? W2 : W1;
    int lda = seg ? lda2 : lda1;
    int ldw = seg ? ldw2 : ldw1;
    int K   = seg ? K2 : K1;
    if (A == nullptr || K <= 0) continue;
    A += (size_t)cg * acgoff;
    W += (size_t)cg * wcgoff;
    for (int k0 = 0; k0 < K; k0 += 32){
      #pragma unroll
      for (int i = 0; i < 2; i++){
        int e = i * 256 + t;
        int kk = e >> 4, c4 = (e & 15) << 2;
        float4 v = make_float4(0.f, 0.f, 0.f, 0.f);
        if (k0 + kk < K) v = *(const float4*)(W + (size_t)(k0 + kk) * ldw + c4);
        *(float4*)&Wl[kk][c4] = v;
      }
      #pragma unroll
      for (int i = 0; i < RPT / 2; i++){
        int e = i * 256 + t;
        int r = e >> 3, c4 = (e & 7) << 2;
        int n = nbase + r;
        float4 v = make_float4(0.f, 0.f, 0.f, 0.f);
        if (n < nrows && k0 + c4 < K) v = *(const float4*)(A + (size_t)n * lda + k0 + c4);
        At[c4 + 0][r] = v.x;
        At[c4 + 1][r] = v.y;
        At[c4 + 2][r] = v.z;
        At[c4 + 3][r] = v.w;
      }
      __syncthreads();
      #pragma unroll 4
      for (int k = 0; k < 32; k++){
        float4 wv = *(const float4*)&Wl[k][tc * 4];
        const float* pw = (const float*)&wv;
        #pragma unroll
        for (int jj = 0; jj < RPT / 4; jj++){
          float4 av = *(const float4*)&At[k][tr * RPT + jj * 4];
          const float* pa = (const float*)&av;
          #pragma unroll
          for (int j = 0; j < 4; j++)
            #pragma unroll
            for (int i = 0; i < 4; i++)
              acc[jj * 4 + j][i] = fmaf(pa[j], pw[i], acc[jj * 4 + j][i]);
        }
      }
      __syncthreads();
    }
  }

  float b0 = 0.f, b1 = 0.f, b2 = 0.f, b3 = 0.f;
  if (bias){
    b0 = bias[cg * 64 + tc * 4 + 0];
    b1 = bias[cg * 64 + tc * 4 + 1];
    b2 = bias[cg * 64 + tc * 4 + 2];
    b3 = bias[cg * 64 + tc * 4 + 3];
  }
  #pragma unroll
  for (int j = 0; j < RPT; j++){
    int n = nbase + tr * RPT + j;
    if (n < nrows){
      float y0 = acc[j][0] + b0, y1 = acc[j][1] + b1;
      float y2 = acc[j][2] + b2, y3 = acc[j][3] + b3;
      if (ELU){ y0 = eluf(y0); y1 = eluf(y1); y2 = eluf(y2); y3 = eluf(y3); }
      *(float4*)(Y + (size_t)n * ldy + cg * 64 + tc * 4) = make_float4(y0, y1, y2, y3);
    }
  }
}

// ---------------- generic bf16-split MFMA GEMM ----------------
// Y[n, cg*64+c] = act( A[n, cg*acgoff + 0..K-1] @ Bfrags[cg] + bias ), K = KSTEPS*32.
// Block = 4 waves; wave = 64 rows x 64 cols (4x4 frags of 16x16x32). grid = (ncg, ceil(N/256)).

template<int KSTEPS, bool ELU, bool BIAS>
__global__ __launch_bounds__(256) void gemm_mfma_kernel(
    const float* __restrict__ A, int lda, int acgoff,
    const unsigned short* __restrict__ Bhi, const unsigned short* __restrict__ Blo,
    const float* __restrict__ bias, float* __restrict__ Y, int ldy)
{
  int t = threadIdx.x;
  int lane = t & 63, wv = t >> 6;
  int cg = blockIdx.x;
  int mbase = blockIdx.y * 256 + wv * 64;
  int fr = lane & 15;
  int ksub = (lane >> 4) << 3;
  const float* Ab = A + (size_t)cg * acgoff;
  f32x4 acc[4][4];
  #pragma unroll
  for (int mi = 0; mi < 4; mi++)
    #pragma unroll
    for (int ni = 0; ni < 4; ni++)
      acc[mi][ni] = (f32x4){0.f, 0.f, 0.f, 0.f};

  #pragma unroll
  for (int ks = 0; ks < KSTEPS; ks++){
    short8v ahi[4], alo[4];
    #pragma unroll
    for (int mi = 0; mi < 4; mi++){
      int r = mbase + mi * 16 + fr;
      float av[8];
      if (r < NN){
        float4 p0 = *(const float4*)(Ab + (size_t)r * lda + ks * 32 + ksub);
        float4 p1 = *(const float4*)(Ab + (size_t)r * lda + ks * 32 + ksub + 4);
        av[0] = p0.x; av[1] = p0.y; av[2] = p0.z; av[3] = p0.w;
        av[4] = p1.x; av[5] = p1.y; av[6] = p1.z; av[7] = p1.w;
      } else {
        #pragma unroll
        for (int j = 0; j < 8; j++) av[j] = 0.f;
      }
      #pragma unroll
      for (int j = 0; j < 8; j++){
        unsigned short h = f2bf(av[j]);
        float res = av[j] - bf2f(h);
        ahi[mi][j] = (short)h;
        alo[mi][j] = (short)f2bf(res);
      }
    }
    #pragma unroll
    for (int ni = 0; ni < 4; ni++){
      size_t boff = ((((size_t)(cg * 4 + ni)) * KSTEPS + ks) * 64 + lane) * 8;
      short8v bh = *(const short8v*)(Bhi + boff);
      short8v bl = *(const short8v*)(Blo + boff);
      #pragma unroll
      for (int mi = 0; mi < 4; mi++){
        acc[mi][ni] = __builtin_amdgcn_mfma_f32_16x16x32_bf16(ahi[mi], bh, acc[mi][ni], 0, 0, 0);
        acc[mi][ni] = __builtin_amdgcn_mfma_f32_16x16x32_bf16(ahi[mi], bl, acc[mi][ni], 0, 0, 0);
        acc[mi][ni] = __builtin_amdgcn_mfma_f32_16x16x32_bf16(alo[mi], bh, acc[mi][ni], 0, 0, 0);
      }
    }
  }
  int crow = (lane >> 4) << 2;
  #pragma unroll
  for (int mi = 0; mi < 4; mi++){
    #pragma unroll
    for (int reg = 0; reg < 4; reg++){
      int r = mbase + mi * 16 + crow + reg;
      if (r < NN){
        #pragma unroll
        for (int ni = 0; ni < 4; ni++){
          float y = acc[mi][ni][reg];
          if (BIAS) y += bias[cg * 64 + ni * 16 + fr];
          if (ELU)  y = eluf(y);
          Y[(size_t)r * ldy + cg * 64 + ni * 16 + fr] = y;
        }
      }
    }
  }
}

// ---------------- GAT1 aggregate: 4 edge-groups x 16 ch-lanes, 4 heads per lane ----------------
// aggG[n, h*64+c] = ( sum_e alpha_eh * h1[src,c] + alpha_self,h * h1[n,c] )

__global__ void gat1_agg_kernel(const float* __restrict__ h1, const float* __restrict__ as_,
                                const float* __restrict__ ad_, const int* __restrict__ offs,
                                const int* __restrict__ csr_src, float* __restrict__ aggG){
  int wid  = (blockIdx.x * blockDim.x + threadIdx.x) >> 6;
  int lane = threadIdx.x & 63;
  if (wid >= NN) return;
  int n0 = offs[wid], n1 = offs[wid + 1];
  int h = lane & 3;
  // phase 1: per-head max (lane = edge-slot x head)
  float adn_s = ad_[wid * 4 + h];
  float m = leakyf(as_[wid * 4 + h] + adn_s);
  for (int k = n0 + (lane >> 2); k < n1; k += 16){
    int s = csr_src[k];
    m = fmaxf(m, leakyf(as_[s * 4 + h] + adn_s));
  }
  #pragma unroll
  for (int o = 4; o < 64; o <<= 1) m = fmaxf(m, __shfl_xor(m, o));
  float m0 = __shfl(m, 0), m1 = __shfl(m, 1), m2 = __shfl(m, 2), m3 = __shfl(m, 3);
  // phase 2: gather + weighted accumulate, 4 edges in flight per wave
  int q = lane & 15, eg = lane >> 4;
  F4 adn = ld4(ad_ + (size_t)wid * 4);
  float den0 = 0.f, den1 = 0.f, den2 = 0.f, den3 = 0.f;
  float4 ac0 = make_float4(0.f,0.f,0.f,0.f), ac1 = ac0, ac2 = ac0, ac3 = ac0;
  for (int k = n0 + eg; k < n1; k += 4){
    int s = csr_src[k];
    F4 a = ld4(as_ + (size_t)s * 4);
    float p0 = expf(leakyf(a.x + adn.x) - m0);
    float p1 = expf(leakyf(a.y + adn.y) - m1);
    float p2 = expf(leakyf(a.z + adn.z) - m2);
    float p3 = expf(leakyf(a.w + adn.w) - m3);
    den0 += p0; den1 += p1; den2 += p2; den3 += p3;
    float4 v = *(const float4*)(h1 + (size_t)s * 64 + q * 4);
    ac0.x += p0*v.x; ac0.y += p0*v.y; ac0.z += p0*v.z; ac0.w += p0*v.w;
    ac1.x += p1*v.x; ac1.y += p1*v.y; ac1.z += p1*v.z; ac1.w += p1*v.w;
    ac2.x += p2*v.x; ac2.y += p2*v.y; ac2.z += p2*v.z; ac2.w += p2*v.w;
    ac3.x += p3*v.x; ac3.y += p3*v.y; ac3.z += p3*v.z; ac3.w += p3*v.w;
  }
  #pragma unroll
  for (int o = 16; o < 64; o <<= 1){
    den0 += __shfl_xor(den0, o); den1 += __shfl_xor(den1, o);
    den2 += __shfl_xor(den2, o); den3 += __shfl_xor(den3, o);
  }
  ac0 = redeg16(ac0); ac1 = redeg16(ac1); ac2 = redeg16(ac2); ac3 = redeg16(ac3);
  // self term
  F4 asn = ld4(as_ + (size_t)wid * 4);
  float ps0 = expf(leakyf(asn.x + adn.x) - m0);
  float ps1 = expf(leakyf(asn.y + adn.y) - m1);
  float ps2 = expf(leakyf(asn.z + adn.z) - m2);
  float ps3 = expf(leakyf(asn.w + adn.w) - m3);
  if (lane < 16){
    float4 v = *(const float4*)(h1 + (size_t)wid * 64 + q * 4);
    float i0 = 1.f / (den0 + ps0), i1 = 1.f / (den1 + ps1);
    float i2 = 1.f / (den2 + ps2), i3 = 1.f / (den3 + ps3);
    float* ag = aggG + (size_t)wid * 256 + q * 4;
    *(float4*)(ag)       = make_float4((ac0.x+ps0*v.x)*i0, (ac0.y+ps0*v.y)*i0, (ac0.z+ps0*v.z)*i0, (ac0.w+ps0*v.w)*i0);
    *(float4*)(ag + 64)  = make_float4((ac1.x+ps1*v.x)*i1, (ac1.y+ps1*v.y)*i1, (ac1.z+ps1*v.z)*i1, (ac1.w+ps1*v.w)*i1);
    *(float4*)(ag + 128) = make_float4((ac2.x+ps2*v.x)*i2, (ac2.y+ps2*v.y)*i2, (ac2.z+ps2*v.z)*i2, (ac2.w+ps2*v.w)*i2);
    *(float4*)(ag + 192) = make_float4((ac3.x+ps3*v.x)*i3, (ac3.y+ps3*v.y)*i3, (ac3.z+ps3*v.z)*i3, (ac3.w+ps3*v.w)*i3);
  }
}

// ---------------- layer-3: per-relation message table (bf16) ----------------

__global__ void xr_kernel(const float* __restrict__ xb2, const float* __restrict__ comp2,
                          unsigned short* __restrict__ xr){
  int idx = blockIdx.x * 256 + threadIdx.x;
  if (idx >= NN * 16) return;
  int n = idx >> 4, q = idx & 15;
  float4 xv[4];
  #pragma unroll
  for (int b = 0; b < 4; b++)
    xv[b] = *(const float4*)(xb2 + (size_t)n * 384 + b * 64 + q * 4);
  #pragma unroll
  for (int r = 0; r < 8; r++){
    float c0 = comp2[r * 4 + 0], c1 = comp2[r * 4 + 1];
    float c2 = comp2[r * 4 + 2], c3 = comp2[r * 4 + 3];
    float m0 = c0 * xv[0].x + c1 * xv[1].x + c2 * xv[2].x + c3 * xv[3].x;
    float m1 = c0 * xv[0].y + c1 * xv[1].y + c2 * xv[2].y + c3 * xv[3].y;
    float m2 = c0 * xv[0].z + c1 * xv[1].z + c2 * xv[2].z + c3 * xv[3].z;
    float m3 = c0 * xv[0].w + c1 * xv[1].w + c2 * xv[2].w + c3 * xv[3].w;
    ushort4 u;
    u.x = f2bf(m0); u.y = f2bf(m1); u.z = f2bf(m2); u.w = f2bf(m3);
    *(ushort4*)(xr + ((size_t)n * 8 + r) * 64 + q * 4) = u;
  }
}

// layer-3 aggregate: 8 edge-groups x 8 ch-lanes (ushort8 = 16B per gather)
__global__ void rgcn2_agg_kernel(const unsigned short* __restrict__ xr,
                                 const float* __restrict__ xb,
                                 const float* __restrict__ bias, const int* __restrict__ offs,
                                 const int* __restrict__ csr_src, const int* __restrict__ csr_et,
                                 float* __restrict__ h3){
  int wid  = (blockIdx.x * blockDim.x + threadIdx.x) >> 6;
  int lane = threadIdx.x & 63;
  if (wid >= NN) return;
  int q = lane & 7, eg = lane >> 3;
  int n0 = offs[wid], n1 = offs[wid + 1];
  float a[8];
  #pragma unroll
  for (int j = 0; j < 8; j++) a[j] = 0.f;
  for (int k = n0 + eg; k < n1; k += 8){
    int s = csr_src[k], e = csr_et[k];
    short8v u = *(const short8v*)(xr + ((size_t)s * 8 + e) * 64 + q * 8);
    #pragma unroll
    for (int j = 0; j < 8; j++) a[j] += bf2f((unsigned short)u[j]);
  }
  #pragma unroll
  for (int o = 8; o < 64; o <<= 1){
    #pragma unroll
    for (int j = 0; j < 8; j++) a[j] += __shfl_xor(a[j], o);
  }
  int dg = n1 - n0;
  float sc = 1.f / (float)(dg > 0 ? dg : 1);
  if (lane < 8){
    const float* rb = xb + (size_t)wid * 384 + 256 + q * 8;
    float4 r0 = *(const float4*)(rb);
    float4 r1 = *(const float4*)(rb + 4);
    float4 b0 = *(const float4*)(bias + q * 8);
    float4 b1 = *(const float4*)(bias + q * 8 + 4);
    float* hp = h3 + (size_t)wid * 64 + q * 8;
    *(float4*)(hp)     = make_float4(eluf(a[0]*sc + r0.x + b0.x), eluf(a[1]*sc + r0.y + b0.y),
                                     eluf(a[2]*sc + r0.z + b0.z), eluf(a[3]*sc + r0.w + b0.w));
    *(float4*)(hp + 4) = make_float4(eluf(a[4]*sc + r1.x + b1.x), eluf(a[5]*sc + r1.y + b1.y),
                                     eluf(a[6]*sc + r1.z + b1.z), eluf(a[7]*sc + r1.w + b1.w));
  }
}

// ---------------- GAT2 ----------------

__global__ void gat_lin2_kernel(const float* __restrict__ h, const float* __restrict__ W,
                                const float* __restrict__ atts, const float* __restrict__ attd,
                                float* __restrict__ hw, float* __restrict__ as_, float* __restrict__ ad_){
  int wid  = (blockIdx.x * blockDim.x + threadIdx.x) >> 6;
  int lane = threadIdx.x & 63;
  if (wid >= NN) return;
  float acc = 0.f;
  if (lane < 12){
    const float* hr = h + (size_t)wid * 64;
    const float* Wc = W + lane;
    #pragma unroll 8
    for (int i = 0; i < 64; i++) acc += hr[i] * Wc[(size_t)i * 12];
    hw[(size_t)wid * 12 + lane] = acc;
  }
  float ts = (lane < 12) ? acc * atts[lane] : 0.f;
  float td = (lane < 12) ? acc * attd[lane] : 0.f;
  int b = (lane < 4) ? lane * 3 : 0;
  float s0 = __shfl(ts, b) + __shfl(ts, b + 1) + __shfl(ts, b + 2);
  float d0 = __shfl(td, b) + __shfl(td, b + 1) + __shfl(td, b + 2);
  if (lane < 4){ as_[wid * 4 + lane] = s0; ad_[wid * 4 + lane] = d0; }
}

__global__ void gat2_final_kernel(const float* __restrict__ hw, const float* __restrict__ as_,
                                  const float* __restrict__ ad_, const float* __restrict__ bg2,
                                  const int* __restrict__ offs, const int* __restrict__ csr_src,
                                  float* __restrict__ out){
  int wid  = (blockIdx.x * blockDim.x + threadIdx.x) >> 6;
  int lane = threadIdx.x & 63;
  if (wid >= NN) return;
  int n0 = offs[wid], n1 = offs[wid + 1];
  F4 adn = ld4(ad_ + (size_t)wid * 4);
  F4 asn = ld4(as_ + (size_t)wid * 4);
  F4 es{leakyf(asn.x + adn.x), leakyf(asn.y + adn.y), leakyf(asn.z + adn.z), leakyf(asn.w + adn.w)};
  F4 m = es;
  for (int k = n0 + lane; k < n1; k += 64){
    int s = csr_src[k];
    F4 a = ld4(as_ + (size_t)s * 4);
    m.x = fmaxf(m.x, leakyf(a.x + adn.x));
    m.y = fmaxf(m.y, leakyf(a.y + adn.y));
    m.z = fmaxf(m.z, leakyf(a.z + adn.z));
    m.w = fmaxf(m.w, leakyf(a.w + adn.w));
  }
  #pragma unroll
  for (int o = 32; o; o >>= 1){
    m.x = fmaxf(m.x, __shfl_xor(m.x, o));
    m.y = fmaxf(m.y, __shfl_xor(m.y, o));
    m.z = fmaxf(m.z, __shfl_xor(m.z, o));
    m.w = fmaxf(m.w, __shfl_xor(m.w, o));
  }
  F4 ps{expf(es.x - m.x), expf(es.y - m.y), expf(es.z - m.z), expf(es.w - m.w)};
  float acc[12];
  #pragma unroll
  for (int j = 0; j < 12; j++) acc[j] = 0.f;
  F4 denp{0.f, 0.f, 0.f, 0.f};
  for (int k = n0 + lane; k < n1; k += 64){
    int s = csr_src[k];
    F4 a = ld4(as_ + (size_t)s * 4);
    F4 p{expf(leakyf(a.x + adn.x) - m.x), expf(leakyf(a.y + adn.y) - m.y),
         expf(leakyf(a.z + adn.z) - m.z), expf(leakyf(a.w + adn.w) - m.w)};
    denp.x += p.x; denp.y += p.y; denp.z += p.z; denp.w += p.w;
    const float* hb = hw + (size_t)s * 12;
    F4 h0 = ld4(hb), h1 = ld4(hb + 4), h2 = ld4(hb + 8);
    acc[0] += p.x * h0.x; acc[1]  += p.x * h0.y; acc[2]  += p.x * h0.z;
    acc[3] += p.y * h0.w; acc[4]  += p.y * h1.x; acc[5]  += p.y * h1.y;
    acc[6] += p.z * h1.z; acc[7]  += p.z * h1.w; acc[8]  += p.z * h2.x;
    acc[9] += p.w * h2.y; acc[10] += p.w * h2.z; acc[11] += p.w * h2.w;
  }
  #pragma unroll
  for (int o = 32; o; o >>= 1){
    denp.x += __shfl_xor(denp.x, o);
    denp.y += __shfl_xor(denp.y, o);
    denp.z += __shfl_xor(denp.z, o);
    denp.w += __shfl_xor(denp.w, o);
    #pragma unroll
    for (int j = 0; j < 12; j++) acc[j] += __shfl_xor(acc[j], o);
  }
  if (lane == 0){
    const float* hn = hw + (size_t)wid * 12;
    float dn[4]  = {denp.x + ps.x, denp.y + ps.y, denp.z + ps.z, denp.w + ps.w};
    float psv[4] = {ps.x, ps.y, ps.z, ps.w};
    float tot = 0.f;
    #pragma unroll
    for (int h_ = 0; h_ < 4; h_++){
      #pragma unroll
      for (int c = 0; c < 3; c++){
        float num = acc[h_ * 3 + c] + psv[h_] * hn[h_ * 3 + c];
        tot += num / dn[h_];
      }
    }
    tot = tot / 12.f + (bg2[0] + bg2[1] + bg2[2]) / 3.f;
    out[wid] = tanhf(tot);
  }
}

// ---------------- launch ----------------

extern "C" void kernel_launch(void* const* d_in, const int* in_sizes, int n_in,
                              void* d_out, int out_size, void* d_ws, size_t ws_size,
                              hipStream_t stream){
  const float* x      = (const float*)d_in[0];
  const int*   ei     = (const int*)d_in[1];
  const int*   et     = (const int*)d_in[2];
  const float* basis1 = (const float*)d_in[3];
  const float* comp1  = (const float*)d_in[4];
  const float* root1  = (const float*)d_in[5];
  const float* brg1   = (const float*)d_in[6];
  const float* Wg1    = (const float*)d_in[7];
  const float* atts1  = (const float*)d_in[8];
  const float* attd1  = (const float*)d_in[9];
  const float* bg1    = (const float*)d_in[10];
  const float* basis2 = (const float*)d_in[11];
  const float* comp2  = (const float*)d_in[12];
  const float* root2  = (const float*)d_in[13];
  const float* brg2   = (const float*)d_in[14];
  const float* Wg2    = (const float*)d_in[15];
  const float* atts2  = (const float*)d_in[16];
  const float* attd2  = (const float*)d_in[17];
  const float* bg2    = (const float*)d_in[18];
  float* out = (float*)d_out;

  const int* src = ei;
  const int* dst = ei + NE;

  char* ws = (char*)d_ws;
  size_t off = 0;
  auto alloc = [&](size_t bytes) -> void* {
    void* p = ws + off;
    off = (off + bytes + 255) & ~(size_t)255;
    return p;
  };
  // persistent
  int*   deg     = (int*)alloc((size_t)NN * 4);
  int*   cursor  = (int*)alloc((size_t)NN * 4);
  int*   offs    = (int*)alloc((size_t)(NN + 1) * 4);
  int*   bsum    = (int*)alloc((size_t)256 * 4);
  int*   csr_src = (int*)alloc((size_t)NE * 4);
  int*   csr_et  = (int*)alloc((size_t)NE * 4);
  float* Wcat2   = (float*)alloc((size_t)256 * 384 * 4);
  unsigned short* Bhi2 = (unsigned short*)alloc((size_t)81920 * 2);  // L3: 5*4*8*64*8
  unsigned short* Blo2 = (unsigned short*)alloc((size_t)81920 * 2);
  unsigned short* Bhi1 = (unsigned short*)alloc((size_t)16384 * 2);  // GAT1: 4*4*2*64*8
  unsigned short* Blo1 = (unsigned short*)alloc((size_t)16384 * 2);
  float* wa_s    = (float*)alloc((size_t)256 * 4);
  float* wa_d    = (float*)alloc((size_t)256 * 4);
  float* h1      = (float*)alloc((size_t)NN * 64 * 4);
  float* h2      = (float*)alloc((size_t)NN * 256 * 4);
  float* h3      = (float*)alloc((size_t)NN * 64 * 4);
  float* hw2     = (float*)alloc((size_t)NN * 12 * 4);
  float* as1     = (float*)alloc((size_t)NN * 4 * 4);
  float* ad1     = (float*)alloc((size_t)NN * 4 * 4);
  float* as2     = (float*)alloc((size_t)NN * 4 * 4);
  float* ad2     = (float*)alloc((size_t)NN * 4 * 4);
  // scratch union: agg1[NN*128] -> aggG[NN*256] -> xb2[NN*384]
  float* S       = (float*)alloc((size_t)NN * 384 * 4);
  float* agg1    = S;
  float* aggG    = S;
  float* xb2     = S;
  // xr (bf16) aliases h1+h2: h1 dead after GAT1 gemm, h2 dead after L3 gemm.
  unsigned short* xr = (unsigned short*)h1;
  (void)ws_size; (void)n_in; (void)in_sizes; (void)out_size;

  const int BLK = 256;
  int gridN   = (NN + BLK - 1) / BLK;
  int gridE   = (NE + BLK - 1) / BLK;
  int gridW   = (NN + 3) / 4;
  int gridM64 = (NN + 63) / 64;     // 469
  int gridM256= (NN + 255) / 256;   // 118

  // CSR build + weight prep
  zero2_kernel<<<gridN, BLK, 0, stream>>>(deg, cursor, NN);
  count_kernel<<<gridE, BLK, 0, stream>>>(dst, deg, NE);
  wcat2_kernel<<<(256 * 384 + 255) / 256, BLK, 0, stream>>>(basis2, root2, Wcat2);
  packB_kernel<<<(10240 + 255) / 256, BLK, 0, stream>>>(Wcat2, 384, 8, 10240, Bhi2, Blo2);
  packB_kernel<<<(2048 + 255) / 256, BLK, 0, stream>>>(Wg1, 256, 2, 2048, Bhi1, Blo1);
  wa_kernel<<<1, BLK, 0, stream>>>(Wg1, atts1, attd1, wa_s, wa_d);
  scan1_kernel<<<gridN, BLK, 0, stream>>>(deg, offs, bsum);
  scan2_kernel<<<1, BLK, 0, stream>>>(bsum, gridN);
  scan3_kernel<<<gridN, BLK, 0, stream>>>(bsum, offs);
  scatter_kernel<<<gridE, BLK, 0, stream>>>(src, dst, et, offs, cursor, csr_src, csr_et, NE);

  // Layer 1: RGCN (32 -> 64) + elu
  agg1_kernel<<<gridW, BLK, 0, stream>>>(x, comp1, offs, csr_src, csr_et, agg1);
  gemmT_kernel<4, true><<<dim3(1, gridM64), BLK, 0, stream>>>(
      agg1, 128, 128, basis1, 64,
      x, 32, 32, root1, 64,
      brg1, h1, 64, NN, 0, 0);

  // Layer 2: GAT (64 -> 256 concat) + elu: logits -> aggregate h1 -> MFMA block-diag GEMM
  logits_kernel<<<(NN * 4 + 255) / 256, BLK, 0, stream>>>(h1, wa_s, wa_d, as1, ad1);
  gat1_agg_kernel<<<gridW, BLK, 0, stream>>>(h1, as1, ad1, offs, csr_src, aggG);
  gemm_mfma_kernel<2, true, true><<<dim3(4, gridM256), BLK, 0, stream>>>(
      aggG, 256, 64, Bhi1, Blo1, bg1, h2, 256);

  // Layer 3: RGCN (256 -> 64) + elu: bf16-split MFMA transform + bf16 message table
  gemm_mfma_kernel<8, false, false><<<dim3(5, gridM256), BLK, 0, stream>>>(
      h2, 256, 0, Bhi2, Blo2, nullptr, xb2, 384);
  xr_kernel<<<(NN * 16 + 255) / 256, BLK, 0, stream>>>(xb2, comp2, xr);
  rgcn2_agg_kernel<<<gridW, BLK, 0, stream>>>(xr, xb2, brg2, offs, csr_src, csr_et, h3);

  // Layer 4: GAT (64 -> 4x3, mean heads) + mean classes + tanh
  gat_lin2_kernel<<<gridW, BLK, 0, stream>>>(h3, Wg2, atts2, attd2, hw2, as2, ad2);
  gat2_final_kernel<<<gridW, BLK, 0, stream>>>(hw2, as2, ad2, bg2, offs, csr_src, out);
}

// Round 15
// 334.461 us; speedup vs baseline: 1.3861x; 1.0245x over previous
//
#include <hip/hip_runtime.h>
#include <cstdint>
#include <cstddef>

#define NN 30000
#define NE 480000

typedef __attribute__((ext_vector_type(8))) short short8v;
typedef __attribute__((ext_vector_type(4))) float f32x4;

__device__ __forceinline__ float leakyf(float x){ return x > 0.f ? x : 0.2f * x; }
__device__ __forceinline__ float eluf(float x){ return x > 0.f ? x : expm1f(x); }

__device__ __forceinline__ float bf2f(unsigned short u){
  return __uint_as_float(((unsigned)u) << 16);
}
__device__ __forceinline__ unsigned short f2bf(float f){
  unsigned x = __float_as_uint(f);
  unsigned r = (x + 0x7FFFu + ((x >> 16) & 1u)) >> 16;
  return (unsigned short)r;
}

struct F4 { float x, y, z, w; };

__device__ __forceinline__ F4 ld4(const float* p){
  float4 v = *(const float4*)p;
  return F4{v.x, v.y, v.z, v.w};
}

__device__ __forceinline__ float4 redeg16(float4 v){
  v.x += __shfl_xor(v.x, 16); v.y += __shfl_xor(v.y, 16);
  v.z += __shfl_xor(v.z, 16); v.w += __shfl_xor(v.w, 16);
  v.x += __shfl_xor(v.x, 32); v.y += __shfl_xor(v.y, 32);
  v.z += __shfl_xor(v.z, 32); v.w += __shfl_xor(v.w, 32);
  return v;
}

// ---------------- CSR build ----------------

__global__ void zero2_kernel(int* __restrict__ a, int* __restrict__ b, int n){
  int i = blockIdx.x * blockDim.x + threadIdx.x;
  if (i < n){ a[i] = 0; b[i] = 0; }
}

__global__ void count_kernel(const int* __restrict__ dst, int* __restrict__ deg, int E){
  int i = blockIdx.x * blockDim.x + threadIdx.x;
  if (i < E) atomicAdd(&deg[dst[i]], 1);
}

__global__ void scan1_kernel(const int* __restrict__ deg, int* __restrict__ offs,
                             int* __restrict__ bsum){
  __shared__ int sh[256];
  int blk = blockIdx.x, t = threadIdx.x, i = blk * 256 + t;
  int v = (i < NN) ? deg[i] : 0;
  sh[t] = v; __syncthreads();
  for (int o = 1; o < 256; o <<= 1){
    int tv = (t >= o) ? sh[t - o] : 0;
    __syncthreads();
    sh[t] += tv;
    __syncthreads();
  }
  if (i < NN) offs[i + 1] = sh[t];
  if (t == 255) bsum[blk] = sh[255];
}

__global__ void scan2_kernel(int* __restrict__ bsum, int nb){
  __shared__ int sh[256];
  int t = threadIdx.x;
  int v = (t < nb) ? bsum[t] : 0;
  sh[t] = v; __syncthreads();
  for (int o = 1; o < 256; o <<= 1){
    int tv = (t >= o) ? sh[t - o] : 0;
    __syncthreads();
    sh[t] += tv;
    __syncthreads();
  }
  if (t < nb) bsum[t] = sh[t];
}

__global__ void scan3_kernel(const int* __restrict__ bsum, int* __restrict__ offs){
  int i = blockIdx.x * 256 + threadIdx.x;
  if (i == 0) offs[0] = 0;
  if (i < NN){
    int blk = i >> 8;
    int add = blk ? bsum[blk - 1] : 0;
    offs[i + 1] += add;
  }
}

__global__ void scatter_kernel(const int* __restrict__ src, const int* __restrict__ dst,
                               const int* __restrict__ et, const int* __restrict__ offs,
                               int* __restrict__ cursor, int* __restrict__ csr_src,
                               int* __restrict__ csr_et, int E){
  int i = blockIdx.x * blockDim.x + threadIdx.x;
  if (i < E){
    int d = dst[i];
    int pos = offs[d] + atomicAdd(&cursor[d], 1);
    csr_src[pos] = src[i];
    csr_et[pos]  = et[i];
  }
}

// ---------------- weight prep ----------------
// Wcat2 [256][384]: cols 0..255 = basis2 (4 bases x 64), 256..319 = root2, 320..383 = 0.

__global__ void wcat2_kernel(const float* __restrict__ basis2, const float* __restrict__ root2,
                             float* __restrict__ Wcat){
  int idx = blockIdx.x * 256 + threadIdx.x;
  if (idx >= 256 * 384) return;
  int k = idx / 384, col = idx - k * 384;
  float v = 0.f;
  if (col < 256){
    int b = col >> 6, c = col & 63;
    v = basis2[((size_t)b * 256 + k) * 64 + c];
  } else if (col < 320){
    v = root2[(size_t)k * 64 + (col - 256)];
  }
  Wcat[idx] = v;
}

// generic MFMA B-fragment pack, bf16 hi/lo split.
// idx = (nf16*ksteps + ks)*64 + lane; element W[ks*32+(lane>>4)*8+j][nf16*16+(lane&15)]
__global__ void packB_kernel(const float* __restrict__ W, int ldw, int ksteps, int total,
                             unsigned short* __restrict__ Bhi, unsigned short* __restrict__ Blo){
  int idx = blockIdx.x * 256 + threadIdx.x;
  if (idx >= total) return;
  int lane = idx & 63;
  int rest = idx >> 6;
  int ks = rest % ksteps;
  int nf16 = rest / ksteps;
  int col = nf16 * 16 + (lane & 15);
  int kbase = ks * 32 + ((lane >> 4) << 3);
  size_t obase = (size_t)idx * 8;
  #pragma unroll
  for (int j = 0; j < 8; j++){
    float v = W[(size_t)(kbase + j) * ldw + col];
    unsigned short h = f2bf(v);
    float res = v - bf2f(h);
    Bhi[obase + j] = h;
    Blo[obase + j] = f2bf(res);
  }
}

// wa_s[k*4+h] = sum_c Wg1[k, h*64+c] * atts1[h,c]  (and wa_d with attd1)
__global__ void wa_kernel(const float* __restrict__ Wg1, const float* __restrict__ atts1,
                          const float* __restrict__ attd1, float* __restrict__ wa_s,
                          float* __restrict__ wa_d){
  int t = threadIdx.x;
  int k = t >> 2, h = t & 3;
  float s = 0.f, d = 0.f;
  const float* wr = Wg1 + (size_t)k * 256 + h * 64;
  const float* pa = atts1 + h * 64;
  const float* pb = attd1 + h * 64;
  #pragma unroll 8
  for (int c = 0; c < 64; c++){ s += wr[c] * pa[c]; d += wr[c] * pb[c]; }
  wa_s[k * 4 + h] = s;
  wa_d[k * 4 + h] = d;
}

// as1[n,h] = h1[n,:] . wa_s[:,h]
__global__ void logits_kernel(const float* __restrict__ h1, const float* __restrict__ wa_s,
                              const float* __restrict__ wa_d, float* __restrict__ as_,
                              float* __restrict__ ad_){
  __shared__ float ws[256], wd[256];
  int t = threadIdx.x;
  ws[t] = wa_s[t];
  wd[t] = wa_d[t];
  __syncthreads();
  int idx = blockIdx.x * 256 + t;
  int n = idx >> 2, h = idx & 3;
  if (n >= NN) return;
  float s = 0.f, d = 0.f;
  const float* hr = h1 + (size_t)n * 64;
  #pragma unroll 4
  for (int k4 = 0; k4 < 16; k4++){
    float4 hv = *(const float4*)(hr + k4 * 4);
    s += hv.x * ws[(k4*4+0)*4+h] + hv.y * ws[(k4*4+1)*4+h]
       + hv.z * ws[(k4*4+2)*4+h] + hv.w * ws[(k4*4+3)*4+h];
    d += hv.x * wd[(k4*4+0)*4+h] + hv.y * wd[(k4*4+1)*4+h]
       + hv.z * wd[(k4*4+2)*4+h] + hv.w * wd[(k4*4+3)*4+h];
  }
  as_[n * 4 + h] = s;
  ad_[n * 4 + h] = d;
}

// ---------------- layer-1 basis-space aggregation (4 edge-groups x float2) ----------------

__global__ void agg1_kernel(const float* __restrict__ x, const float* __restrict__ comp,
                            const int* __restrict__ offs, const int* __restrict__ csr_src,
                            const int* __restrict__ csr_et, float* __restrict__ agg){
  int wid  = (blockIdx.x * blockDim.x + threadIdx.x) >> 6;
  int lane = threadIdx.x & 63;
  if (wid >= NN) return;
  int q = lane & 15, eg = lane >> 4;
  int c2 = q * 2;
  int n0 = offs[wid], n1 = offs[wid + 1];
  float a00 = 0.f, a01 = 0.f, a10 = 0.f, a11 = 0.f;
  float a20 = 0.f, a21 = 0.f, a30 = 0.f, a31 = 0.f;
  for (int k = n0 + eg; k < n1; k += 4){
    int s = csr_src[k], e = csr_et[k];
    float2 v = *(const float2*)(x + (size_t)s * 32 + c2);
    F4 cp = ld4(comp + (size_t)e * 4);
    a00 += cp.x * v.x; a01 += cp.x * v.y;
    a10 += cp.y * v.x; a11 += cp.y * v.y;
    a20 += cp.z * v.x; a21 += cp.z * v.y;
    a30 += cp.w * v.x; a31 += cp.w * v.y;
  }
  #pragma unroll
  for (int o = 16; o < 64; o <<= 1){
    a00 += __shfl_xor(a00, o); a01 += __shfl_xor(a01, o);
    a10 += __shfl_xor(a10, o); a11 += __shfl_xor(a11, o);
    a20 += __shfl_xor(a20, o); a21 += __shfl_xor(a21, o);
    a30 += __shfl_xor(a30, o); a31 += __shfl_xor(a31, o);
  }
  int dg = n1 - n0;
  float sc = 1.f / (float)(dg > 0 ? dg : 1);
  if (lane < 16){
    float* ar = agg + (size_t)wid * 128 + c2;
    *(float2*)(ar)      = make_float2(a00 * sc, a01 * sc);
    *(float2*)(ar + 32) = make_float2(a10 * sc, a11 * sc);
    *(float2*)(ar + 64) = make_float2(a20 * sc, a21 * sc);
    *(float2*)(ar + 96) = make_float2(a30 * sc, a31 * sc);
  }
}

// ---------------- (RPT*16)-row x 64-col fused GEMM (layer 1 only) ----------------

template<int RPT, bool ELU>
__global__ __launch_bounds__(256) void gemmT_kernel(
    const float* __restrict__ A1, int lda1, int K1,
    const float* __restrict__ W1, int ldw1,
    const float* __restrict__ A2, int lda2, int K2,
    const float* __restrict__ W2, int ldw2,
    const float* __restrict__ bias,
    float* __restrict__ Y, int ldy,
    int nrows, int acgoff, int wcgoff)
{
  __shared__ float At[32][RPT * 16 + 4];
  __shared__ float Wl[32][68];
  int t = threadIdx.x;
  int tc = t & 15, tr = t >> 4;
  int cg = blockIdx.x;
  int nbase = blockIdx.y * (RPT * 16);
  float acc[RPT][4];
  #pragma unroll
  for (int j = 0; j < RPT; j++)
    #pragma unroll
    for (int i = 0; i < 4; i++) acc[j][i] = 0.f;

  for (int seg = 0; seg < 2; seg++){
    const float* A = seg ? A2 : A1;
    const float* W = seg ? W2 : W1;
    int lda = seg ? lda2 : lda1;
    int ldw = seg ? ldw2 : ldw1;
    int K   = seg ? K2 : K1;
    if (A == nullptr || K <= 0) continue;
    A += (size_t)cg * acgoff;
    W += (size_t)cg * wcgoff;
    for (int k0 = 0; k0 < K; k0 += 32){
      #pragma unroll
      for (int i = 0; i < 2; i++){
        int e = i * 256 + t;
        int kk = e >> 4, c4 = (e & 15) << 2;
        float4 v = make_float4(0.f, 0.f, 0.f, 0.f);
        if (k0 + kk < K) v = *(const float4*)(W + (size_t)(k0 + kk) * ldw + c4);
        *(float4*)&Wl[kk][c4] = v;
      }
      #pragma unroll
      for (int i = 0; i < RPT / 2; i++){
        int e = i * 256 + t;
        int r = e >> 3, c4 = (e & 7) << 2;
        int n = nbase + r;
        float4 v = make_float4(0.f, 0.f, 0.f, 0.f);
        if (n < nrows && k0 + c4 < K) v = *(const float4*)(A + (size_t)n * lda + k0 + c4);
        At[c4 + 0][r] = v.x;
        At[c4 + 1][r] = v.y;
        At[c4 + 2][r] = v.z;
        At[c4 + 3][r] = v.w;
      }
      __syncthreads();
      #pragma unroll 4
      for (int k = 0; k < 32; k++){
        float4 wv = *(const float4*)&Wl[k][tc * 4];
        const float* pw = (const float*)&wv;
        #pragma unroll
        for (int jj = 0; jj < RPT / 4; jj++){
          float4 av = *(const float4*)&At[k][tr * RPT + jj * 4];
          const float* pa = (const float*)&av;
          #pragma unroll
          for (int j = 0; j < 4; j++)
            #pragma unroll
            for (int i = 0; i < 4; i++)
              acc[jj * 4 + j][i] = fmaf(pa[j], pw[i], acc[jj * 4 + j][i]);
        }
      }
      __syncthreads();
    }
  }

  float b0 = 0.f, b1 = 0.f, b2 = 0.f, b3 = 0.f;
  if (bias){
    b0 = bias[cg * 64 + tc * 4 + 0];
    b1 = bias[cg * 64 + tc * 4 + 1];
    b2 = bias[cg * 64 + tc * 4 + 2];
    b3 = bias[cg * 64 + tc * 4 + 3];
  }
  #pragma unroll
  for (int j = 0; j < RPT; j++){
    int n = nbase + tr * RPT + j;
    if (n < nrows){
      float y0 = acc[j][0] + b0, y1 = acc[j][1] + b1;
      float y2 = acc[j][2] + b2, y3 = acc[j][3] + b3;
      if (ELU){ y0 = eluf(y0); y1 = eluf(y1); y2 = eluf(y2); y3 = eluf(y3); }
      *(float4*)(Y + (size_t)n * ldy + cg * 64 + tc * 4) = make_float4(y0, y1, y2, y3);
    }
  }
}

// ---------------- generic bf16-split MFMA GEMM (GAT1 block-diag) ----------------

template<int KSTEPS, bool ELU, bool BIAS>
__global__ __launch_bounds__(256) void gemm_mfma_kernel(
    const float* __restrict__ A, int lda, int acgoff,
    const unsigned short* __restrict__ Bhi, const unsigned short* __restrict__ Blo,
    const float* __restrict__ bias, float* __restrict__ Y, int ldy)
{
  int t = threadIdx.x;
  int lane = t & 63, wv = t >> 6;
  int cg = blockIdx.x;
  int mbase = blockIdx.y * 256 + wv * 64;
  int fr = lane & 15;
  int ksub = (lane >> 4) << 3;
  const float* Ab = A + (size_t)cg * acgoff;
  f32x4 acc[4][4];
  #pragma unroll
  for (int mi = 0; mi < 4; mi++)
    #pragma unroll
    for (int ni = 0; ni < 4; ni++)
      acc[mi][ni] = (f32x4){0.f, 0.f, 0.f, 0.f};

  #pragma unroll
  for (int ks = 0; ks < KSTEPS; ks++){
    short8v ahi[4], alo[4];
    #pragma unroll
    for (int mi = 0; mi < 4; mi++){
      int r = mbase + mi * 16 + fr;
      float av[8];
      if (r < NN){
        float4 p0 = *(const float4*)(Ab + (size_t)r * lda + ks * 32 + ksub);
        float4 p1 = *(const float4*)(Ab + (size_t)r * lda + ks * 32 + ksub + 4);
        av[0] = p0.x; av[1] = p0.y; av[2] = p0.z; av[3] = p0.w;
        av[4] = p1.x; av[5] = p1.y; av[6] = p1.z; av[7] = p1.w;
      } else {
        #pragma unroll
        for (int j = 0; j < 8; j++) av[j] = 0.f;
      }
      #pragma unroll
      for (int j = 0; j < 8; j++){
        unsigned short h = f2bf(av[j]);
        float res = av[j] - bf2f(h);
        ahi[mi][j] = (short)h;
        alo[mi][j] = (short)f2bf(res);
      }
    }
    #pragma unroll
    for (int ni = 0; ni < 4; ni++){
      size_t boff = ((((size_t)(cg * 4 + ni)) * KSTEPS + ks) * 64 + lane) * 8;
      short8v bh = *(const short8v*)(Bhi + boff);
      short8v bl = *(const short8v*)(Blo + boff);
      #pragma unroll
      for (int mi = 0; mi < 4; mi++){
        acc[mi][ni] = __builtin_amdgcn_mfma_f32_16x16x32_bf16(ahi[mi], bh, acc[mi][ni], 0, 0, 0);
        acc[mi][ni] = __builtin_amdgcn_mfma_f32_16x16x32_bf16(ahi[mi], bl, acc[mi][ni], 0, 0, 0);
        acc[mi][ni] = __builtin_amdgcn_mfma_f32_16x16x32_bf16(alo[mi], bh, acc[mi][ni], 0, 0, 0);
      }
    }
  }
  int crow = (lane >> 4) << 2;
  #pragma unroll
  for (int mi = 0; mi < 4; mi++){
    #pragma unroll
    for (int reg = 0; reg < 4; reg++){
      int r = mbase + mi * 16 + crow + reg;
      if (r < NN){
        #pragma unroll
        for (int ni = 0; ni < 4; ni++){
          float y = acc[mi][ni][reg];
          if (BIAS) y += bias[cg * 64 + ni * 16 + fr];
          if (ELU)  y = eluf(y);
          Y[(size_t)r * ldy + cg * 64 + ni * 16 + fr] = y;
        }
      }
    }
  }
}

// ---------------- L3 fused MFMA GEMM: A read ONCE, xr + root produced in epilogue ----------
// wave = 16 rows x 320 cols (acc[20]); block = 4 waves = 64 rows; grid = 469.
// Epilogue: xr[n,r,o] = sum_b comp2[r,b]*C[n, b*64+o] (bf16), rootb[n,o] = C[n, 256+o] (fp32).

__global__ __launch_bounds__(256) void gemm_l3_fused_kernel(
    const float* __restrict__ A,
    const unsigned short* __restrict__ Bhi, const unsigned short* __restrict__ Blo,
    const float* __restrict__ comp2,
    unsigned short* __restrict__ xr, float* __restrict__ rootb)
{
  int t = threadIdx.x;
  int lane = t & 63, wv = t >> 6;
  int mbase = blockIdx.x * 64 + wv * 16;
  int fr = lane & 15;
  int ksub = (lane >> 4) << 3;
  f32x4 acc[20];
  #pragma unroll
  for (int ni = 0; ni < 20; ni++) acc[ni] = (f32x4){0.f, 0.f, 0.f, 0.f};

  int ar = mbase + fr;
  bool arok = (ar < NN);
  for (int ks = 0; ks < 8; ks++){
    float av[8];
    if (arok){
      float4 p0 = *(const float4*)(A + (size_t)ar * 256 + ks * 32 + ksub);
      float4 p1 = *(const float4*)(A + (size_t)ar * 256 + ks * 32 + ksub + 4);
      av[0] = p0.x; av[1] = p0.y; av[2] = p0.z; av[3] = p0.w;
      av[4] = p1.x; av[5] = p1.y; av[6] = p1.z; av[7] = p1.w;
    } else {
      #pragma unroll
      for (int j = 0; j < 8; j++) av[j] = 0.f;
    }
    short8v ahi, alo;
    #pragma unroll
    for (int j = 0; j < 8; j++){
      unsigned short h = f2bf(av[j]);
      float res = av[j] - bf2f(h);
      ahi[j] = (short)h;
      alo[j] = (short)f2bf(res);
    }
    #pragma unroll
    for (int ni = 0; ni < 20; ni++){
      size_t boff = (((size_t)ni * 8 + ks) * 64 + lane) * 8;
      short8v bh = *(const short8v*)(Bhi + boff);
      short8v bl = *(const short8v*)(Blo + boff);
      acc[ni] = __builtin_amdgcn_mfma_f32_16x16x32_bf16(ahi, bh, acc[ni], 0, 0, 0);
      acc[ni] = __builtin_amdgcn_mfma_f32_16x16x32_bf16(ahi, bl, acc[ni], 0, 0, 0);
      acc[ni] = __builtin_amdgcn_mfma_f32_16x16x32_bf16(alo, bh, acc[ni], 0, 0, 0);
    }
  }

  float cp[32];
  #pragma unroll
  for (int i = 0; i < 32; i++) cp[i] = comp2[i];
  int crow = (lane >> 4) << 2;
  #pragma unroll
  for (int reg = 0; reg < 4; reg++){
    int r = mbase + crow + reg;
    if (r >= NN) continue;
    #pragma unroll
    for (int of = 0; of < 4; of++){
      float b0 = acc[of][reg], b1 = acc[4 + of][reg];
      float b2 = acc[8 + of][reg], b3 = acc[12 + of][reg];
      rootb[(size_t)r * 64 + of * 16 + fr] = acc[16 + of][reg];
      #pragma unroll
      for (int rr = 0; rr < 8; rr++){
        float m = cp[rr*4+0]*b0 + cp[rr*4+1]*b1 + cp[rr*4+2]*b2 + cp[rr*4+3]*b3;
        xr[((size_t)r * 8 + rr) * 64 + of * 16 + fr] = f2bf(m);
      }
    }
  }
}

// ---------------- GAT1 aggregate: 4 edge-groups x 16 ch-lanes, 4 heads per lane ----------------

__global__ void gat1_agg_kernel(const float* __restrict__ h1, const float* __restrict__ as_,
                                const float* __restrict__ ad_, const int* __restrict__ offs,
                                const int* __restrict__ csr_src, float* __restrict__ aggG){
  int wid  = (blockIdx.x * blockDim.x + threadIdx.x) >> 6;
  int lane = threadIdx.x & 63;
  if (wid >= NN) return;
  int n0 = offs[wid], n1 = offs[wid + 1];
  int h = lane & 3;
  float adn_s = ad_[wid * 4 + h];
  float m = leakyf(as_[wid * 4 + h] + adn_s);
  for (int k = n0 + (lane >> 2); k < n1; k += 16){
    int s = csr_src[k];
    m = fmaxf(m, leakyf(as_[s * 4 + h] + adn_s));
  }
  #pragma unroll
  for (int o = 4; o < 64; o <<= 1) m = fmaxf(m, __shfl_xor(m, o));
  float m0 = __shfl(m, 0), m1 = __shfl(m, 1), m2 = __shfl(m, 2), m3 = __shfl(m, 3);
  int q = lane & 15, eg = lane >> 4;
  F4 adn = ld4(ad_ + (size_t)wid * 4);
  float den0 = 0.f, den1 = 0.f, den2 = 0.f, den3 = 0.f;
  float4 ac0 = make_float4(0.f,0.f,0.f,0.f), ac1 = ac0, ac2 = ac0, ac3 = ac0;
  for (int k = n0 + eg; k < n1; k += 4){
    int s = csr_src[k];
    F4 a = ld4(as_ + (size_t)s * 4);
    float p0 = expf(leakyf(a.x + adn.x) - m0);
    float p1 = expf(leakyf(a.y + adn.y) - m1);
    float p2 = expf(leakyf(a.z + adn.z) - m2);
    float p3 = expf(leakyf(a.w + adn.w) - m3);
    den0 += p0; den1 += p1; den2 += p2; den3 += p3;
    float4 v = *(const float4*)(h1 + (size_t)s * 64 + q * 4);
    ac0.x += p0*v.x; ac0.y += p0*v.y; ac0.z += p0*v.z; ac0.w += p0*v.w;
    ac1.x += p1*v.x; ac1.y += p1*v.y; ac1.z += p1*v.z; ac1.w += p1*v.w;
    ac2.x += p2*v.x; ac2.y += p2*v.y; ac2.z += p2*v.z; ac2.w += p2*v.w;
    ac3.x += p3*v.x; ac3.y += p3*v.y; ac3.z += p3*v.z; ac3.w += p3*v.w;
  }
  #pragma unroll
  for (int o = 16; o < 64; o <<= 1){
    den0 += __shfl_xor(den0, o); den1 += __shfl_xor(den1, o);
    den2 += __shfl_xor(den2, o); den3 += __shfl_xor(den3, o);
  }
  ac0 = redeg16(ac0); ac1 = redeg16(ac1); ac2 = redeg16(ac2); ac3 = redeg16(ac3);
  F4 asn = ld4(as_ + (size_t)wid * 4);
  float ps0 = expf(leakyf(asn.x + adn.x) - m0);
  float ps1 = expf(leakyf(asn.y + adn.y) - m1);
  float ps2 = expf(leakyf(asn.z + adn.z) - m2);
  float ps3 = expf(leakyf(asn.w + adn.w) - m3);
  if (lane < 16){
    float4 v = *(const float4*)(h1 + (size_t)wid * 64 + q * 4);
    float i0 = 1.f / (den0 + ps0), i1 = 1.f / (den1 + ps1);
    float i2 = 1.f / (den2 + ps2), i3 = 1.f / (den3 + ps3);
    float* ag = aggG + (size_t)wid * 256 + q * 4;
    *(float4*)(ag)       = make_float4((ac0.x+ps0*v.x)*i0, (ac0.y+ps0*v.y)*i0, (ac0.z+ps0*v.z)*i0, (ac0.w+ps0*v.w)*i0);
    *(float4*)(ag + 64)  = make_float4((ac1.x+ps1*v.x)*i1, (ac1.y+ps1*v.y)*i1, (ac1.z+ps1*v.z)*i1, (ac1.w+ps1*v.w)*i1);
    *(float4*)(ag + 128) = make_float4((ac2.x+ps2*v.x)*i2, (ac2.y+ps2*v.y)*i2, (ac2.z+ps2*v.z)*i2, (ac2.w+ps2*v.w)*i2);
    *(float4*)(ag + 192) = make_float4((ac3.x+ps3*v.x)*i3, (ac3.y+ps3*v.y)*i3, (ac3.z+ps3*v.z)*i3, (ac3.w+ps3*v.w)*i3);
  }
}

// ---------------- layer-3 aggregate: 8 edge-groups x 8 ch-lanes (ushort8 gathers) ----------

__global__ void rgcn2_agg_kernel(const unsigned short* __restrict__ xr,
                                 const float* __restrict__ rootb,
                                 const float* __restrict__ bias, const int* __restrict__ offs,
                                 const int* __restrict__ csr_src, const int* __restrict__ csr_et,
                                 float* __restrict__ h3){
  int wid  = (blockIdx.x * blockDim.x + threadIdx.x) >> 6;
  int lane = threadIdx.x & 63;
  if (wid >= NN) return;
  int q = lane & 7, eg = lane >> 3;
  int n0 = offs[wid], n1 = offs[wid + 1];
  float a[8];
  #pragma unroll
  for (int j = 0; j < 8; j++) a[j] = 0.f;
  for (int k = n0 + eg; k < n1; k += 8){
    int s = csr_src[k], e = csr_et[k];
    short8v u = *(const short8v*)(xr + ((size_t)s * 8 + e) * 64 + q * 8);
    #pragma unroll
    for (int j = 0; j < 8; j++) a[j] += bf2f((unsigned short)u[j]);
  }
  #pragma unroll
  for (int o = 8; o < 64; o <<= 1){
    #pragma unroll
    for (int j = 0; j < 8; j++) a[j] += __shfl_xor(a[j], o);
  }
  int dg = n1 - n0;
  float sc = 1.f / (float)(dg > 0 ? dg : 1);
  if (lane < 8){
    const float* rb = rootb + (size_t)wid * 64 + q * 8;
    float4 r0 = *(const float4*)(rb);
    float4 r1 = *(const float4*)(rb + 4);
    float4 b0 = *(const float4*)(bias + q * 8);
    float4 b1 = *(const float4*)(bias + q * 8 + 4);
    float* hp = h3 + (size_t)wid * 64 + q * 8;
    *(float4*)(hp)     = make_float4(eluf(a[0]*sc + r0.x + b0.x), eluf(a[1]*sc + r0.y + b0.y),
                                     eluf(a[2]*sc + r0.z + b0.z), eluf(a[3]*sc + r0.w + b0.w));
    *(float4*)(hp + 4) = make_float4(eluf(a[4]*sc + r1.x + b1.x), eluf(a[5]*sc + r1.y + b1.y),
                                     eluf(a[6]*sc + r1.z + b1.z), eluf(a[7]*sc + r1.w + b1.w));
  }
}

// ---------------- GAT2 ----------------

__global__ void gat_lin2_kernel(const float* __restrict__ h, const float* __restrict__ W,
                                const float* __restrict__ atts, const float* __restrict__ attd,
                                float* __restrict__ hw, float* __restrict__ as_, float* __restrict__ ad_){
  int wid  = (blockIdx.x * blockDim.x + threadIdx.x) >> 6;
  int lane = threadIdx.x & 63;
  if (wid >= NN) return;
  float acc = 0.f;
  if (lane < 12){
    const float* hr = h + (size_t)wid * 64;
    const float* Wc = W + lane;
    #pragma unroll 8
    for (int i = 0; i < 64; i++) acc += hr[i] * Wc[(size_t)i * 12];
    hw[(size_t)wid * 12 + lane] = acc;
  }
  float ts = (lane < 12) ? acc * atts[lane] : 0.f;
  float td = (lane < 12) ? acc * attd[lane] : 0.f;
  int b = (lane < 4) ? lane * 3 : 0;
  float s0 = __shfl(ts, b) + __shfl(ts, b + 1) + __shfl(ts, b + 2);
  float d0 = __shfl(td, b) + __shfl(td, b + 1) + __shfl(td, b + 2);
  if (lane < 4){ as_[wid * 4 + lane] = s0; ad_[wid * 4 + lane] = d0; }
}

__global__ void gat2_final_kernel(const float* __restrict__ hw, const float* __restrict__ as_,
                                  const float* __restrict__ ad_, const float* __restrict__ bg2,
                                  const int* __restrict__ offs, const int* __restrict__ csr_src,
                                  float* __restrict__ out){
  int wid  = (blockIdx.x * blockDim.x + threadIdx.x) >> 6;
  int lane = threadIdx.x & 63;
  if (wid >= NN) return;
  int n0 = offs[wid], n1 = offs[wid + 1];
  F4 adn = ld4(ad_ + (size_t)wid * 4);
  F4 asn = ld4(as_ + (size_t)wid * 4);
  F4 es{leakyf(asn.x + adn.x), leakyf(asn.y + adn.y), leakyf(asn.z + adn.z), leakyf(asn.w + adn.w)};
  F4 m = es;
  for (int k = n0 + lane; k < n1; k += 64){
    int s = csr_src[k];
    F4 a = ld4(as_ + (size_t)s * 4);
    m.x = fmaxf(m.x, leakyf(a.x + adn.x));
    m.y = fmaxf(m.y, leakyf(a.y + adn.y));
    m.z = fmaxf(m.z, leakyf(a.z + adn.z));
    m.w = fmaxf(m.w, leakyf(a.w + adn.w));
  }
  #pragma unroll
  for (int o = 32; o; o >>= 1){
    m.x = fmaxf(m.x, __shfl_xor(m.x, o));
    m.y = fmaxf(m.y, __shfl_xor(m.y, o));
    m.z = fmaxf(m.z, __shfl_xor(m.z, o));
    m.w = fmaxf(m.w, __shfl_xor(m.w, o));
  }
  F4 ps{expf(es.x - m.x), expf(es.y - m.y), expf(es.z - m.z), expf(es.w - m.w)};
  float acc[12];
  #pragma unroll
  for (int j = 0; j < 12; j++) acc[j] = 0.f;
  F4 denp{0.f, 0.f, 0.f, 0.f};
  for (int k = n0 + lane; k < n1; k += 64){
    int s = csr_src[k];
    F4 a = ld4(as_ + (size_t)s * 4);
    F4 p{expf(leakyf(a.x + adn.x) - m.x), expf(leakyf(a.y + adn.y) - m.y),
         expf(leakyf(a.z + adn.z) - m.z), expf(leakyf(a.w + adn.w) - m.w)};
    denp.x += p.x; denp.y += p.y; denp.z += p.z; denp.w += p.w;
    const float* hb = hw + (size_t)s * 12;
    F4 h0 = ld4(hb), h1 = ld4(hb + 4), h2 = ld4(hb + 8);
    acc[0] += p.x * h0.x; acc[1]  += p.x * h0.y; acc[2]  += p.x * h0.z;
    acc[3] += p.y * h0.w; acc[4]  += p.y * h1.x; acc[5]  += p.y * h1.y;
    acc[6] += p.z * h1.z; acc[7]  += p.z * h1.w; acc[8]  += p.z * h2.x;
    acc[9] += p.w * h2.y; acc[10] += p.w * h2.z; acc[11] += p.w * h2.w;
  }
  #pragma unroll
  for (int o = 32; o; o >>= 1){
    denp.x += __shfl_xor(denp.x, o);
    denp.y += __shfl_xor(denp.y, o);
    denp.z += __shfl_xor(denp.z, o);
    denp.w += __shfl_xor(denp.w, o);
    #pragma unroll
    for (int j = 0; j < 12; j++) acc[j] += __shfl_xor(acc[j], o);
  }
  if (lane == 0){
    const float* hn = hw + (size_t)wid * 12;
    float dn[4]  = {denp.x + ps.x, denp.y + ps.y, denp.z + ps.z, denp.w + ps.w};
    float psv[4] = {ps.x, ps.y, ps.z, ps.w};
    float tot = 0.f;
    #pragma unroll
    for (int h_ = 0; h_ < 4; h_++){
      #pragma unroll
      for (int c = 0; c < 3; c++){
        float num = acc[h_ * 3 + c] + psv[h_] * hn[h_ * 3 + c];
        tot += num / dn[h_];
      }
    }
    tot = tot / 12.f + (bg2[0] + bg2[1] + bg2[2]) / 3.f;
    out[wid] = tanhf(tot);
  }
}

// ---------------- launch ----------------

extern "C" void kernel_launch(void* const* d_in, const int* in_sizes, int n_in,
                              void* d_out, int out_size, void* d_ws, size_t ws_size,
                              hipStream_t stream){
  const float* x      = (const float*)d_in[0];
  const int*   ei     = (const int*)d_in[1];
  const int*   et     = (const int*)d_in[2];
  const float* basis1 = (const float*)d_in[3];
  const float* comp1  = (const float*)d_in[4];
  const float* root1  = (const float*)d_in[5];
  const float* brg1   = (const float*)d_in[6];
  const float* Wg1    = (const float*)d_in[7];
  const float* atts1  = (const float*)d_in[8];
  const float* attd1  = (const float*)d_in[9];
  const float* bg1    = (const float*)d_in[10];
  const float* basis2 = (const float*)d_in[11];
  const float* comp2  = (const float*)d_in[12];
  const float* root2  = (const float*)d_in[13];
  const float* brg2   = (const float*)d_in[14];
  const float* Wg2    = (const float*)d_in[15];
  const float* atts2  = (const float*)d_in[16];
  const float* attd2  = (const float*)d_in[17];
  const float* bg2    = (const float*)d_in[18];
  float* out = (float*)d_out;

  const int* src = ei;
  const int* dst = ei + NE;

  char* ws = (char*)d_ws;
  size_t off = 0;
  auto alloc = [&](size_t bytes) -> void* {
    void* p = ws + off;
    off = (off + bytes + 255) & ~(size_t)255;
    return p;
  };
  // persistent
  int*   deg     = (int*)alloc((size_t)NN * 4);
  int*   cursor  = (int*)alloc((size_t)NN * 4);
  int*   offs    = (int*)alloc((size_t)(NN + 1) * 4);
  int*   bsum    = (int*)alloc((size_t)256 * 4);
  int*   csr_src = (int*)alloc((size_t)NE * 4);
  int*   csr_et  = (int*)alloc((size_t)NE * 4);
  float* Wcat2   = (float*)alloc((size_t)256 * 384 * 4);
  unsigned short* Bhi2 = (unsigned short*)alloc((size_t)81920 * 2);  // L3: 20*8*64*8
  unsigned short* Blo2 = (unsigned short*)alloc((size_t)81920 * 2);
  unsigned short* Bhi1 = (unsigned short*)alloc((size_t)16384 * 2);  // GAT1: 16*2*64*8
  unsigned short* Blo1 = (unsigned short*)alloc((size_t)16384 * 2);
  float* wa_s    = (float*)alloc((size_t)256 * 4);
  float* wa_d    = (float*)alloc((size_t)256 * 4);
  float* h1      = (float*)alloc((size_t)NN * 64 * 4);
  float* h2      = (float*)alloc((size_t)NN * 256 * 4);
  float* h3      = (float*)alloc((size_t)NN * 64 * 4);
  float* hw2     = (float*)alloc((size_t)NN * 12 * 4);
  float* as1     = (float*)alloc((size_t)NN * 4 * 4);
  float* ad1     = (float*)alloc((size_t)NN * 4 * 4);
  float* as2     = (float*)alloc((size_t)NN * 4 * 4);
  float* ad2     = (float*)alloc((size_t)NN * 4 * 4);
  // scratch union S (NN*384 floats):
  //   agg1[NN*128] -> aggG[NN*256] -> { xr bf16 [NN*512] (= NN*256 floats), rootb [NN*64] }
  float* S       = (float*)alloc((size_t)NN * 384 * 4);
  float* agg1    = S;
  float* aggG    = S;
  unsigned short* xr = (unsigned short*)S;          // NN*512 ushorts = NN*256 floats
  float* rootb   = S + (size_t)NN * 256;            // NN*64 floats
  (void)ws_size; (void)n_in; (void)in_sizes; (void)out_size;

  const int BLK = 256;
  int gridN   = (NN + BLK - 1) / BLK;
  int gridE   = (NE + BLK - 1) / BLK;
  int gridW   = (NN + 3) / 4;
  int gridM64 = (NN + 63) / 64;     // 469
  int gridM256= (NN + 255) / 256;   // 118

  // CSR build + weight prep
  zero2_kernel<<<gridN, BLK, 0, stream>>>(deg, cursor, NN);
  count_kernel<<<gridE, BLK, 0, stream>>>(dst, deg, NE);
  wcat2_kernel<<<(256 * 384 + 255) / 256, BLK, 0, stream>>>(basis2, root2, Wcat2);
  packB_kernel<<<(10240 + 255) / 256, BLK, 0, stream>>>(Wcat2, 384, 8, 10240, Bhi2, Blo2);
  packB_kernel<<<(2048 + 255) / 256, BLK, 0, stream>>>(Wg1, 256, 2, 2048, Bhi1, Blo1);
  wa_kernel<<<1, BLK, 0, stream>>>(Wg1, atts1, attd1, wa_s, wa_d);
  scan1_kernel<<<gridN, BLK, 0, stream>>>(deg, offs, bsum);
  scan2_kernel<<<1, BLK, 0, stream>>>(bsum, gridN);
  scan3_kernel<<<gridN, BLK, 0, stream>>>(bsum, offs);
  scatter_kernel<<<gridE, BLK, 0, stream>>>(src, dst, et, offs, cursor, csr_src, csr_et, NE);

  // Layer 1: RGCN (32 -> 64) + elu
  agg1_kernel<<<gridW, BLK, 0, stream>>>(x, comp1, offs, csr_src, csr_et, agg1);
  gemmT_kernel<4, true><<<dim3(1, gridM64), BLK, 0, stream>>>(
      agg1, 128, 128, basis1, 64,
      x, 32, 32, root1, 64,
      brg1, h1, 64, NN, 0, 0);

  // Layer 2: GAT (64 -> 256 concat) + elu: logits -> aggregate h1 -> MFMA block-diag GEMM
  logits_kernel<<<(NN * 4 + 255) / 256, BLK, 0, stream>>>(h1, wa_s, wa_d, as1, ad1);
  gat1_agg_kernel<<<gridW, BLK, 0, stream>>>(h1, as1, ad1, offs, csr_src, aggG);
  gemm_mfma_kernel<2, true, true><<<dim3(4, gridM256), BLK, 0, stream>>>(
      aggG, 256, 64, Bhi1, Blo1, bg1, h2, 256);

  // Layer 3: RGCN (256 -> 64) + elu: fused MFMA transform (A read once) -> xr + root
  gemm_l3_fused_kernel<<<gridM64, BLK, 0, stream>>>(h2, Bhi2, Blo2, comp2, xr, rootb);
  rgcn2_agg_kernel<<<gridW, BLK, 0, stream>>>(xr, rootb, brg2, offs, csr_src, csr_et, h3);

  // Layer 4: GAT (64 -> 4x3, mean heads) + mean classes + tanh
  gat_lin2_kernel<<<gridW, BLK, 0, stream>>>(h3, Wg2, atts2, attd2, hw2, as2, ad2);
  gat2_final_kernel<<<gridW, BLK, 0, stream>>>(hw2, as2, ad2, bg2, offs, csr_src, out);
}

// Round 16
// 324.738 us; speedup vs baseline: 1.4276x; 1.0299x over previous
//
#include <hip/hip_runtime.h>
#include <cstdint>
#include <cstddef>

#define NN 30000
#define NE 480000

typedef __attribute__((ext_vector_type(8))) short short8v;
typedef __attribute__((ext_vector_type(4))) float f32x4;

__device__ __forceinline__ float leakyf(float x){ return x > 0.f ? x : 0.2f * x; }
__device__ __forceinline__ float eluf(float x){ return x > 0.f ? x : expm1f(x); }

__device__ __forceinline__ float bf2f(unsigned short u){
  return __uint_as_float(((unsigned)u) << 16);
}
__device__ __forceinline__ unsigned short f2bf(float f){
  unsigned x = __float_as_uint(f);
  unsigned r = (x + 0x7FFFu + ((x >> 16) & 1u)) >> 16;
  return (unsigned short)r;
}

struct F4 { float x, y, z, w; };

__device__ __forceinline__ F4 ld4(const float* p){
  float4 v = *(const float4*)p;
  return F4{v.x, v.y, v.z, v.w};
}

__device__ __forceinline__ float4 redeg16(float4 v){
  v.x += __shfl_xor(v.x, 16); v.y += __shfl_xor(v.y, 16);
  v.z += __shfl_xor(v.z, 16); v.w += __shfl_xor(v.w, 16);
  v.x += __shfl_xor(v.x, 32); v.y += __shfl_xor(v.y, 32);
  v.z += __shfl_xor(v.z, 32); v.w += __shfl_xor(v.w, 32);
  return v;
}

// ---------------- CSR build ----------------

__global__ void zero2_kernel(int* __restrict__ a, int* __restrict__ b, int n){
  int i = blockIdx.x * blockDim.x + threadIdx.x;
  if (i < n){ a[i] = 0; b[i] = 0; }
}

__global__ void count_kernel(const int* __restrict__ dst, int* __restrict__ deg, int E){
  int i = blockIdx.x * blockDim.x + threadIdx.x;
  if (i < E) atomicAdd(&deg[dst[i]], 1);
}

__global__ void scan1_kernel(const int* __restrict__ deg, int* __restrict__ offs,
                             int* __restrict__ bsum){
  __shared__ int sh[256];
  int blk = blockIdx.x, t = threadIdx.x, i = blk * 256 + t;
  int v = (i < NN) ? deg[i] : 0;
  sh[t] = v; __syncthreads();
  for (int o = 1; o < 256; o <<= 1){
    int tv = (t >= o) ? sh[t - o] : 0;
    __syncthreads();
    sh[t] += tv;
    __syncthreads();
  }
  if (i < NN) offs[i + 1] = sh[t];
  if (t == 255) bsum[blk] = sh[255];
}

__global__ void scan2_kernel(int* __restrict__ bsum, int nb){
  __shared__ int sh[256];
  int t = threadIdx.x;
  int v = (t < nb) ? bsum[t] : 0;
  sh[t] = v; __syncthreads();
  for (int o = 1; o < 256; o <<= 1){
    int tv = (t >= o) ? sh[t - o] : 0;
    __syncthreads();
    sh[t] += tv;
    __syncthreads();
  }
  if (t < nb) bsum[t] = sh[t];
}

__global__ void scan3_kernel(const int* __restrict__ bsum, int* __restrict__ offs){
  int i = blockIdx.x * 256 + threadIdx.x;
  if (i == 0) offs[0] = 0;
  if (i < NN){
    int blk = i >> 8;
    int add = blk ? bsum[blk - 1] : 0;
    offs[i + 1] += add;
  }
}

__global__ void scatter_kernel(const int* __restrict__ src, const int* __restrict__ dst,
                               const int* __restrict__ et, const int* __restrict__ offs,
                               int* __restrict__ cursor, int* __restrict__ csr_src,
                               int* __restrict__ csr_et, int E){
  int i = blockIdx.x * blockDim.x + threadIdx.x;
  if (i < E){
    int d = dst[i];
    int pos = offs[d] + atomicAdd(&cursor[d], 1);
    csr_src[pos] = src[i];
    csr_et[pos]  = et[i];
  }
}

// ---------------- weight prep ----------------
// Wcat2 [256][384]: cols 0..255 = basis2 (4 bases x 64), 256..319 = root2, 320..383 = 0.

__global__ void wcat2_kernel(const float* __restrict__ basis2, const float* __restrict__ root2,
                             float* __restrict__ Wcat){
  int idx = blockIdx.x * 256 + threadIdx.x;
  if (idx >= 256 * 384) return;
  int k = idx / 384, col = idx - k * 384;
  float v = 0.f;
  if (col < 256){
    int b = col >> 6, c = col & 63;
    v = basis2[((size_t)b * 256 + k) * 64 + c];
  } else if (col < 320){
    v = root2[(size_t)k * 64 + (col - 256)];
  }
  Wcat[idx] = v;
}

// generic MFMA B-fragment pack, bf16 hi/lo split.
// idx = (nf16*ksteps + ks)*64 + lane; element W[ks*32+(lane>>4)*8+j][nf16*16+(lane&15)]
__global__ void packB_kernel(const float* __restrict__ W, int ldw, int ksteps, int total,
                             unsigned short* __restrict__ Bhi, unsigned short* __restrict__ Blo){
  int idx = blockIdx.x * 256 + threadIdx.x;
  if (idx >= total) return;
  int lane = idx & 63;
  int rest = idx >> 6;
  int ks = rest % ksteps;
  int nf16 = rest / ksteps;
  int col = nf16 * 16 + (lane & 15);
  int kbase = ks * 32 + ((lane >> 4) << 3);
  size_t obase = (size_t)idx * 8;
  #pragma unroll
  for (int j = 0; j < 8; j++){
    float v = W[(size_t)(kbase + j) * ldw + col];
    unsigned short h = f2bf(v);
    float res = v - bf2f(h);
    Bhi[obase + j] = h;
    Blo[obase + j] = f2bf(res);
  }
}

// wa_s[k*4+h] = sum_c Wg1[k, h*64+c] * atts1[h,c]  (and wa_d with attd1)
__global__ void wa_kernel(const float* __restrict__ Wg1, const float* __restrict__ atts1,
                          const float* __restrict__ attd1, float* __restrict__ wa_s,
                          float* __restrict__ wa_d){
  int t = threadIdx.x;
  int k = t >> 2, h = t & 3;
  float s = 0.f, d = 0.f;
  const float* wr = Wg1 + (size_t)k * 256 + h * 64;
  const float* pa = atts1 + h * 64;
  const float* pb = attd1 + h * 64;
  #pragma unroll 8
  for (int c = 0; c < 64; c++){ s += wr[c] * pa[c]; d += wr[c] * pb[c]; }
  wa_s[k * 4 + h] = s;
  wa_d[k * 4 + h] = d;
}

// as1[n,h] = h1[n,:] . wa_s[:,h]
__global__ void logits_kernel(const float* __restrict__ h1, const float* __restrict__ wa_s,
                              const float* __restrict__ wa_d, float* __restrict__ as_,
                              float* __restrict__ ad_){
  __shared__ float ws[256], wd[256];
  int t = threadIdx.x;
  ws[t] = wa_s[t];
  wd[t] = wa_d[t];
  __syncthreads();
  int idx = blockIdx.x * 256 + t;
  int n = idx >> 2, h = idx & 3;
  if (n >= NN) return;
  float s = 0.f, d = 0.f;
  const float* hr = h1 + (size_t)n * 64;
  #pragma unroll 4
  for (int k4 = 0; k4 < 16; k4++){
    float4 hv = *(const float4*)(hr + k4 * 4);
    s += hv.x * ws[(k4*4+0)*4+h] + hv.y * ws[(k4*4+1)*4+h]
       + hv.z * ws[(k4*4+2)*4+h] + hv.w * ws[(k4*4+3)*4+h];
    d += hv.x * wd[(k4*4+0)*4+h] + hv.y * wd[(k4*4+1)*4+h]
       + hv.z * wd[(k4*4+2)*4+h] + hv.w * wd[(k4*4+3)*4+h];
  }
  as_[n * 4 + h] = s;
  ad_[n * 4 + h] = d;
}

// ---------------- layer-1 basis-space aggregation (4 edge-groups x float2) ----------------

__global__ void agg1_kernel(const float* __restrict__ x, const float* __restrict__ comp,
                            const int* __restrict__ offs, const int* __restrict__ csr_src,
                            const int* __restrict__ csr_et, float* __restrict__ agg){
  int wid  = (blockIdx.x * blockDim.x + threadIdx.x) >> 6;
  int lane = threadIdx.x & 63;
  if (wid >= NN) return;
  int q = lane & 15, eg = lane >> 4;
  int c2 = q * 2;
  int n0 = offs[wid], n1 = offs[wid + 1];
  float a00 = 0.f, a01 = 0.f, a10 = 0.f, a11 = 0.f;
  float a20 = 0.f, a21 = 0.f, a30 = 0.f, a31 = 0.f;
  for (int k = n0 + eg; k < n1; k += 4){
    int s = csr_src[k], e = csr_et[k];
    float2 v = *(const float2*)(x + (size_t)s * 32 + c2);
    F4 cp = ld4(comp + (size_t)e * 4);
    a00 += cp.x * v.x; a01 += cp.x * v.y;
    a10 += cp.y * v.x; a11 += cp.y * v.y;
    a20 += cp.z * v.x; a21 += cp.z * v.y;
    a30 += cp.w * v.x; a31 += cp.w * v.y;
  }
  #pragma unroll
  for (int o = 16; o < 64; o <<= 1){
    a00 += __shfl_xor(a00, o); a01 += __shfl_xor(a01, o);
    a10 += __shfl_xor(a10, o); a11 += __shfl_xor(a11, o);
    a20 += __shfl_xor(a20, o); a21 += __shfl_xor(a21, o);
    a30 += __shfl_xor(a30, o); a31 += __shfl_xor(a31, o);
  }
  int dg = n1 - n0;
  float sc = 1.f / (float)(dg > 0 ? dg : 1);
  if (lane < 16){
    float* ar = agg + (size_t)wid * 128 + c2;
    *(float2*)(ar)      = make_float2(a00 * sc, a01 * sc);
    *(float2*)(ar + 32) = make_float2(a10 * sc, a11 * sc);
    *(float2*)(ar + 64) = make_float2(a20 * sc, a21 * sc);
    *(float2*)(ar + 96) = make_float2(a30 * sc, a31 * sc);
  }
}

// ---------------- (RPT*16)-row x 64-col fused GEMM (layer 1 only) ----------------

template<int RPT, bool ELU>
__global__ __launch_bounds__(256) void gemmT_kernel(
    const float* __restrict__ A1, int lda1, int K1,
    const float* __restrict__ W1, int ldw1,
    const float* __restrict__ A2, int lda2, int K2,
    const float* __restrict__ W2, int ldw2,
    const float* __restrict__ bias,
    float* __restrict__ Y, int ldy,
    int nrows, int acgoff, int wcgoff)
{
  __shared__ float At[32][RPT * 16 + 4];
  __shared__ float Wl[32][68];
  int t = threadIdx.x;
  int tc = t & 15, tr = t >> 4;
  int cg = blockIdx.x;
  int nbase = blockIdx.y * (RPT * 16);
  float acc[RPT][4];
  #pragma unroll
  for (int j = 0; j < RPT; j++)
    #pragma unroll
    for (int i = 0; i < 4; i++) acc[j][i] = 0.f;

  for (int seg = 0; seg < 2; seg++){
    const float* A = seg ? A2 : A1;
    const float* W = seg ? W2 : W1;
    int lda = seg ? lda2 : lda1;
    int ldw = seg ? ldw2 : ldw1;
    int K   = seg ? K2 : K1;
    if (A == nullptr || K <= 0) continue;
    A += (size_t)cg * acgoff;
    W += (size_t)cg * wcgoff;
    for (int k0 = 0; k0 < K; k0 += 32){
      #pragma unroll
      for (int i = 0; i < 2; i++){
        int e = i * 256 + t;
        int kk = e >> 4, c4 = (e & 15) << 2;
        float4 v = make_float4(0.f, 0.f, 0.f, 0.f);
        if (k0 + kk < K) v = *(const float4*)(W + (size_t)(k0 + kk) * ldw + c4);
        *(float4*)&Wl[kk][c4] = v;
      }
      #pragma unroll
      for (int i = 0; i < RPT / 2; i++){
        int e = i * 256 + t;
        int r = e >> 3, c4 = (e & 7) << 2;
        int n = nbase + r;
        float4 v = make_float4(0.f, 0.f, 0.f, 0.f);
        if (n < nrows && k0 + c4 < K) v = *(const float4*)(A + (size_t)n * lda + k0 + c4);
        At[c4 + 0][r] = v.x;
        At[c4 + 1][r] = v.y;
        At[c4 + 2][r] = v.z;
        At[c4 + 3][r] = v.w;
      }
      __syncthreads();
      #pragma unroll 4
      for (int k = 0; k < 32; k++){
        float4 wv = *(const float4*)&Wl[k][tc * 4];
        const float* pw = (const float*)&wv;
        #pragma unroll
        for (int jj = 0; jj < RPT / 4; jj++){
          float4 av = *(const float4*)&At[k][tr * RPT + jj * 4];
          const float* pa = (const float*)&av;
          #pragma unroll
          for (int j = 0; j < 4; j++)
            #pragma unroll
            for (int i = 0; i < 4; i++)
              acc[jj * 4 + j][i] = fmaf(pa[j], pw[i], acc[jj * 4 + j][i]);
        }
      }
      __syncthreads();
    }
  }

  float b0 = 0.f, b1 = 0.f, b2 = 0.f, b3 = 0.f;
  if (bias){
    b0 = bias[cg * 64 + tc * 4 + 0];
    b1 = bias[cg * 64 + tc * 4 + 1];
    b2 = bias[cg * 64 + tc * 4 + 2];
    b3 = bias[cg * 64 + tc * 4 + 3];
  }
  #pragma unroll
  for (int j = 0; j < RPT; j++){
    int n = nbase + tr * RPT + j;
    if (n < nrows){
      float y0 = acc[j][0] + b0, y1 = acc[j][1] + b1;
      float y2 = acc[j][2] + b2, y3 = acc[j][3] + b3;
      if (ELU){ y0 = eluf(y0); y1 = eluf(y1); y2 = eluf(y2); y3 = eluf(y3); }
      *(float4*)(Y + (size_t)n * ldy + cg * 64 + tc * 4) = make_float4(y0, y1, y2, y3);
    }
  }
}

// ---------------- generic bf16-split MFMA GEMM (GAT1 block-diag) ----------------

template<int KSTEPS, bool ELU, bool BIAS>
__global__ __launch_bounds__(256) void gemm_mfma_kernel(
    const float* __restrict__ A, int lda, int acgoff,
    const unsigned short* __restrict__ Bhi, const unsigned short* __restrict__ Blo,
    const float* __restrict__ bias, float* __restrict__ Y, int ldy)
{
  int t = threadIdx.x;
  int lane = t & 63, wv = t >> 6;
  int cg = blockIdx.x;
  int mbase = blockIdx.y * 256 + wv * 64;
  int fr = lane & 15;
  int ksub = (lane >> 4) << 3;
  const float* Ab = A + (size_t)cg * acgoff;
  f32x4 acc[4][4];
  #pragma unroll
  for (int mi = 0; mi < 4; mi++)
    #pragma unroll
    for (int ni = 0; ni < 4; ni++)
      acc[mi][ni] = (f32x4){0.f, 0.f, 0.f, 0.f};

  #pragma unroll
  for (int ks = 0; ks < KSTEPS; ks++){
    short8v ahi[4], alo[4];
    #pragma unroll
    for (int mi = 0; mi < 4; mi++){
      int r = mbase + mi * 16 + fr;
      float av[8];
      if (r < NN){
        float4 p0 = *(const float4*)(Ab + (size_t)r * lda + ks * 32 + ksub);
        float4 p1 = *(const float4*)(Ab + (size_t)r * lda + ks * 32 + ksub + 4);
        av[0] = p0.x; av[1] = p0.y; av[2] = p0.z; av[3] = p0.w;
        av[4] = p1.x; av[5] = p1.y; av[6] = p1.z; av[7] = p1.w;
      } else {
        #pragma unroll
        for (int j = 0; j < 8; j++) av[j] = 0.f;
      }
      #pragma unroll
      for (int j = 0; j < 8; j++){
        unsigned short h = f2bf(av[j]);
        float res = av[j] - bf2f(h);
        ahi[mi][j] = (short)h;
        alo[mi][j] = (short)f2bf(res);
      }
    }
    #pragma unroll
    for (int ni = 0; ni < 4; ni++){
      size_t boff = ((((size_t)(cg * 4 + ni)) * KSTEPS + ks) * 64 + lane) * 8;
      short8v bh = *(const short8v*)(Bhi + boff);
      short8v bl = *(const short8v*)(Blo + boff);
      #pragma unroll
      for (int mi = 0; mi < 4; mi++){
        acc[mi][ni] = __builtin_amdgcn_mfma_f32_16x16x32_bf16(ahi[mi], bh, acc[mi][ni], 0, 0, 0);
        acc[mi][ni] = __builtin_amdgcn_mfma_f32_16x16x32_bf16(ahi[mi], bl, acc[mi][ni], 0, 0, 0);
        acc[mi][ni] = __builtin_amdgcn_mfma_f32_16x16x32_bf16(alo[mi], bh, acc[mi][ni], 0, 0, 0);
      }
    }
  }
  int crow = (lane >> 4) << 2;
  #pragma unroll
  for (int mi = 0; mi < 4; mi++){
    #pragma unroll
    for (int reg = 0; reg < 4; reg++){
      int r = mbase + mi * 16 + crow + reg;
      if (r < NN){
        #pragma unroll
        for (int ni = 0; ni < 4; ni++){
          float y = acc[mi][ni][reg];
          if (BIAS) y += bias[cg * 64 + ni * 16 + fr];
          if (ELU)  y = eluf(y);
          Y[(size_t)r * ldy + cg * 64 + ni * 16 + fr] = y;
        }
      }
    }
  }
}

// ---------------- L3 fused MFMA GEMM, of-split for occupancy ----------------
// grid (4 ofs, 469 row-tiles); wave = 16 rows x 80 cols (5 frags: 4 bases + root at of).
// Epilogue: xr[n,r,of*16+fr] = sum_b comp2[r,b]*accb (bf16); rootb[n,of*16+fr] (fp32).

__global__ __launch_bounds__(256) void gemm_l3_fused_kernel(
    const float* __restrict__ A,
    const unsigned short* __restrict__ Bhi, const unsigned short* __restrict__ Blo,
    const float* __restrict__ comp2,
    unsigned short* __restrict__ xr, float* __restrict__ rootb)
{
  int t = threadIdx.x;
  int lane = t & 63, wv = t >> 6;
  int of = blockIdx.x;
  int mbase = blockIdx.y * 64 + wv * 16;
  int fr = lane & 15;
  int ksub = (lane >> 4) << 3;
  f32x4 acc[5];
  #pragma unroll
  for (int b = 0; b < 5; b++) acc[b] = (f32x4){0.f, 0.f, 0.f, 0.f};

  int ar = mbase + fr;
  bool arok = (ar < NN);
  for (int ks = 0; ks < 8; ks++){
    float av[8];
    if (arok){
      float4 p0 = *(const float4*)(A + (size_t)ar * 256 + ks * 32 + ksub);
      float4 p1 = *(const float4*)(A + (size_t)ar * 256 + ks * 32 + ksub + 4);
      av[0] = p0.x; av[1] = p0.y; av[2] = p0.z; av[3] = p0.w;
      av[4] = p1.x; av[5] = p1.y; av[6] = p1.z; av[7] = p1.w;
    } else {
      #pragma unroll
      for (int j = 0; j < 8; j++) av[j] = 0.f;
    }
    short8v ahi, alo;
    #pragma unroll
    for (int j = 0; j < 8; j++){
      unsigned short h = f2bf(av[j]);
      float res = av[j] - bf2f(h);
      ahi[j] = (short)h;
      alo[j] = (short)f2bf(res);
    }
    #pragma unroll
    for (int b = 0; b < 5; b++){
      int nig = b * 4 + of;                 // global fragment id (b<4: basis, b=4: root)
      size_t boff = (((size_t)nig * 8 + ks) * 64 + lane) * 8;
      short8v bh = *(const short8v*)(Bhi + boff);
      short8v bl = *(const short8v*)(Blo + boff);
      acc[b] = __builtin_amdgcn_mfma_f32_16x16x32_bf16(ahi, bh, acc[b], 0, 0, 0);
      acc[b] = __builtin_amdgcn_mfma_f32_16x16x32_bf16(ahi, bl, acc[b], 0, 0, 0);
      acc[b] = __builtin_amdgcn_mfma_f32_16x16x32_bf16(alo, bh, acc[b], 0, 0, 0);
    }
  }

  float cp[32];
  #pragma unroll
  for (int i = 0; i < 32; i++) cp[i] = comp2[i];
  int crow = (lane >> 4) << 2;
  int col = of * 16 + fr;
  #pragma unroll
  for (int reg = 0; reg < 4; reg++){
    int r = mbase + crow + reg;
    if (r >= NN) continue;
    float b0 = acc[0][reg], b1 = acc[1][reg], b2 = acc[2][reg], b3 = acc[3][reg];
    rootb[(size_t)r * 64 + col] = acc[4][reg];
    #pragma unroll
    for (int rr = 0; rr < 8; rr++){
      float m = cp[rr*4+0]*b0 + cp[rr*4+1]*b1 + cp[rr*4+2]*b2 + cp[rr*4+3]*b3;
      xr[((size_t)r * 8 + rr) * 64 + col] = f2bf(m);
    }
  }
}

// ---------------- GAT1 aggregate: 4 edge-groups x 16 ch-lanes, 4 heads per lane ----------------

__global__ void gat1_agg_kernel(const float* __restrict__ h1, const float* __restrict__ as_,
                                const float* __restrict__ ad_, const int* __restrict__ offs,
                                const int* __restrict__ csr_src, float* __restrict__ aggG){
  int wid  = (blockIdx.x * blockDim.x + threadIdx.x) >> 6;
  int lane = threadIdx.x & 63;
  if (wid >= NN) return;
  int n0 = offs[wid], n1 = offs[wid + 1];
  int h = lane & 3;
  float adn_s = ad_[wid * 4 + h];
  float m = leakyf(as_[wid * 4 + h] + adn_s);
  for (int k = n0 + (lane >> 2); k < n1; k += 16){
    int s = csr_src[k];
    m = fmaxf(m, leakyf(as_[s * 4 + h] + adn_s));
  }
  #pragma unroll
  for (int o = 4; o < 64; o <<= 1) m = fmaxf(m, __shfl_xor(m, o));
  float m0 = __shfl(m, 0), m1 = __shfl(m, 1), m2 = __shfl(m, 2), m3 = __shfl(m, 3);
  int q = lane & 15, eg = lane >> 4;
  F4 adn = ld4(ad_ + (size_t)wid * 4);
  float den0 = 0.f, den1 = 0.f, den2 = 0.f, den3 = 0.f;
  float4 ac0 = make_float4(0.f,0.f,0.f,0.f), ac1 = ac0, ac2 = ac0, ac3 = ac0;
  for (int k = n0 + eg; k < n1; k += 4){
    int s = csr_src[k];
    F4 a = ld4(as_ + (size_t)s * 4);
    float p0 = expf(leakyf(a.x + adn.x) - m0);
    float p1 = expf(leakyf(a.y + adn.y) - m1);
    float p2 = expf(leakyf(a.z + adn.z) - m2);
    float p3 = expf(leakyf(a.w + adn.w) - m3);
    den0 += p0; den1 += p1; den2 += p2; den3 += p3;
    float4 v = *(const float4*)(h1 + (size_t)s * 64 + q * 4);
    ac0.x += p0*v.x; ac0.y += p0*v.y; ac0.z += p0*v.z; ac0.w += p0*v.w;
    ac1.x += p1*v.x; ac1.y += p1*v.y; ac1.z += p1*v.z; ac1.w += p1*v.w;
    ac2.x += p2*v.x; ac2.y += p2*v.y; ac2.z += p2*v.z; ac2.w += p2*v.w;
    ac3.x += p3*v.x; ac3.y += p3*v.y; ac3.z += p3*v.z; ac3.w += p3*v.w;
  }
  #pragma unroll
  for (int o = 16; o < 64; o <<= 1){
    den0 += __shfl_xor(den0, o); den1 += __shfl_xor(den1, o);
    den2 += __shfl_xor(den2, o); den3 += __shfl_xor(den3, o);
  }
  ac0 = redeg16(ac0); ac1 = redeg16(ac1); ac2 = redeg16(ac2); ac3 = redeg16(ac3);
  F4 asn = ld4(as_ + (size_t)wid * 4);
  float ps0 = expf(leakyf(asn.x + adn.x) - m0);
  float ps1 = expf(leakyf(asn.y + adn.y) - m1);
  float ps2 = expf(leakyf(asn.z + adn.z) - m2);
  float ps3 = expf(leakyf(asn.w + adn.w) - m3);
  if (lane < 16){
    float4 v = *(const float4*)(h1 + (size_t)wid * 64 + q * 4);
    float i0 = 1.f / (den0 + ps0), i1 = 1.f / (den1 + ps1);
    float i2 = 1.f / (den2 + ps2), i3 = 1.f / (den3 + ps3);
    float* ag = aggG + (size_t)wid * 256 + q * 4;
    *(float4*)(ag)       = make_float4((ac0.x+ps0*v.x)*i0, (ac0.y+ps0*v.y)*i0, (ac0.z+ps0*v.z)*i0, (ac0.w+ps0*v.w)*i0);
    *(float4*)(ag + 64)  = make_float4((ac1.x+ps1*v.x)*i1, (ac1.y+ps1*v.y)*i1, (ac1.z+ps1*v.z)*i1, (ac1.w+ps1*v.w)*i1);
    *(float4*)(ag + 128) = make_float4((ac2.x+ps2*v.x)*i2, (ac2.y+ps2*v.y)*i2, (ac2.z+ps2*v.z)*i2, (ac2.w+ps2*v.w)*i2);
    *(float4*)(ag + 192) = make_float4((ac3.x+ps3*v.x)*i3, (ac3.y+ps3*v.y)*i3, (ac3.z+ps3*v.z)*i3, (ac3.w+ps3*v.w)*i3);
  }
}

// ---------------- layer-3 aggregate: 8 edge-groups x 8 ch-lanes (ushort8 gathers) ----------

__global__ void rgcn2_agg_kernel(const unsigned short* __restrict__ xr,
                                 const float* __restrict__ rootb,
                                 const float* __restrict__ bias, const int* __restrict__ offs,
                                 const int* __restrict__ csr_src, const int* __restrict__ csr_et,
                                 float* __restrict__ h3){
  int wid  = (blockIdx.x * blockDim.x + threadIdx.x) >> 6;
  int lane = threadIdx.x & 63;
  if (wid >= NN) return;
  int q = lane & 7, eg = lane >> 3;
  int n0 = offs[wid], n1 = offs[wid + 1];
  float a[8];
  #pragma unroll
  for (int j = 0; j < 8; j++) a[j] = 0.f;
  for (int k = n0 + eg; k < n1; k += 8){
    int s = csr_src[k], e = csr_et[k];
    short8v u = *(const short8v*)(xr + ((size_t)s * 8 + e) * 64 + q * 8);
    #pragma unroll
    for (int j = 0; j < 8; j++) a[j] += bf2f((unsigned short)u[j]);
  }
  #pragma unroll
  for (int o = 8; o < 64; o <<= 1){
    #pragma unroll
    for (int j = 0; j < 8; j++) a[j] += __shfl_xor(a[j], o);
  }
  int dg = n1 - n0;
  float sc = 1.f / (float)(dg > 0 ? dg : 1);
  if (lane < 8){
    const float* rb = rootb + (size_t)wid * 64 + q * 8;
    float4 r0 = *(const float4*)(rb);
    float4 r1 = *(const float4*)(rb + 4);
    float4 b0 = *(const float4*)(bias + q * 8);
    float4 b1 = *(const float4*)(bias + q * 8 + 4);
    float* hp = h3 + (size_t)wid * 64 + q * 8;
    *(float4*)(hp)     = make_float4(eluf(a[0]*sc + r0.x + b0.x), eluf(a[1]*sc + r0.y + b0.y),
                                     eluf(a[2]*sc + r0.z + b0.z), eluf(a[3]*sc + r0.w + b0.w));
    *(float4*)(hp + 4) = make_float4(eluf(a[4]*sc + r1.x + b1.x), eluf(a[5]*sc + r1.y + b1.y),
                                     eluf(a[6]*sc + r1.z + b1.z), eluf(a[7]*sc + r1.w + b1.w));
  }
}

// ---------------- GAT2 ----------------

__global__ void gat_lin2_kernel(const float* __restrict__ h, const float* __restrict__ W,
                                const float* __restrict__ atts, const float* __restrict__ attd,
                                float* __restrict__ hw, float* __restrict__ as_, float* __restrict__ ad_){
  int wid  = (blockIdx.x * blockDim.x + threadIdx.x) >> 6;
  int lane = threadIdx.x & 63;
  if (wid >= NN) return;
  float acc = 0.f;
  if (lane < 12){
    const float* hr = h + (size_t)wid * 64;
    const float* Wc = W + lane;
    #pragma unroll 8
    for (int i = 0; i < 64; i++) acc += hr[i] * Wc[(size_t)i * 12];
    hw[(size_t)wid * 12 + lane] = acc;
  }
  float ts = (lane < 12) ? acc * atts[lane] : 0.f;
  float td = (lane < 12) ? acc * attd[lane] : 0.f;
  int b = (lane < 4) ? lane * 3 : 0;
  float s0 = __shfl(ts, b) + __shfl(ts, b + 1) + __shfl(ts, b + 2);
  float d0 = __shfl(td, b) + __shfl(td, b + 1) + __shfl(td, b + 2);
  if (lane < 4){ as_[wid * 4 + lane] = s0; ad_[wid * 4 + lane] = d0; }
}

__global__ void gat2_final_kernel(const float* __restrict__ hw, const float* __restrict__ as_,
                                  const float* __restrict__ ad_, const float* __restrict__ bg2,
                                  const int* __restrict__ offs, const int* __restrict__ csr_src,
                                  float* __restrict__ out){
  int wid  = (blockIdx.x * blockDim.x + threadIdx.x) >> 6;
  int lane = threadIdx.x & 63;
  if (wid >= NN) return;
  int n0 = offs[wid], n1 = offs[wid + 1];
  F4 adn = ld4(ad_ + (size_t)wid * 4);
  F4 asn = ld4(as_ + (size_t)wid * 4);
  F4 es{leakyf(asn.x + adn.x), leakyf(asn.y + adn.y), leakyf(asn.z + adn.z), leakyf(asn.w + adn.w)};
  F4 m = es;
  for (int k = n0 + lane; k < n1; k += 64){
    int s = csr_src[k];
    F4 a = ld4(as_ + (size_t)s * 4);
    m.x = fmaxf(m.x, leakyf(a.x + adn.x));
    m.y = fmaxf(m.y, leakyf(a.y + adn.y));
    m.z = fmaxf(m.z, leakyf(a.z + adn.z));
    m.w = fmaxf(m.w, leakyf(a.w + adn.w));
  }
  #pragma unroll
  for (int o = 32; o; o >>= 1){
    m.x = fmaxf(m.x, __shfl_xor(m.x, o));
    m.y = fmaxf(m.y, __shfl_xor(m.y, o));
    m.z = fmaxf(m.z, __shfl_xor(m.z, o));
    m.w = fmaxf(m.w, __shfl_xor(m.w, o));
  }
  F4 ps{expf(es.x - m.x), expf(es.y - m.y), expf(es.z - m.z), expf(es.w - m.w)};
  float acc[12];
  #pragma unroll
  for (int j = 0; j < 12; j++) acc[j] = 0.f;
  F4 denp{0.f, 0.f, 0.f, 0.f};
  for (int k = n0 + lane; k < n1; k += 64){
    int s = csr_src[k];
    F4 a = ld4(as_ + (size_t)s * 4);
    F4 p{expf(leakyf(a.x + adn.x) - m.x), expf(leakyf(a.y + adn.y) - m.y),
         expf(leakyf(a.z + adn.z) - m.z), expf(leakyf(a.w + adn.w) - m.w)};
    denp.x += p.x; denp.y += p.y; denp.z += p.z; denp.w += p.w;
    const float* hb = hw + (size_t)s * 12;
    F4 h0 = ld4(hb), h1 = ld4(hb + 4), h2 = ld4(hb + 8);
    acc[0] += p.x * h0.x; acc[1]  += p.x * h0.y; acc[2]  += p.x * h0.z;
    acc[3] += p.y * h0.w; acc[4]  += p.y * h1.x; acc[5]  += p.y * h1.y;
    acc[6] += p.z * h1.z; acc[7]  += p.z * h1.w; acc[8]  += p.z * h2.x;
    acc[9] += p.w * h2.y; acc[10] += p.w * h2.z; acc[11] += p.w * h2.w;
  }
  #pragma unroll
  for (int o = 32; o; o >>= 1){
    denp.x += __shfl_xor(denp.x, o);
    denp.y += __shfl_xor(denp.y, o);
    denp.z += __shfl_xor(denp.z, o);
    denp.w += __shfl_xor(denp.w, o);
    #pragma unroll
    for (int j = 0; j < 12; j++) acc[j] += __shfl_xor(acc[j], o);
  }
  if (lane == 0){
    const float* hn = hw + (size_t)wid * 12;
    float dn[4]  = {denp.x + ps.x, denp.y + ps.y, denp.z + ps.z, denp.w + ps.w};
    float psv[4] = {ps.x, ps.y, ps.z, ps.w};
    float tot = 0.f;
    #pragma unroll
    for (int h_ = 0; h_ < 4; h_++){
      #pragma unroll
      for (int c = 0; c < 3; c++){
        float num = acc[h_ * 3 + c] + psv[h_] * hn[h_ * 3 + c];
        tot += num / dn[h_];
      }
    }
    tot = tot / 12.f + (bg2[0] + bg2[1] + bg2[2]) / 3.f;
    out[wid] = tanhf(tot);
  }
}

// ---------------- launch ----------------

extern "C" void kernel_launch(void* const* d_in, const int* in_sizes, int n_in,
                              void* d_out, int out_size, void* d_ws, size_t ws_size,
                              hipStream_t stream){
  const float* x      = (const float*)d_in[0];
  const int*   ei     = (const int*)d_in[1];
  const int*   et     = (const int*)d_in[2];
  const float* basis1 = (const float*)d_in[3];
  const float* comp1  = (const float*)d_in[4];
  const float* root1  = (const float*)d_in[5];
  const float* brg1   = (const float*)d_in[6];
  const float* Wg1    = (const float*)d_in[7];
  const float* atts1  = (const float*)d_in[8];
  const float* attd1  = (const float*)d_in[9];
  const float* bg1    = (const float*)d_in[10];
  const float* basis2 = (const float*)d_in[11];
  const float* comp2  = (const float*)d_in[12];
  const float* root2  = (const float*)d_in[13];
  const float* brg2   = (const float*)d_in[14];
  const float* Wg2    = (const float*)d_in[15];
  const float* atts2  = (const float*)d_in[16];
  const float* attd2  = (const float*)d_in[17];
  const float* bg2    = (const float*)d_in[18];
  float* out = (float*)d_out;

  const int* src = ei;
  const int* dst = ei + NE;

  char* ws = (char*)d_ws;
  size_t off = 0;
  auto alloc = [&](size_t bytes) -> void* {
    void* p = ws + off;
    off = (off + bytes + 255) & ~(size_t)255;
    return p;
  };
  // persistent
  int*   deg     = (int*)alloc((size_t)NN * 4);
  int*   cursor  = (int*)alloc((size_t)NN * 4);
  int*   offs    = (int*)alloc((size_t)(NN + 1) * 4);
  int*   bsum    = (int*)alloc((size_t)256 * 4);
  int*   csr_src = (int*)alloc((size_t)NE * 4);
  int*   csr_et  = (int*)alloc((size_t)NE * 4);
  float* Wcat2   = (float*)alloc((size_t)256 * 384 * 4);
  unsigned short* Bhi2 = (unsigned short*)alloc((size_t)81920 * 2);  // L3: 20*8*64*8
  unsigned short* Blo2 = (unsigned short*)alloc((size_t)81920 * 2);
  unsigned short* Bhi1 = (unsigned short*)alloc((size_t)16384 * 2);  // GAT1: 16*2*64*8
  unsigned short* Blo1 = (unsigned short*)alloc((size_t)16384 * 2);
  float* wa_s    = (float*)alloc((size_t)256 * 4);
  float* wa_d    = (float*)alloc((size_t)256 * 4);
  float* h1      = (float*)alloc((size_t)NN * 64 * 4);
  float* h2      = (float*)alloc((size_t)NN * 256 * 4);
  float* h3      = (float*)alloc((size_t)NN * 64 * 4);
  float* hw2     = (float*)alloc((size_t)NN * 12 * 4);
  float* as1     = (float*)alloc((size_t)NN * 4 * 4);
  float* ad1     = (float*)alloc((size_t)NN * 4 * 4);
  float* as2     = (float*)alloc((size_t)NN * 4 * 4);
  float* ad2     = (float*)alloc((size_t)NN * 4 * 4);
  // scratch union S (NN*384 floats):
  //   agg1[NN*128] -> aggG[NN*256] -> { xr bf16 [NN*512] (= NN*256 floats), rootb [NN*64] }
  float* S       = (float*)alloc((size_t)NN * 384 * 4);
  float* agg1    = S;
  float* aggG    = S;
  unsigned short* xr = (unsigned short*)S;          // NN*512 ushorts = NN*256 floats
  float* rootb   = S + (size_t)NN * 256;            // NN*64 floats
  (void)ws_size; (void)n_in; (void)in_sizes; (void)out_size;

  const int BLK = 256;
  int gridN   = (NN + BLK - 1) / BLK;
  int gridE   = (NE + BLK - 1) / BLK;
  int gridW   = (NN + 3) / 4;
  int gridM64 = (NN + 63) / 64;     // 469
  int gridM256= (NN + 255) / 256;   // 118

  // CSR build + weight prep
  zero2_kernel<<<gridN, BLK, 0, stream>>>(deg, cursor, NN);
  count_kernel<<<gridE, BLK, 0, stream>>>(dst, deg, NE);
  wcat2_kernel<<<(256 * 384 + 255) / 256, BLK, 0, stream>>>(basis2, root2, Wcat2);
  packB_kernel<<<(10240 + 255) / 256, BLK, 0, stream>>>(Wcat2, 384, 8, 10240, Bhi2, Blo2);
  packB_kernel<<<(2048 + 255) / 256, BLK, 0, stream>>>(Wg1, 256, 2, 2048, Bhi1, Blo1);
  wa_kernel<<<1, BLK, 0, stream>>>(Wg1, atts1, attd1, wa_s, wa_d);
  scan1_kernel<<<gridN, BLK, 0, stream>>>(deg, offs, bsum);
  scan2_kernel<<<1, BLK, 0, stream>>>(bsum, gridN);
  scan3_kernel<<<gridN, BLK, 0, stream>>>(bsum, offs);
  scatter_kernel<<<gridE, BLK, 0, stream>>>(src, dst, et, offs, cursor, csr_src, csr_et, NE);

  // Layer 1: RGCN (32 -> 64) + elu
  agg1_kernel<<<gridW, BLK, 0, stream>>>(x, comp1, offs, csr_src, csr_et, agg1);
  gemmT_kernel<4, true><<<dim3(1, gridM64), BLK, 0, stream>>>(
      agg1, 128, 128, basis1, 64,
      x, 32, 32, root1, 64,
      brg1, h1, 64, NN, 0, 0);

  // Layer 2: GAT (64 -> 256 concat) + elu: logits -> aggregate h1 -> MFMA block-diag GEMM
  logits_kernel<<<(NN * 4 + 255) / 256, BLK, 0, stream>>>(h1, wa_s, wa_d, as1, ad1);
  gat1_agg_kernel<<<gridW, BLK, 0, stream>>>(h1, as1, ad1, offs, csr_src, aggG);
  gemm_mfma_kernel<2, true, true><<<dim3(4, gridM256), BLK, 0, stream>>>(
      aggG, 256, 64, Bhi1, Blo1, bg1, h2, 256);

  // Layer 3: RGCN (256 -> 64) + elu: fused MFMA transform (of-split x4) -> xr + root
  gemm_l3_fused_kernel<<<dim3(4, gridM64), BLK, 0, stream>>>(h2, Bhi2, Blo2, comp2, xr, rootb);
  rgcn2_agg_kernel<<<gridW, BLK, 0, stream>>>(xr, rootb, brg2, offs, csr_src, csr_et, h3);

  // Layer 4: GAT (64 -> 4x3, mean heads) + mean classes + tanh
  gat_lin2_kernel<<<gridW, BLK, 0, stream>>>(h3, Wg2, atts2, attd2, hw2, as2, ad2);
  gat2_final_kernel<<<gridW, BLK, 0, stream>>>(hw2, as2, ad2, bg2, offs, csr_src, out);
}